// Round 5
// baseline (1676.894 us; speedup 1.0000x reference)
//
#include <hip/hip_runtime.h>

#define N_NODES 50000
#define N_PAD   50176            // 392 * 128
#define N_EDGES 1600000
#define IN_CH   512
#define HID     256
#define OUT_CH  40
#define BN_EPS  1e-5f

typedef __attribute__((ext_vector_type(8))) short s16x8;
typedef __attribute__((ext_vector_type(8))) unsigned short u16x8;
typedef __attribute__((ext_vector_type(4))) float f32x4;

__device__ __forceinline__ unsigned short f2bf_rne(float f) {
    unsigned u = __float_as_uint(f);
    u += 0x7FFFu + ((u >> 16) & 1u);
    return (unsigned short)(u >> 16);
}
__device__ __forceinline__ float bf2f(unsigned short s) {
    return __uint_as_float((unsigned)s << 16);
}

// async global->LDS, 16B per lane; LDS dest is wave-uniform base + lane*16
__device__ __forceinline__ void gload_lds16(const void* gsrc, void* ldst) {
    __builtin_amdgcn_global_load_lds(
        (const __attribute__((address_space(1))) unsigned int*)gsrc,
        (__attribute__((address_space(3))) unsigned int*)ldst,
        16, 0, 0);
}

// ---------------- degree counting ----------------
__global__ void count_deg_kernel(const int* __restrict__ row, const int* __restrict__ col,
                                 int* __restrict__ deg_row, int* __restrict__ deg_col, int E) {
    int e = blockIdx.x * blockDim.x + threadIdx.x;
    if (e < E) {
        atomicAdd(&deg_row[row[e]], 1);
        atomicAdd(&deg_col[col[e]], 1);
    }
}

__global__ void dis_kernel(const int* __restrict__ deg_row, float* __restrict__ dis, int n) {
    int i = blockIdx.x * blockDim.x + threadIdx.x;
    if (i < n) {
        float d = (float)max(deg_row[i], 1);
        dis[i] = rsqrtf(d);
    }
}

// ---------------- 3-phase exclusive prefix sum ----------------
__global__ void scan1_kernel(const int* __restrict__ deg, int* __restrict__ bsums, int n) {
    __shared__ int sd[256];
    int t = threadIdx.x;
    int i = blockIdx.x * 256 + t;
    sd[t] = (i < n) ? deg[i] : 0;
    __syncthreads();
    for (int o = 128; o > 0; o >>= 1) {
        if (t < o) sd[t] += sd[t + o];
        __syncthreads();
    }
    if (t == 0) bsums[blockIdx.x] = sd[0];
}

__global__ void scan2_kernel(int* __restrict__ bsums, int nb) {   // 1 block, 256 threads
    __shared__ int sd[256];
    int t = threadIdx.x;
    int v = (t < nb) ? bsums[t] : 0;
    sd[t] = v;
    __syncthreads();
    for (int o = 1; o < 256; o <<= 1) {
        int u = (t >= o) ? sd[t - o] : 0;
        __syncthreads();
        sd[t] += u;
        __syncthreads();
    }
    if (t < nb) bsums[t] = sd[t] - v;   // exclusive
}

__global__ void scan3_kernel(const int* __restrict__ deg, const int* __restrict__ bsums,
                             int* __restrict__ offsets, int n) {
    __shared__ int sd[256];
    int t = threadIdx.x;
    int i = blockIdx.x * 256 + t;
    sd[t] = (i < n) ? deg[i] : 0;
    __syncthreads();
    for (int o = 1; o < 256; o <<= 1) {
        int u = (t >= o) ? sd[t - o] : 0;
        __syncthreads();
        sd[t] += u;
        __syncthreads();
    }
    if (i < n) offsets[i + 1] = bsums[blockIdx.x] + sd[t];
    if (i == 0) offsets[0] = 0;
}

// ---------------- CSR fill (group edges by destination col) ----------------
__global__ void fill_csr_kernel(const int* __restrict__ row, const int* __restrict__ col,
                                const float* __restrict__ dis, const int* __restrict__ offsets,
                                int* __restrict__ cursor, int* __restrict__ csr_row,
                                float* __restrict__ csr_norm, int E) {
    int e = blockIdx.x * blockDim.x + threadIdx.x;
    if (e < E) {
        int r = row[e], c = col[e];
        int pos = atomicAdd(&cursor[c], 1);
        int idx = offsets[c] + pos;
        csr_row[idx] = r;
        csr_norm[idx] = dis[r] * dis[c];
    }
}

// ---------------- x hi/lo split ----------------
__global__ void split_x_kernel(const float* __restrict__ x, unsigned short* __restrict__ xhi,
                               unsigned short* __restrict__ xlo, int n4) {
    int i = blockIdx.x * blockDim.x + threadIdx.x;
    if (i < n4) {
        float4 v = ((const float4*)x)[i];
        float r[4] = {v.x, v.y, v.z, v.w};
        ushort4 hs, ls;
        unsigned short* hp = (unsigned short*)&hs;
        unsigned short* lp = (unsigned short*)&ls;
        #pragma unroll
        for (int j = 0; j < 4; ++j) {
            unsigned short h = f2bf_rne(r[j]);
            hp[j] = h;
            lp[j] = f2bf_rne(r[j] - bf2f(h));
        }
        ((ushort4*)xhi)[i] = hs;
        ((ushort4*)xlo)[i] = ls;
    }
}

// ---------------- propagation, column-pass version ----------------
// grid (N/4, 8): pass p gathers a 32-col slice (3.2 MB table -> per-XCD L2-resident).
// Per node: wave split into 4 quarter-waves; quarter q handles edges {i+q, i+4+q, ...};
// each lane reads one dword (2 bf16) -> 64B coalesced per edge. Cross-quarter shfl reduce.
#define PROP_PASSES 8
#define PROP_COLS   (HID / PROP_PASSES)   // 32 columns = 16 dwords = 64B slice

__global__ void prop_kernel(const unsigned short* __restrict__ hsrc,
                            const int* __restrict__ offsets,
                            const int* __restrict__ csr_row, const float* __restrict__ csr_norm,
                            unsigned short* __restrict__ Ohi, unsigned short* __restrict__ Olo,
                            int n) {
    int node = blockIdx.x * 4 + (threadIdx.x >> 6);
    if (node >= n) return;
    int lane = threadIdx.x & 63;
    int q    = lane >> 4;               // quarter-wave id -> edge offset
    int cl   = lane & 15;               // dword index within the 64B slice
    int cbase = blockIdx.y * PROP_COLS + cl * 2;
    const unsigned short* tab = hsrc + cbase;
    int beg = offsets[node], end = offsets[node + 1];
    float a0 = 0.f, a1 = 0.f;
    for (int i = beg; i < end; i += 8) {
        int e0 = i + q, e1 = i + 4 + q;
        float w0 = (e0 < end) ? csr_norm[e0] : 0.f;
        float w1 = (e1 < end) ? csr_norm[e1] : 0.f;
        int s0 = csr_row[min(e0, end - 1)];
        int s1 = csr_row[min(e1, end - 1)];
        unsigned v0 = *(const unsigned*)(tab + (size_t)s0 * HID);
        unsigned v1 = *(const unsigned*)(tab + (size_t)s1 * HID);
        a0 += w0 * bf2f((unsigned short)(v0 & 0xffff)) + w1 * bf2f((unsigned short)(v1 & 0xffff));
        a1 += w0 * bf2f((unsigned short)(v0 >> 16))    + w1 * bf2f((unsigned short)(v1 >> 16));
    }
    a0 += __shfl_xor(a0, 16); a0 += __shfl_xor(a0, 32);
    a1 += __shfl_xor(a1, 16); a1 += __shfl_xor(a1, 32);
    if (q == 0) {
        unsigned short h0 = f2bf_rne(a0), h1 = f2bf_rne(a1);
        *(unsigned*)(Ohi + (size_t)node * HID + cbase) = (unsigned)h0 | ((unsigned)h1 << 16);
    } else if (q == 1) {
        unsigned short h0 = f2bf_rne(a0), h1 = f2bf_rne(a1);
        unsigned short l0 = f2bf_rne(a0 - bf2f(h0));
        unsigned short l1 = f2bf_rne(a1 - bf2f(h1));
        *(unsigned*)(Olo + (size_t)node * HID + cbase) = (unsigned)l0 | ((unsigned)l1 << 16);
    }
}

// ---------------- tiled transpose + hi/lo split: src[R][C] -> dst[C][R] bf16 pair ----------------
__global__ void transpose_split_kernel(const float* __restrict__ src,
                                       unsigned short* __restrict__ dhi,
                                       unsigned short* __restrict__ dlo, int R, int C) {
    __shared__ float tile[32][33];
    int c0 = blockIdx.x * 32, r0 = blockIdx.y * 32;
    int tx = threadIdx.x, ty = threadIdx.y;   // block (32, 8)
    #pragma unroll
    for (int i = 0; i < 32; i += 8) {
        int r = r0 + ty + i, c = c0 + tx;
        tile[ty + i][tx] = (r < R && c < C) ? src[(size_t)r * C + c] : 0.f;
    }
    __syncthreads();
    #pragma unroll
    for (int i = 0; i < 32; i += 8) {
        int c = c0 + ty + i, r = r0 + tx;
        if (c < C && r < R) {
            float f = tile[tx][ty + i];
            unsigned short h = f2bf_rne(f);
            dhi[(size_t)c * R + r] = h;
            dlo[(size_t)c * R + r] = f2bf_rne(f - bf2f(h));
        }
    }
}

// ---------------- MFMA GEMM, double-buffered LDS, counted-overlap 2-phase ----------------
#define GBM 128
#define GBN 128
#define GBK 32

template<int ACT, int OUTMODE, int NC>   // NC = number of column blocks (2 -> XCD-paired swizzle)
__global__ __launch_bounds__(256)
void mfma_gemm_kernel(const unsigned short* __restrict__ A0h, const unsigned short* __restrict__ A0l,
                      const unsigned short* __restrict__ A1h, const unsigned short* __restrict__ A1l,
                      const unsigned short* __restrict__ A2h, const unsigned short* __restrict__ A2l,
                      const unsigned short* __restrict__ Wh, const unsigned short* __restrict__ Wl,
                      const float* __restrict__ bvec,
                      float* __restrict__ C, unsigned short* __restrict__ Chi,
                      unsigned short* __restrict__ Clo,
                      int M, int K, int seg, int Kout) {
    // [buf][kgroup(4)][row(128)][8 bf16]; 8KB per plane per buf -> 64KB total
    __shared__ __attribute__((aligned(16))) unsigned short As_hi[2][4 * GBM * 8];
    __shared__ __attribute__((aligned(16))) unsigned short As_lo[2][4 * GBM * 8];
    __shared__ __attribute__((aligned(16))) unsigned short Bs_hi[2][4 * GBN * 8];
    __shared__ __attribute__((aligned(16))) unsigned short Bs_lo[2][4 * GBN * 8];

    int tid  = threadIdx.x;
    int lane = tid & 63;
    int w    = tid >> 6;                   // wave id == the kgroup this wave stages
    int wm   = w & 1, wn = w >> 1;         // 2x2 waves, 64x64 each
    int kg   = lane >> 4, lr = lane & 15;

    int bid = blockIdx.x, p, c;
    if (NC == 2) { p = ((bid >> 4) << 3) + (bid & 7); c = (bid >> 3) & 1; }
    else         { p = bid; c = 0; }
    int bm = p * GBM, bn = c * GBN;

    f32x4 acc[4][4];
    #pragma unroll
    for (int i = 0; i < 4; ++i)
        #pragma unroll
        for (int j = 0; j < 4; ++j)
            acc[i][j] = (f32x4){0.f, 0.f, 0.f, 0.f};

    auto STAGE = [&](int buf, int k0) {
        const unsigned short *Aph, *Apl; int kl0;
        if (k0 < seg)          { Aph = A0h; Apl = A0l; kl0 = k0; }
        else if (k0 < 2 * seg) { Aph = A1h; Apl = A1l; kl0 = k0 - seg; }
        else                   { Aph = A2h; Apl = A2l; kl0 = k0 - 2 * seg; }
        const unsigned short* a_h = Aph + (size_t)(bm + lane) * seg + kl0 + w * 8;
        const unsigned short* a_l = Apl + (size_t)(bm + lane) * seg + kl0 + w * 8;
        const unsigned short* b_h = Wh + (size_t)(bn + lane) * K + k0 + w * 8;
        const unsigned short* b_l = Wl + (size_t)(bn + lane) * K + k0 + w * 8;
        size_t rA = (size_t)64 * seg, rB = (size_t)64 * K;
        gload_lds16(a_h,      &As_hi[buf][(w * 128) * 8]);
        gload_lds16(a_h + rA, &As_hi[buf][(w * 128 + 64) * 8]);
        gload_lds16(a_l,      &As_lo[buf][(w * 128) * 8]);
        gload_lds16(a_l + rA, &As_lo[buf][(w * 128 + 64) * 8]);
        gload_lds16(b_h,      &Bs_hi[buf][(w * 128) * 8]);
        gload_lds16(b_h + rB, &Bs_hi[buf][(w * 128 + 64) * 8]);
        gload_lds16(b_l,      &Bs_lo[buf][(w * 128) * 8]);
        gload_lds16(b_l + rB, &Bs_lo[buf][(w * 128 + 64) * 8]);
    };

    int nt = K / GBK;
    STAGE(0, 0);
    asm volatile("s_waitcnt vmcnt(0)" ::: "memory");
    __builtin_amdgcn_s_barrier();
    __builtin_amdgcn_sched_barrier(0);

    for (int t = 0; t < nt; ++t) {
        int cur = t & 1;
        if (t + 1 < nt) STAGE(cur ^ 1, (t + 1) * GBK);   // overlaps this step's compute

        int abase = (kg * GBM + wm * 64 + lr) * 8;
        int bbase = (kg * GBN + wn * 64 + lr) * 8;
        s16x8 ah[4], al[4], bh[4], bl[4];
        #pragma unroll
        for (int mf = 0; mf < 4; ++mf) {
            ah[mf] = *(const s16x8*)&As_hi[cur][abase + mf * 16 * 8];
            al[mf] = *(const s16x8*)&As_lo[cur][abase + mf * 16 * 8];
        }
        #pragma unroll
        for (int nf = 0; nf < 4; ++nf) {
            bh[nf] = *(const s16x8*)&Bs_hi[cur][bbase + nf * 16 * 8];
            bl[nf] = *(const s16x8*)&Bs_lo[cur][bbase + nf * 16 * 8];
        }
        #pragma unroll
        for (int mf = 0; mf < 4; ++mf)
            #pragma unroll
            for (int nf = 0; nf < 4; ++nf) {
                acc[mf][nf] = __builtin_amdgcn_mfma_f32_16x16x32_bf16(ah[mf], bh[nf], acc[mf][nf], 0, 0, 0);
                acc[mf][nf] = __builtin_amdgcn_mfma_f32_16x16x32_bf16(al[mf], bh[nf], acc[mf][nf], 0, 0, 0);
                acc[mf][nf] = __builtin_amdgcn_mfma_f32_16x16x32_bf16(ah[mf], bl[nf], acc[mf][nf], 0, 0, 0);
            }

        asm volatile("s_waitcnt vmcnt(0)" ::: "memory");  // next tile landed
        __builtin_amdgcn_s_barrier();                     // all reads of buf 'cur' done
        __builtin_amdgcn_sched_barrier(0);
    }

    // ---- epilogue: C/D layout col = lane&15, row = (lane>>4)*4 + reg ----
    #pragma unroll
    for (int nf = 0; nf < 4; ++nf) {
        int col = bn + wn * 64 + nf * 16 + lr;
        if (col >= Kout) continue;
        float bv = bvec[col];
        #pragma unroll
        for (int mf = 0; mf < 4; ++mf) {
            #pragma unroll
            for (int i = 0; i < 4; ++i) {
                int rw = bm + wm * 64 + mf * 16 + kg * 4 + i;
                if (rw < M) {
                    float v = acc[mf][nf][i] + bv;
                    if (ACT == 1) v = fmaxf(v, 0.f);
                    if (OUTMODE == 0) {
                        C[(size_t)rw * Kout + col] = v;
                    } else {
                        unsigned short hs = f2bf_rne(v);
                        Chi[(size_t)rw * Kout + col] = hs;
                        Clo[(size_t)rw * Kout + col] = f2bf_rne(v - bf2f(hs));
                    }
                }
            }
        }
    }
}

// ---------------- BN column stats ----------------
__global__ void colstats_kernel(const float* __restrict__ y, float* __restrict__ sums,
                                float* __restrict__ sumsq, int M) {
    int col = threadIdx.x;  // 256 threads = HID
    int r0 = blockIdx.x * 128;
    int r1 = min(r0 + 128, M);
    float s = 0.f, s2 = 0.f;
    for (int r = r0; r < r1; ++r) {
        float v = y[(size_t)r * HID + col];
        s += v; s2 += v * v;
    }
    atomicAdd(&sums[col], s);
    atomicAdd(&sumsq[col], s2);
}

__global__ void bnrelu_kernel(const float* __restrict__ y, const float* __restrict__ sums,
                              const float* __restrict__ sumsq, const float* __restrict__ g,
                              const float* __restrict__ beta,
                              unsigned short* __restrict__ Hhi, unsigned short* __restrict__ Hlo,
                              int M) {
    int idx = blockIdx.x * blockDim.x + threadIdx.x;   // group of 4 channels
    if (idx < M * HID / 4) {
        int col0 = (idx * 4) & (HID - 1);
        float4 v = ((const float4*)y)[idx];
        float invM = 1.0f / (float)M;
        float r[4] = {v.x, v.y, v.z, v.w};
        ushort4 hs, ls;
        unsigned short* hp = (unsigned short*)&hs;
        unsigned short* lp = (unsigned short*)&ls;
        #pragma unroll
        for (int j = 0; j < 4; ++j) {
            int col = col0 + j;
            float mean = sums[col] * invM;
            float var  = fmaxf(sumsq[col] * invM - mean * mean, 0.f);
            float o = (r[j] - mean) * rsqrtf(var + BN_EPS) * g[col] + beta[col];
            o = fmaxf(o, 0.f);
            unsigned short h = f2bf_rne(o);
            hp[j] = h;
            lp[j] = f2bf_rne(o - bf2f(h));
        }
        ((ushort4*)Hhi)[idx] = hs;
        ((ushort4*)Hlo)[idx] = ls;
    }
}

extern "C" void kernel_launch(void* const* d_in, const int* in_sizes, int n_in,
                              void* d_out, int out_size, void* d_ws, size_t ws_size,
                              hipStream_t stream) {
    const float* x      = (const float*)d_in[0];
    const int*   ei     = (const int*)d_in[1];
    const float* W_feat = (const float*)d_in[2];
    const float* b_feat = (const float*)d_in[3];
    const float* W0     = (const float*)d_in[4];
    const float* b0     = (const float*)d_in[5];
    const float* g0     = (const float*)d_in[6];
    const float* beta0  = (const float*)d_in[7];
    const float* W1     = (const float*)d_in[8];
    const float* b1     = (const float*)d_in[9];
    const float* g1     = (const float*)d_in[10];
    const float* beta1  = (const float*)d_in[11];
    const float* Wc     = (const float*)d_in[12];
    const float* bc     = (const float*)d_in[13];
    float* out = (float*)d_out;

    const int N = N_NODES, E = N_EDGES;
    const int* row = ei;
    const int* col = ei + E;

    // workspace carve-up
    char* ws = (char*)d_ws;
    size_t off = 0;
    auto alloc = [&](size_t bytes) -> void* {
        void* p = ws + off;
        off = (off + bytes + 255) & ~(size_t)255;
        return p;
    };
    int*   deg_row  = (int*)  alloc(N * 4);
    int*   deg_col  = (int*)  alloc(N * 4);
    int*   cursor   = (int*)  alloc(N * 4);
    int*   offsets  = (int*)  alloc((N + 1) * 4);
    int*   bsums    = (int*)  alloc(256 * 4);
    float* dis      = (float*)alloc(N * 4);
    int*   csr_row  = (int*)  alloc((size_t)E * 4);
    float* csr_norm = (float*)alloc((size_t)E * 4);
    unsigned short* x_hi    = (unsigned short*)alloc((size_t)N_PAD * IN_CH * 2);
    unsigned short* x_lo    = (unsigned short*)alloc((size_t)N_PAD * IN_CH * 2);
    unsigned short* h_hi    = (unsigned short*)alloc((size_t)N_PAD * HID * 2);
    unsigned short* h_lo    = (unsigned short*)alloc((size_t)N_PAD * HID * 2);
    unsigned short* agg1_hi = (unsigned short*)alloc((size_t)N_PAD * HID * 2);
    unsigned short* agg1_lo = (unsigned short*)alloc((size_t)N_PAD * HID * 2);
    // lifetime aliasing: x_hi/x_lo are dead after the feat GEMM; reuse the region
    unsigned short* agg2_hi = x_hi;
    unsigned short* agg2_lo = x_hi + (size_t)N_PAD * HID;
    float*          y       = (float*)x_lo;
    float* sums     = (float*)alloc(HID * 4);
    float* sumsq    = (float*)alloc(HID * 4);
    unsigned short* WTf_hi = (unsigned short*)alloc((size_t)HID * IN_CH * 2);
    unsigned short* WTf_lo = (unsigned short*)alloc((size_t)HID * IN_CH * 2);
    unsigned short* WT0_hi = (unsigned short*)alloc((size_t)HID * 3 * HID * 2);
    unsigned short* WT0_lo = (unsigned short*)alloc((size_t)HID * 3 * HID * 2);
    unsigned short* WT1_hi = (unsigned short*)alloc((size_t)HID * 3 * HID * 2);
    unsigned short* WT1_lo = (unsigned short*)alloc((size_t)HID * 3 * HID * 2);
    unsigned short* WTc_hi = (unsigned short*)alloc((size_t)128 * HID * 2);   // 40 rows padded to 128
    unsigned short* WTc_lo = (unsigned short*)alloc((size_t)128 * HID * 2);

    hipMemsetAsync(deg_row, 0, N * 4, stream);
    hipMemsetAsync(deg_col, 0, N * 4, stream);
    hipMemsetAsync(cursor, 0, N * 4, stream);
    hipMemsetAsync(WTc_hi, 0, (size_t)128 * HID * 2, stream);
    hipMemsetAsync(WTc_lo, 0, (size_t)128 * HID * 2, stream);

    // operand pre-splits (independent of CSR build)
    split_x_kernel<<<(N * IN_CH / 4 + 255) / 256, 256, 0, stream>>>(x, x_hi, x_lo, N * IN_CH / 4);
    dim3 tb(32, 8);
    transpose_split_kernel<<<dim3(HID / 32, IN_CH / 32), tb, 0, stream>>>(W_feat, WTf_hi, WTf_lo, IN_CH, HID);
    transpose_split_kernel<<<dim3(HID / 32, 3 * HID / 32), tb, 0, stream>>>(W0, WT0_hi, WT0_lo, 3 * HID, HID);
    transpose_split_kernel<<<dim3(HID / 32, 3 * HID / 32), tb, 0, stream>>>(W1, WT1_hi, WT1_lo, 3 * HID, HID);
    transpose_split_kernel<<<dim3((OUT_CH + 31) / 32, HID / 32), tb, 0, stream>>>(Wc, WTc_hi, WTc_lo, HID, OUT_CH);

    count_deg_kernel<<<(E + 255) / 256, 256, 0, stream>>>(row, col, deg_row, deg_col, E);
    dis_kernel<<<(N + 255) / 256, 256, 0, stream>>>(deg_row, dis, N);
    const int NB_SCAN = (N + 255) / 256;   // 196
    scan1_kernel<<<NB_SCAN, 256, 0, stream>>>(deg_col, bsums, N);
    scan2_kernel<<<1, 256, 0, stream>>>(bsums, NB_SCAN);
    scan3_kernel<<<NB_SCAN, 256, 0, stream>>>(deg_col, bsums, offsets, N);
    fill_csr_kernel<<<(E + 255) / 256, 256, 0, stream>>>(row, col, dis, offsets, cursor,
                                                         csr_row, csr_norm, E);

    const int NPAN = N_PAD / GBM;          // 392 row-panels
    // h = relu(x @ W_feat + b_feat) -> hi/lo pair
    mfma_gemm_kernel<1, 1, 2><<<NPAN * 2, 256, 0, stream>>>(
        x_hi, x_lo, nullptr, nullptr, nullptr, nullptr, WTf_hi, WTf_lo, b_feat,
        nullptr, h_hi, h_lo, N, IN_CH, IN_CH, HID);

    const unsigned short* WThs[2] = {WT0_hi, WT1_hi};
    const unsigned short* WTls[2] = {WT0_lo, WT1_lo};
    const float* bs[2]    = {b0, b1};
    const float* gs[2]    = {g0, g1};
    const float* betas[2] = {beta0, beta1};
    dim3 pgrid((N + 3) / 4, PROP_PASSES);
    for (int layer = 0; layer < 2; ++layer) {
        prop_kernel<<<pgrid, 256, 0, stream>>>(h_hi, offsets, csr_row, csr_norm,
                                               agg1_hi, agg1_lo, N);
        prop_kernel<<<pgrid, 256, 0, stream>>>(agg1_hi, offsets, csr_row, csr_norm,
                                               agg2_hi, agg2_lo, N);
        mfma_gemm_kernel<0, 0, 2><<<NPAN * 2, 256, 0, stream>>>(
            h_hi, h_lo, agg1_hi, agg1_lo, agg2_hi, agg2_lo, WThs[layer], WTls[layer], bs[layer],
            y, nullptr, nullptr, N, 3 * HID, HID, HID);
        hipMemsetAsync(sums, 0, HID * 4, stream);
        hipMemsetAsync(sumsq, 0, HID * 4, stream);
        colstats_kernel<<<(N + 127) / 128, HID, 0, stream>>>(y, sums, sumsq, N);
        bnrelu_kernel<<<(N * HID / 4 + 255) / 256, 256, 0, stream>>>(y, sums, sumsq, gs[layer],
                                                                     betas[layer], h_hi, h_lo, N);
    }

    mfma_gemm_kernel<0, 0, 1><<<NPAN, 256, 0, stream>>>(
        h_hi, h_lo, nullptr, nullptr, nullptr, nullptr, WTc_hi, WTc_lo, bc,
        out, nullptr, nullptr, N, HID, HID, OUT_CH);
}

// Round 6
// 1233.930 us; speedup vs baseline: 1.3590x; 1.3590x over previous
//
#include <hip/hip_runtime.h>

#define N_NODES 50000
#define N_PAD   50176            // 392 * 128
#define N_EDGES 1600000
#define IN_CH   512
#define HID     256
#define OUT_CH  40
#define BN_EPS  1e-5f

typedef __attribute__((ext_vector_type(8))) short s16x8;
typedef __attribute__((ext_vector_type(8))) unsigned short u16x8;
typedef __attribute__((ext_vector_type(4))) float f32x4;

__device__ __forceinline__ unsigned short f2bf_rne(float f) {
    unsigned u = __float_as_uint(f);
    u += 0x7FFFu + ((u >> 16) & 1u);
    return (unsigned short)(u >> 16);
}
__device__ __forceinline__ float bf2f(unsigned short s) {
    return __uint_as_float((unsigned)s << 16);
}

// async global->LDS, 16B per lane; LDS dest is wave-uniform base + lane*16
__device__ __forceinline__ void gload_lds16(const void* gsrc, void* ldst) {
    __builtin_amdgcn_global_load_lds(
        (const __attribute__((address_space(1))) unsigned int*)gsrc,
        (__attribute__((address_space(3))) unsigned int*)ldst,
        16, 0, 0);
}

// ---------------- degree counting ----------------
__global__ void count_deg_kernel(const int* __restrict__ row, const int* __restrict__ col,
                                 int* __restrict__ deg_row, int* __restrict__ deg_col, int E) {
    int e = blockIdx.x * blockDim.x + threadIdx.x;
    if (e < E) {
        atomicAdd(&deg_row[row[e]], 1);
        atomicAdd(&deg_col[col[e]], 1);
    }
}

__global__ void dis_kernel(const int* __restrict__ deg_row, float* __restrict__ dis, int n) {
    int i = blockIdx.x * blockDim.x + threadIdx.x;
    if (i < n) {
        float d = (float)max(deg_row[i], 1);
        dis[i] = rsqrtf(d);
    }
}

// ---------------- 3-phase exclusive prefix sum ----------------
__global__ void scan1_kernel(const int* __restrict__ deg, int* __restrict__ bsums, int n) {
    __shared__ int sd[256];
    int t = threadIdx.x;
    int i = blockIdx.x * 256 + t;
    sd[t] = (i < n) ? deg[i] : 0;
    __syncthreads();
    for (int o = 128; o > 0; o >>= 1) {
        if (t < o) sd[t] += sd[t + o];
        __syncthreads();
    }
    if (t == 0) bsums[blockIdx.x] = sd[0];
}

__global__ void scan2_kernel(int* __restrict__ bsums, int nb) {   // 1 block, 256 threads
    __shared__ int sd[256];
    int t = threadIdx.x;
    int v = (t < nb) ? bsums[t] : 0;
    sd[t] = v;
    __syncthreads();
    for (int o = 1; o < 256; o <<= 1) {
        int u = (t >= o) ? sd[t - o] : 0;
        __syncthreads();
        sd[t] += u;
        __syncthreads();
    }
    if (t < nb) bsums[t] = sd[t] - v;   // exclusive
}

__global__ void scan3_kernel(const int* __restrict__ deg, const int* __restrict__ bsums,
                             int* __restrict__ offsets, int n) {
    __shared__ int sd[256];
    int t = threadIdx.x;
    int i = blockIdx.x * 256 + t;
    sd[t] = (i < n) ? deg[i] : 0;
    __syncthreads();
    for (int o = 1; o < 256; o <<= 1) {
        int u = (t >= o) ? sd[t - o] : 0;
        __syncthreads();
        sd[t] += u;
        __syncthreads();
    }
    if (i < n) offsets[i + 1] = bsums[blockIdx.x] + sd[t];
    if (i == 0) offsets[0] = 0;
}

// ---------------- CSR fill (group edges by destination col) ----------------
__global__ void fill_csr_kernel(const int* __restrict__ row, const int* __restrict__ col,
                                const float* __restrict__ dis, const int* __restrict__ offsets,
                                int* __restrict__ cursor, int* __restrict__ csr_row,
                                float* __restrict__ csr_norm, int E) {
    int e = blockIdx.x * blockDim.x + threadIdx.x;
    if (e < E) {
        int r = row[e], c = col[e];
        int pos = atomicAdd(&cursor[c], 1);
        int idx = offsets[c] + pos;
        csr_row[idx] = r;
        csr_norm[idx] = dis[r] * dis[c];
    }
}

// ---------------- x hi/lo split ----------------
__global__ void split_x_kernel(const float* __restrict__ x, unsigned short* __restrict__ xhi,
                               unsigned short* __restrict__ xlo, int n4) {
    int i = blockIdx.x * blockDim.x + threadIdx.x;
    if (i < n4) {
        float4 v = ((const float4*)x)[i];
        float r[4] = {v.x, v.y, v.z, v.w};
        ushort4 hs, ls;
        unsigned short* hp = (unsigned short*)&hs;
        unsigned short* lp = (unsigned short*)&ls;
        #pragma unroll
        for (int j = 0; j < 4; ++j) {
            unsigned short h = f2bf_rne(r[j]);
            hp[j] = h;
            lp[j] = f2bf_rne(r[j] - bf2f(h));
        }
        ((ushort4*)xhi)[i] = hs;
        ((ushort4*)xlo)[i] = ls;
    }
}

// ---------------- propagation (full-row gather, deep MLP) ----------------
// 1 node per wave; 2 half-waves each gather a full 512B row per edge;
// 4-deep unroll per half -> 8 gathers in flight per wave.
// Half0 writes hi plane, half1 writes lo plane after cross-half reduce.
__global__ void prop_kernel(const unsigned short* __restrict__ hsrc,
                            const int* __restrict__ offsets,
                            const int* __restrict__ csr_row, const float* __restrict__ csr_norm,
                            unsigned short* __restrict__ Ohi, unsigned short* __restrict__ Olo,
                            int n) {
    int node = blockIdx.x * 4 + (threadIdx.x >> 6);
    if (node >= n) return;
    int lane = threadIdx.x & 63;
    int half = lane >> 5;
    int cl   = lane & 31;           // 16B chunk id within the 512B row
    int beg = offsets[node], end = offsets[node + 1];
    float acc[8] = {0.f, 0.f, 0.f, 0.f, 0.f, 0.f, 0.f, 0.f};
    for (int i = beg; i < end; i += 8) {
        int ii[4] = {i + half, i + 2 + half, i + 4 + half, i + 6 + half};
        float w[4];
        int s[4];
        #pragma unroll
        for (int u = 0; u < 4; ++u) {
            w[u] = (ii[u] < end) ? csr_norm[ii[u]] : 0.f;
            s[u] = csr_row[min(ii[u], end - 1)];
        }
        u16x8 v[4];
        #pragma unroll
        for (int u = 0; u < 4; ++u)
            v[u] = *(const u16x8*)(hsrc + (size_t)s[u] * HID + cl * 8);
        #pragma unroll
        for (int u = 0; u < 4; ++u)
            #pragma unroll
            for (int j = 0; j < 8; ++j)
                acc[j] += w[u] * bf2f((unsigned short)v[u][j]);
    }
    #pragma unroll
    for (int j = 0; j < 8; ++j) acc[j] += __shfl_xor(acc[j], 32);
    u16x8 ov;
    if (half == 0) {
        #pragma unroll
        for (int j = 0; j < 8; ++j) ov[j] = f2bf_rne(acc[j]);
        *(u16x8*)(Ohi + (size_t)node * HID + cl * 8) = ov;
    } else {
        #pragma unroll
        for (int j = 0; j < 8; ++j) {
            unsigned short h = f2bf_rne(acc[j]);
            ov[j] = f2bf_rne(acc[j] - bf2f(h));
        }
        *(u16x8*)(Olo + (size_t)node * HID + cl * 8) = ov;
    }
}

// ---------------- tiled transpose + hi/lo split: src[R][C] -> dst[C][R] bf16 pair ----------------
__global__ void transpose_split_kernel(const float* __restrict__ src,
                                       unsigned short* __restrict__ dhi,
                                       unsigned short* __restrict__ dlo, int R, int C) {
    __shared__ float tile[32][33];
    int c0 = blockIdx.x * 32, r0 = blockIdx.y * 32;
    int tx = threadIdx.x, ty = threadIdx.y;   // block (32, 8)
    #pragma unroll
    for (int i = 0; i < 32; i += 8) {
        int r = r0 + ty + i, c = c0 + tx;
        tile[ty + i][tx] = (r < R && c < C) ? src[(size_t)r * C + c] : 0.f;
    }
    __syncthreads();
    #pragma unroll
    for (int i = 0; i < 32; i += 8) {
        int c = c0 + ty + i, r = r0 + tx;
        if (c < C && r < R) {
            float f = tile[tx][ty + i];
            unsigned short h = f2bf_rne(f);
            dhi[(size_t)c * R + r] = h;
            dlo[(size_t)c * R + r] = f2bf_rne(f - bf2f(h));
        }
    }
}

// ---------------- MFMA GEMM, double-buffered LDS, counted-overlap 2-phase ----------------
#define GBM 128
#define GBN 128
#define GBK 32

template<int ACT, int OUTMODE, int NC>   // NC = number of column blocks (2 -> XCD-paired swizzle)
__global__ __launch_bounds__(256)
void mfma_gemm_kernel(const unsigned short* __restrict__ A0h, const unsigned short* __restrict__ A0l,
                      const unsigned short* __restrict__ A1h, const unsigned short* __restrict__ A1l,
                      const unsigned short* __restrict__ A2h, const unsigned short* __restrict__ A2l,
                      const unsigned short* __restrict__ Wh, const unsigned short* __restrict__ Wl,
                      const float* __restrict__ bvec,
                      float* __restrict__ C, unsigned short* __restrict__ Chi,
                      unsigned short* __restrict__ Clo,
                      int M, int K, int seg, int Kout) {
    // [buf][kgroup(4)][row(128)][8 bf16]; 8KB per plane per buf -> 64KB total
    __shared__ __attribute__((aligned(16))) unsigned short As_hi[2][4 * GBM * 8];
    __shared__ __attribute__((aligned(16))) unsigned short As_lo[2][4 * GBM * 8];
    __shared__ __attribute__((aligned(16))) unsigned short Bs_hi[2][4 * GBN * 8];
    __shared__ __attribute__((aligned(16))) unsigned short Bs_lo[2][4 * GBN * 8];

    int tid  = threadIdx.x;
    int lane = tid & 63;
    int w    = tid >> 6;                   // wave id == the kgroup this wave stages
    int wm   = w & 1, wn = w >> 1;         // 2x2 waves, 64x64 each
    int kg   = lane >> 4, lr = lane & 15;

    int bid = blockIdx.x, p, c;
    if (NC == 2) { p = ((bid >> 4) << 3) + (bid & 7); c = (bid >> 3) & 1; }
    else         { p = bid; c = 0; }
    int bm = p * GBM, bn = c * GBN;

    f32x4 acc[4][4];
    #pragma unroll
    for (int i = 0; i < 4; ++i)
        #pragma unroll
        for (int j = 0; j < 4; ++j)
            acc[i][j] = (f32x4){0.f, 0.f, 0.f, 0.f};

    auto STAGE = [&](int buf, int k0) {
        const unsigned short *Aph, *Apl; int kl0;
        if (k0 < seg)          { Aph = A0h; Apl = A0l; kl0 = k0; }
        else if (k0 < 2 * seg) { Aph = A1h; Apl = A1l; kl0 = k0 - seg; }
        else                   { Aph = A2h; Apl = A2l; kl0 = k0 - 2 * seg; }
        const unsigned short* a_h = Aph + (size_t)(bm + lane) * seg + kl0 + w * 8;
        const unsigned short* a_l = Apl + (size_t)(bm + lane) * seg + kl0 + w * 8;
        const unsigned short* b_h = Wh + (size_t)(bn + lane) * K + k0 + w * 8;
        const unsigned short* b_l = Wl + (size_t)(bn + lane) * K + k0 + w * 8;
        size_t rA = (size_t)64 * seg, rB = (size_t)64 * K;
        gload_lds16(a_h,      &As_hi[buf][(w * 128) * 8]);
        gload_lds16(a_h + rA, &As_hi[buf][(w * 128 + 64) * 8]);
        gload_lds16(a_l,      &As_lo[buf][(w * 128) * 8]);
        gload_lds16(a_l + rA, &As_lo[buf][(w * 128 + 64) * 8]);
        gload_lds16(b_h,      &Bs_hi[buf][(w * 128) * 8]);
        gload_lds16(b_h + rB, &Bs_hi[buf][(w * 128 + 64) * 8]);
        gload_lds16(b_l,      &Bs_lo[buf][(w * 128) * 8]);
        gload_lds16(b_l + rB, &Bs_lo[buf][(w * 128 + 64) * 8]);
    };

    int nt = K / GBK;
    STAGE(0, 0);
    asm volatile("s_waitcnt vmcnt(0)" ::: "memory");
    __builtin_amdgcn_s_barrier();
    __builtin_amdgcn_sched_barrier(0);

    for (int t = 0; t < nt; ++t) {
        int cur = t & 1;
        if (t + 1 < nt) STAGE(cur ^ 1, (t + 1) * GBK);   // overlaps this step's compute

        int abase = (kg * GBM + wm * 64 + lr) * 8;
        int bbase = (kg * GBN + wn * 64 + lr) * 8;
        s16x8 ah[4], al[4], bh[4], bl[4];
        #pragma unroll
        for (int mf = 0; mf < 4; ++mf) {
            ah[mf] = *(const s16x8*)&As_hi[cur][abase + mf * 16 * 8];
            al[mf] = *(const s16x8*)&As_lo[cur][abase + mf * 16 * 8];
        }
        #pragma unroll
        for (int nf = 0; nf < 4; ++nf) {
            bh[nf] = *(const s16x8*)&Bs_hi[cur][bbase + nf * 16 * 8];
            bl[nf] = *(const s16x8*)&Bs_lo[cur][bbase + nf * 16 * 8];
        }
        #pragma unroll
        for (int mf = 0; mf < 4; ++mf)
            #pragma unroll
            for (int nf = 0; nf < 4; ++nf) {
                acc[mf][nf] = __builtin_amdgcn_mfma_f32_16x16x32_bf16(ah[mf], bh[nf], acc[mf][nf], 0, 0, 0);
                acc[mf][nf] = __builtin_amdgcn_mfma_f32_16x16x32_bf16(al[mf], bh[nf], acc[mf][nf], 0, 0, 0);
                acc[mf][nf] = __builtin_amdgcn_mfma_f32_16x16x32_bf16(ah[mf], bl[nf], acc[mf][nf], 0, 0, 0);
            }

        asm volatile("s_waitcnt vmcnt(0)" ::: "memory");  // next tile landed
        __builtin_amdgcn_s_barrier();                     // all reads of buf 'cur' done
        __builtin_amdgcn_sched_barrier(0);
    }

    // ---- epilogue: C/D layout col = lane&15, row = (lane>>4)*4 + reg ----
    #pragma unroll
    for (int nf = 0; nf < 4; ++nf) {
        int col = bn + wn * 64 + nf * 16 + lr;
        if (col >= Kout) continue;
        float bv = bvec[col];
        #pragma unroll
        for (int mf = 0; mf < 4; ++mf) {
            #pragma unroll
            for (int i = 0; i < 4; ++i) {
                int rw = bm + wm * 64 + mf * 16 + kg * 4 + i;
                if (rw < M) {
                    float v = acc[mf][nf][i] + bv;
                    if (ACT == 1) v = fmaxf(v, 0.f);
                    if (OUTMODE == 0) {
                        C[(size_t)rw * Kout + col] = v;
                    } else {
                        unsigned short hs = f2bf_rne(v);
                        Chi[(size_t)rw * Kout + col] = hs;
                        Clo[(size_t)rw * Kout + col] = f2bf_rne(v - bf2f(hs));
                    }
                }
            }
        }
    }
}

// ---------------- BN column stats ----------------
__global__ void colstats_kernel(const float* __restrict__ y, float* __restrict__ sums,
                                float* __restrict__ sumsq, int M) {
    int col = threadIdx.x;  // 256 threads = HID
    int r0 = blockIdx.x * 128;
    int r1 = min(r0 + 128, M);
    float s = 0.f, s2 = 0.f;
    for (int r = r0; r < r1; ++r) {
        float v = y[(size_t)r * HID + col];
        s += v; s2 += v * v;
    }
    atomicAdd(&sums[col], s);
    atomicAdd(&sumsq[col], s2);
}

__global__ void bnrelu_kernel(const float* __restrict__ y, const float* __restrict__ sums,
                              const float* __restrict__ sumsq, const float* __restrict__ g,
                              const float* __restrict__ beta,
                              unsigned short* __restrict__ Hhi, unsigned short* __restrict__ Hlo,
                              int M) {
    int idx = blockIdx.x * blockDim.x + threadIdx.x;   // group of 4 channels
    if (idx < M * HID / 4) {
        int col0 = (idx * 4) & (HID - 1);
        float4 v = ((const float4*)y)[idx];
        float invM = 1.0f / (float)M;
        float r[4] = {v.x, v.y, v.z, v.w};
        ushort4 hs, ls;
        unsigned short* hp = (unsigned short*)&hs;
        unsigned short* lp = (unsigned short*)&ls;
        #pragma unroll
        for (int j = 0; j < 4; ++j) {
            int col = col0 + j;
            float mean = sums[col] * invM;
            float var  = fmaxf(sumsq[col] * invM - mean * mean, 0.f);
            float o = (r[j] - mean) * rsqrtf(var + BN_EPS) * g[col] + beta[col];
            o = fmaxf(o, 0.f);
            unsigned short h = f2bf_rne(o);
            hp[j] = h;
            lp[j] = f2bf_rne(o - bf2f(h));
        }
        ((ushort4*)Hhi)[idx] = hs;
        ((ushort4*)Hlo)[idx] = ls;
    }
}

extern "C" void kernel_launch(void* const* d_in, const int* in_sizes, int n_in,
                              void* d_out, int out_size, void* d_ws, size_t ws_size,
                              hipStream_t stream) {
    const float* x      = (const float*)d_in[0];
    const int*   ei     = (const int*)d_in[1];
    const float* W_feat = (const float*)d_in[2];
    const float* b_feat = (const float*)d_in[3];
    const float* W0     = (const float*)d_in[4];
    const float* b0     = (const float*)d_in[5];
    const float* g0     = (const float*)d_in[6];
    const float* beta0  = (const float*)d_in[7];
    const float* W1     = (const float*)d_in[8];
    const float* b1     = (const float*)d_in[9];
    const float* g1     = (const float*)d_in[10];
    const float* beta1  = (const float*)d_in[11];
    const float* Wc     = (const float*)d_in[12];
    const float* bc     = (const float*)d_in[13];
    float* out = (float*)d_out;

    const int N = N_NODES, E = N_EDGES;
    const int* row = ei;
    const int* col = ei + E;

    // workspace carve-up
    char* ws = (char*)d_ws;
    size_t off = 0;
    auto alloc = [&](size_t bytes) -> void* {
        void* p = ws + off;
        off = (off + bytes + 255) & ~(size_t)255;
        return p;
    };
    int*   deg_row  = (int*)  alloc(N * 4);
    int*   deg_col  = (int*)  alloc(N * 4);
    int*   cursor   = (int*)  alloc(N * 4);
    int*   offsets  = (int*)  alloc((N + 1) * 4);
    int*   bsums    = (int*)  alloc(256 * 4);
    float* dis      = (float*)alloc(N * 4);
    int*   csr_row  = (int*)  alloc((size_t)E * 4);
    float* csr_norm = (float*)alloc((size_t)E * 4);
    unsigned short* x_hi    = (unsigned short*)alloc((size_t)N_PAD * IN_CH * 2);
    unsigned short* x_lo    = (unsigned short*)alloc((size_t)N_PAD * IN_CH * 2);
    unsigned short* h_hi    = (unsigned short*)alloc((size_t)N_PAD * HID * 2);
    unsigned short* h_lo    = (unsigned short*)alloc((size_t)N_PAD * HID * 2);
    unsigned short* agg1_hi = (unsigned short*)alloc((size_t)N_PAD * HID * 2);
    unsigned short* agg1_lo = (unsigned short*)alloc((size_t)N_PAD * HID * 2);
    // lifetime aliasing: x_hi/x_lo are dead after the feat GEMM; reuse the region
    unsigned short* agg2_hi = x_hi;
    unsigned short* agg2_lo = x_hi + (size_t)N_PAD * HID;
    float*          y       = (float*)x_lo;
    float* sums     = (float*)alloc(HID * 4);
    float* sumsq    = (float*)alloc(HID * 4);
    unsigned short* WTf_hi = (unsigned short*)alloc((size_t)HID * IN_CH * 2);
    unsigned short* WTf_lo = (unsigned short*)alloc((size_t)HID * IN_CH * 2);
    unsigned short* WT0_hi = (unsigned short*)alloc((size_t)HID * 3 * HID * 2);
    unsigned short* WT0_lo = (unsigned short*)alloc((size_t)HID * 3 * HID * 2);
    unsigned short* WT1_hi = (unsigned short*)alloc((size_t)HID * 3 * HID * 2);
    unsigned short* WT1_lo = (unsigned short*)alloc((size_t)HID * 3 * HID * 2);
    unsigned short* WTc_hi = (unsigned short*)alloc((size_t)128 * HID * 2);   // 40 rows padded to 128
    unsigned short* WTc_lo = (unsigned short*)alloc((size_t)128 * HID * 2);

    hipMemsetAsync(deg_row, 0, N * 4, stream);
    hipMemsetAsync(deg_col, 0, N * 4, stream);
    hipMemsetAsync(cursor, 0, N * 4, stream);
    hipMemsetAsync(WTc_hi, 0, (size_t)128 * HID * 2, stream);
    hipMemsetAsync(WTc_lo, 0, (size_t)128 * HID * 2, stream);

    // operand pre-splits (independent of CSR build)
    split_x_kernel<<<(N * IN_CH / 4 + 255) / 256, 256, 0, stream>>>(x, x_hi, x_lo, N * IN_CH / 4);
    dim3 tb(32, 8);
    transpose_split_kernel<<<dim3(HID / 32, IN_CH / 32), tb, 0, stream>>>(W_feat, WTf_hi, WTf_lo, IN_CH, HID);
    transpose_split_kernel<<<dim3(HID / 32, 3 * HID / 32), tb, 0, stream>>>(W0, WT0_hi, WT0_lo, 3 * HID, HID);
    transpose_split_kernel<<<dim3(HID / 32, 3 * HID / 32), tb, 0, stream>>>(W1, WT1_hi, WT1_lo, 3 * HID, HID);
    transpose_split_kernel<<<dim3((OUT_CH + 31) / 32, HID / 32), tb, 0, stream>>>(Wc, WTc_hi, WTc_lo, HID, OUT_CH);

    count_deg_kernel<<<(E + 255) / 256, 256, 0, stream>>>(row, col, deg_row, deg_col, E);
    dis_kernel<<<(N + 255) / 256, 256, 0, stream>>>(deg_row, dis, N);
    const int NB_SCAN = (N + 255) / 256;   // 196
    scan1_kernel<<<NB_SCAN, 256, 0, stream>>>(deg_col, bsums, N);
    scan2_kernel<<<1, 256, 0, stream>>>(bsums, NB_SCAN);
    scan3_kernel<<<NB_SCAN, 256, 0, stream>>>(deg_col, bsums, offsets, N);
    fill_csr_kernel<<<(E + 255) / 256, 256, 0, stream>>>(row, col, dis, offsets, cursor,
                                                         csr_row, csr_norm, E);

    const int NPAN = N_PAD / GBM;          // 392 row-panels
    // h = relu(x @ W_feat + b_feat) -> hi/lo pair
    mfma_gemm_kernel<1, 1, 2><<<NPAN * 2, 256, 0, stream>>>(
        x_hi, x_lo, nullptr, nullptr, nullptr, nullptr, WTf_hi, WTf_lo, b_feat,
        nullptr, h_hi, h_lo, N, IN_CH, IN_CH, HID);

    const unsigned short* WThs[2] = {WT0_hi, WT1_hi};
    const unsigned short* WTls[2] = {WT0_lo, WT1_lo};
    const float* bs[2]    = {b0, b1};
    const float* gs[2]    = {g0, g1};
    const float* betas[2] = {beta0, beta1};
    int prop_grid = (N + 3) / 4;
    for (int layer = 0; layer < 2; ++layer) {
        prop_kernel<<<prop_grid, 256, 0, stream>>>(h_hi, offsets, csr_row, csr_norm,
                                                   agg1_hi, agg1_lo, N);
        prop_kernel<<<prop_grid, 256, 0, stream>>>(agg1_hi, offsets, csr_row, csr_norm,
                                                   agg2_hi, agg2_lo, N);
        mfma_gemm_kernel<0, 0, 2><<<NPAN * 2, 256, 0, stream>>>(
            h_hi, h_lo, agg1_hi, agg1_lo, agg2_hi, agg2_lo, WThs[layer], WTls[layer], bs[layer],
            y, nullptr, nullptr, N, 3 * HID, HID, HID);
        hipMemsetAsync(sums, 0, HID * 4, stream);
        hipMemsetAsync(sumsq, 0, HID * 4, stream);
        colstats_kernel<<<(N + 127) / 128, HID, 0, stream>>>(y, sums, sumsq, N);
        bnrelu_kernel<<<(N * HID / 4 + 255) / 256, 256, 0, stream>>>(y, sums, sumsq, gs[layer],
                                                                     betas[layer], h_hi, h_lo, N);
    }

    mfma_gemm_kernel<0, 0, 1><<<NPAN, 256, 0, stream>>>(
        h_hi, h_lo, nullptr, nullptr, nullptr, nullptr, WTc_hi, WTc_lo, bc,
        out, nullptr, nullptr, N, HID, HID, OUT_CH);
}

// Round 7
// 1113.883 us; speedup vs baseline: 1.5054x; 1.1078x over previous
//
#include <hip/hip_runtime.h>

#define N_NODES 50000
#define N_PAD   50176            // 392 * 128
#define N_EDGES 1600000
#define IN_CH   512
#define HID     256
#define OUT_CH  40
#define BN_EPS  1e-5f

typedef __attribute__((ext_vector_type(8))) short s16x8;
typedef __attribute__((ext_vector_type(8))) unsigned short u16x8;
typedef __attribute__((ext_vector_type(4))) float f32x4;

__device__ __forceinline__ unsigned short f2bf_rne(float f) {
    unsigned u = __float_as_uint(f);
    u += 0x7FFFu + ((u >> 16) & 1u);
    return (unsigned short)(u >> 16);
}
__device__ __forceinline__ float bf2f(unsigned short s) {
    return __uint_as_float((unsigned)s << 16);
}

// async global->LDS, 16B per lane; LDS dest is wave-uniform base + lane*16
__device__ __forceinline__ void gload_lds16(const void* gsrc, void* ldst) {
    __builtin_amdgcn_global_load_lds(
        (const __attribute__((address_space(1))) unsigned int*)gsrc,
        (__attribute__((address_space(3))) unsigned int*)ldst,
        16, 0, 0);
}

// ---------------- degree counting ----------------
__global__ void count_deg_kernel(const int* __restrict__ row, const int* __restrict__ col,
                                 int* __restrict__ deg_row, int* __restrict__ deg_col, int E) {
    int e = blockIdx.x * blockDim.x + threadIdx.x;
    if (e < E) {
        atomicAdd(&deg_row[row[e]], 1);
        atomicAdd(&deg_col[col[e]], 1);
    }
}

__global__ void dis_kernel(const int* __restrict__ deg_row, float* __restrict__ dis, int n) {
    int i = blockIdx.x * blockDim.x + threadIdx.x;
    if (i < n) {
        float d = (float)max(deg_row[i], 1);
        dis[i] = rsqrtf(d);
    }
}

// ---------------- 3-phase exclusive prefix sum ----------------
__global__ void scan1_kernel(const int* __restrict__ deg, int* __restrict__ bsums, int n) {
    __shared__ int sd[256];
    int t = threadIdx.x;
    int i = blockIdx.x * 256 + t;
    sd[t] = (i < n) ? deg[i] : 0;
    __syncthreads();
    for (int o = 128; o > 0; o >>= 1) {
        if (t < o) sd[t] += sd[t + o];
        __syncthreads();
    }
    if (t == 0) bsums[blockIdx.x] = sd[0];
}

__global__ void scan2_kernel(int* __restrict__ bsums, int nb) {   // 1 block, 256 threads
    __shared__ int sd[256];
    int t = threadIdx.x;
    int v = (t < nb) ? bsums[t] : 0;
    sd[t] = v;
    __syncthreads();
    for (int o = 1; o < 256; o <<= 1) {
        int u = (t >= o) ? sd[t - o] : 0;
        __syncthreads();
        sd[t] += u;
        __syncthreads();
    }
    if (t < nb) bsums[t] = sd[t] - v;   // exclusive
}

__global__ void scan3_kernel(const int* __restrict__ deg, const int* __restrict__ bsums,
                             int* __restrict__ offsets, int n) {
    __shared__ int sd[256];
    int t = threadIdx.x;
    int i = blockIdx.x * 256 + t;
    sd[t] = (i < n) ? deg[i] : 0;
    __syncthreads();
    for (int o = 1; o < 256; o <<= 1) {
        int u = (t >= o) ? sd[t - o] : 0;
        __syncthreads();
        sd[t] += u;
        __syncthreads();
    }
    if (i < n) offsets[i + 1] = bsums[blockIdx.x] + sd[t];
    if (i == 0) offsets[0] = 0;
}

// ---------------- CSR fill: single 8B record {src_row, norm_bits} per edge ----------------
__global__ void fill_csr_kernel(const int* __restrict__ row, const int* __restrict__ col,
                                const float* __restrict__ dis, const int* __restrict__ offsets,
                                int* __restrict__ cursor, int2* __restrict__ csr, int E) {
    int e = blockIdx.x * blockDim.x + threadIdx.x;
    if (e < E) {
        int r = row[e], c = col[e];
        int pos = atomicAdd(&cursor[c], 1);
        int idx = offsets[c] + pos;
        float nrm = dis[r] * dis[c];
        csr[idx] = make_int2(r, __float_as_int(nrm));
    }
}

// ---------------- x hi/lo split ----------------
__global__ void split_x_kernel(const float* __restrict__ x, unsigned short* __restrict__ xhi,
                               unsigned short* __restrict__ xlo, int n4) {
    int i = blockIdx.x * blockDim.x + threadIdx.x;
    if (i < n4) {
        float4 v = ((const float4*)x)[i];
        float r[4] = {v.x, v.y, v.z, v.w};
        ushort4 hs, ls;
        unsigned short* hp = (unsigned short*)&hs;
        unsigned short* lp = (unsigned short*)&ls;
        #pragma unroll
        for (int j = 0; j < 4; ++j) {
            unsigned short h = f2bf_rne(r[j]);
            hp[j] = h;
            lp[j] = f2bf_rne(r[j] - bf2f(h));
        }
        ((ushort4*)xhi)[i] = hs;
        ((ushort4*)xlo)[i] = ls;
    }
}

// ---------------- propagation (full-row gather, deep MLP) ----------------
// 1 node per wave; 2 half-waves each gather a full 512B row per edge;
// 4-deep unroll per half -> 8 gathers in flight per wave.
// Half0 writes hi plane, half1 writes lo plane after cross-half reduce.
__global__ void prop_kernel(const unsigned short* __restrict__ hsrc,
                            const int* __restrict__ offsets,
                            const int2* __restrict__ csr,
                            unsigned short* __restrict__ Ohi, unsigned short* __restrict__ Olo,
                            int n) {
    int node = blockIdx.x * 4 + (threadIdx.x >> 6);
    if (node >= n) return;
    int lane = threadIdx.x & 63;
    int half = lane >> 5;
    int cl   = lane & 31;           // 16B chunk id within the 512B row
    int beg = offsets[node], end = offsets[node + 1];
    float acc[8] = {0.f, 0.f, 0.f, 0.f, 0.f, 0.f, 0.f, 0.f};
    for (int i = beg; i < end; i += 8) {
        int ii[4] = {i + half, i + 2 + half, i + 4 + half, i + 6 + half};
        float w[4];
        int s[4];
        #pragma unroll
        for (int u = 0; u < 4; ++u) {
            int2 rec = csr[min(ii[u], end - 1)];
            w[u] = (ii[u] < end) ? __int_as_float(rec.y) : 0.f;
            s[u] = rec.x;
        }
        u16x8 v[4];
        #pragma unroll
        for (int u = 0; u < 4; ++u)
            v[u] = *(const u16x8*)(hsrc + (size_t)s[u] * HID + cl * 8);
        #pragma unroll
        for (int u = 0; u < 4; ++u)
            #pragma unroll
            for (int j = 0; j < 8; ++j)
                acc[j] += w[u] * bf2f((unsigned short)v[u][j]);
    }
    #pragma unroll
    for (int j = 0; j < 8; ++j) acc[j] += __shfl_xor(acc[j], 32);
    u16x8 ov;
    if (half == 0) {
        #pragma unroll
        for (int j = 0; j < 8; ++j) ov[j] = f2bf_rne(acc[j]);
        *(u16x8*)(Ohi + (size_t)node * HID + cl * 8) = ov;
    } else {
        #pragma unroll
        for (int j = 0; j < 8; ++j) {
            unsigned short h = f2bf_rne(acc[j]);
            ov[j] = f2bf_rne(acc[j] - bf2f(h));
        }
        *(u16x8*)(Olo + (size_t)node * HID + cl * 8) = ov;
    }
}

// ---------------- tiled transpose + hi/lo split: src[R][C] -> dst[C][R] bf16 pair ----------------
__global__ void transpose_split_kernel(const float* __restrict__ src,
                                       unsigned short* __restrict__ dhi,
                                       unsigned short* __restrict__ dlo, int R, int C) {
    __shared__ float tile[32][33];
    int c0 = blockIdx.x * 32, r0 = blockIdx.y * 32;
    int tx = threadIdx.x, ty = threadIdx.y;   // block (32, 8)
    #pragma unroll
    for (int i = 0; i < 32; i += 8) {
        int r = r0 + ty + i, c = c0 + tx;
        tile[ty + i][tx] = (r < R && c < C) ? src[(size_t)r * C + c] : 0.f;
    }
    __syncthreads();
    #pragma unroll
    for (int i = 0; i < 32; i += 8) {
        int c = c0 + ty + i, r = r0 + tx;
        if (c < C && r < R) {
            float f = tile[tx][ty + i];
            unsigned short h = f2bf_rne(f);
            dhi[(size_t)c * R + r] = h;
            dlo[(size_t)c * R + r] = f2bf_rne(f - bf2f(h));
        }
    }
}

// ---------------- MFMA GEMM, double-buffered LDS, counted-overlap 2-phase ----------------
#define GBM 128
#define GBN 128
#define GBK 32

// ACT: relu; OUTMODE: 0 = fp32 C, 1 = bf16 hi/lo pair; NC: column blocks; STATS: fused BN colstats
template<int ACT, int OUTMODE, int NC, int STATS>
__global__ __launch_bounds__(256)
void mfma_gemm_kernel(const unsigned short* __restrict__ A0h, const unsigned short* __restrict__ A0l,
                      const unsigned short* __restrict__ A1h, const unsigned short* __restrict__ A1l,
                      const unsigned short* __restrict__ A2h, const unsigned short* __restrict__ A2l,
                      const unsigned short* __restrict__ Wh, const unsigned short* __restrict__ Wl,
                      const float* __restrict__ bvec,
                      float* __restrict__ C, unsigned short* __restrict__ Chi,
                      unsigned short* __restrict__ Clo,
                      float* __restrict__ bn_sums, float* __restrict__ bn_sumsq,
                      int M, int K, int seg, int Kout) {
    // [buf][kgroup(4)][row(128)][8 bf16]; 8KB per plane per buf -> 64KB total
    __shared__ __attribute__((aligned(16))) unsigned short As_hi[2][4 * GBM * 8];
    __shared__ __attribute__((aligned(16))) unsigned short As_lo[2][4 * GBM * 8];
    __shared__ __attribute__((aligned(16))) unsigned short Bs_hi[2][4 * GBN * 8];
    __shared__ __attribute__((aligned(16))) unsigned short Bs_lo[2][4 * GBN * 8];

    int tid  = threadIdx.x;
    int lane = tid & 63;
    int w    = tid >> 6;                   // wave id == the kgroup this wave stages
    int wm   = w & 1, wn = w >> 1;         // 2x2 waves, 64x64 each
    int kg   = lane >> 4, lr = lane & 15;

    int bid = blockIdx.x, p, c;
    if (NC == 2) { p = ((bid >> 4) << 3) + (bid & 7); c = (bid >> 3) & 1; }
    else         { p = bid; c = 0; }
    int bm = p * GBM, bn = c * GBN;

    f32x4 acc[4][4];
    #pragma unroll
    for (int i = 0; i < 4; ++i)
        #pragma unroll
        for (int j = 0; j < 4; ++j)
            acc[i][j] = (f32x4){0.f, 0.f, 0.f, 0.f};

    auto STAGE = [&](int buf, int k0) {
        const unsigned short *Aph, *Apl; int kl0;
        if (k0 < seg)          { Aph = A0h; Apl = A0l; kl0 = k0; }
        else if (k0 < 2 * seg) { Aph = A1h; Apl = A1l; kl0 = k0 - seg; }
        else                   { Aph = A2h; Apl = A2l; kl0 = k0 - 2 * seg; }
        const unsigned short* a_h = Aph + (size_t)(bm + lane) * seg + kl0 + w * 8;
        const unsigned short* a_l = Apl + (size_t)(bm + lane) * seg + kl0 + w * 8;
        const unsigned short* b_h = Wh + (size_t)(bn + lane) * K + k0 + w * 8;
        const unsigned short* b_l = Wl + (size_t)(bn + lane) * K + k0 + w * 8;
        size_t rA = (size_t)64 * seg, rB = (size_t)64 * K;
        gload_lds16(a_h,      &As_hi[buf][(w * 128) * 8]);
        gload_lds16(a_h + rA, &As_hi[buf][(w * 128 + 64) * 8]);
        gload_lds16(a_l,      &As_lo[buf][(w * 128) * 8]);
        gload_lds16(a_l + rA, &As_lo[buf][(w * 128 + 64) * 8]);
        gload_lds16(b_h,      &Bs_hi[buf][(w * 128) * 8]);
        gload_lds16(b_h + rB, &Bs_hi[buf][(w * 128 + 64) * 8]);
        gload_lds16(b_l,      &Bs_lo[buf][(w * 128) * 8]);
        gload_lds16(b_l + rB, &Bs_lo[buf][(w * 128 + 64) * 8]);
    };

    int nt = K / GBK;
    STAGE(0, 0);
    asm volatile("s_waitcnt vmcnt(0)" ::: "memory");
    __builtin_amdgcn_s_barrier();
    __builtin_amdgcn_sched_barrier(0);

    for (int t = 0; t < nt; ++t) {
        int cur = t & 1;
        if (t + 1 < nt) STAGE(cur ^ 1, (t + 1) * GBK);   // overlaps this step's compute

        int abase = (kg * GBM + wm * 64 + lr) * 8;
        int bbase = (kg * GBN + wn * 64 + lr) * 8;
        s16x8 ah[4], al[4], bh[4], bl[4];
        #pragma unroll
        for (int mf = 0; mf < 4; ++mf) {
            ah[mf] = *(const s16x8*)&As_hi[cur][abase + mf * 16 * 8];
            al[mf] = *(const s16x8*)&As_lo[cur][abase + mf * 16 * 8];
        }
        #pragma unroll
        for (int nf = 0; nf < 4; ++nf) {
            bh[nf] = *(const s16x8*)&Bs_hi[cur][bbase + nf * 16 * 8];
            bl[nf] = *(const s16x8*)&Bs_lo[cur][bbase + nf * 16 * 8];
        }
        #pragma unroll
        for (int mf = 0; mf < 4; ++mf)
            #pragma unroll
            for (int nf = 0; nf < 4; ++nf) {
                acc[mf][nf] = __builtin_amdgcn_mfma_f32_16x16x32_bf16(ah[mf], bh[nf], acc[mf][nf], 0, 0, 0);
                acc[mf][nf] = __builtin_amdgcn_mfma_f32_16x16x32_bf16(al[mf], bh[nf], acc[mf][nf], 0, 0, 0);
                acc[mf][nf] = __builtin_amdgcn_mfma_f32_16x16x32_bf16(ah[mf], bl[nf], acc[mf][nf], 0, 0, 0);
            }

        asm volatile("s_waitcnt vmcnt(0)" ::: "memory");  // next tile landed
        __builtin_amdgcn_s_barrier();                     // all reads of buf 'cur' done
        __builtin_amdgcn_sched_barrier(0);
    }

    // ---- epilogue: C/D layout col = lane&15, row = (lane>>4)*4 + reg ----
    #pragma unroll
    for (int nf = 0; nf < 4; ++nf) {
        int col = bn + wn * 64 + nf * 16 + lr;
        if (col >= Kout) continue;
        float bv = bvec[col];
        float s1 = 0.f, s2 = 0.f;
        #pragma unroll
        for (int mf = 0; mf < 4; ++mf) {
            #pragma unroll
            for (int i = 0; i < 4; ++i) {
                int rw = bm + wm * 64 + mf * 16 + kg * 4 + i;
                if (rw < M) {
                    float v = acc[mf][nf][i] + bv;
                    if (ACT == 1) v = fmaxf(v, 0.f);
                    if (STATS) { s1 += v; s2 += v * v; }
                    if (OUTMODE == 0) {
                        C[(size_t)rw * Kout + col] = v;
                    } else {
                        unsigned short hs = f2bf_rne(v);
                        Chi[(size_t)rw * Kout + col] = hs;
                        Clo[(size_t)rw * Kout + col] = f2bf_rne(v - bf2f(hs));
                    }
                }
            }
        }
        if (STATS) {
            s1 += __shfl_xor(s1, 16); s1 += __shfl_xor(s1, 32);
            s2 += __shfl_xor(s2, 16); s2 += __shfl_xor(s2, 32);
            if (kg == 0) {
                atomicAdd(&bn_sums[col], s1);
                atomicAdd(&bn_sumsq[col], s2);
            }
        }
    }
}

__global__ void bnrelu_kernel(const float* __restrict__ y, const float* __restrict__ sums,
                              const float* __restrict__ sumsq, const float* __restrict__ g,
                              const float* __restrict__ beta,
                              unsigned short* __restrict__ Hhi, unsigned short* __restrict__ Hlo,
                              int M) {
    int idx = blockIdx.x * blockDim.x + threadIdx.x;   // group of 4 channels
    if (idx < M * HID / 4) {
        int col0 = (idx * 4) & (HID - 1);
        float4 v = ((const float4*)y)[idx];
        float invM = 1.0f / (float)M;
        float r[4] = {v.x, v.y, v.z, v.w};
        ushort4 hs, ls;
        unsigned short* hp = (unsigned short*)&hs;
        unsigned short* lp = (unsigned short*)&ls;
        #pragma unroll
        for (int j = 0; j < 4; ++j) {
            int col = col0 + j;
            float mean = sums[col] * invM;
            float var  = fmaxf(sumsq[col] * invM - mean * mean, 0.f);
            float o = (r[j] - mean) * rsqrtf(var + BN_EPS) * g[col] + beta[col];
            o = fmaxf(o, 0.f);
            unsigned short h = f2bf_rne(o);
            hp[j] = h;
            lp[j] = f2bf_rne(o - bf2f(h));
        }
        ((ushort4*)Hhi)[idx] = hs;
        ((ushort4*)Hlo)[idx] = ls;
    }
}

extern "C" void kernel_launch(void* const* d_in, const int* in_sizes, int n_in,
                              void* d_out, int out_size, void* d_ws, size_t ws_size,
                              hipStream_t stream) {
    const float* x      = (const float*)d_in[0];
    const int*   ei     = (const int*)d_in[1];
    const float* W_feat = (const float*)d_in[2];
    const float* b_feat = (const float*)d_in[3];
    const float* W0     = (const float*)d_in[4];
    const float* b0     = (const float*)d_in[5];
    const float* g0     = (const float*)d_in[6];
    const float* beta0  = (const float*)d_in[7];
    const float* W1     = (const float*)d_in[8];
    const float* b1     = (const float*)d_in[9];
    const float* g1     = (const float*)d_in[10];
    const float* beta1  = (const float*)d_in[11];
    const float* Wc     = (const float*)d_in[12];
    const float* bc     = (const float*)d_in[13];
    float* out = (float*)d_out;

    const int N = N_NODES, E = N_EDGES;
    const int* row = ei;
    const int* col = ei + E;

    // workspace carve-up
    char* ws = (char*)d_ws;
    size_t off = 0;
    auto alloc = [&](size_t bytes) -> void* {
        void* p = ws + off;
        off = (off + bytes + 255) & ~(size_t)255;
        return p;
    };
    int*   deg_row  = (int*)  alloc(N * 4);
    int*   deg_col  = (int*)  alloc(N * 4);
    int*   cursor   = (int*)  alloc(N * 4);
    int*   offsets  = (int*)  alloc((N + 1) * 4);
    int*   bsums    = (int*)  alloc(256 * 4);
    float* dis      = (float*)alloc(N * 4);
    int2*  csr      = (int2*) alloc((size_t)E * 8);
    unsigned short* x_hi    = (unsigned short*)alloc((size_t)N_PAD * IN_CH * 2);
    unsigned short* x_lo    = (unsigned short*)alloc((size_t)N_PAD * IN_CH * 2);
    unsigned short* h_hi    = (unsigned short*)alloc((size_t)N_PAD * HID * 2);
    unsigned short* h_lo    = (unsigned short*)alloc((size_t)N_PAD * HID * 2);
    unsigned short* agg1_hi = (unsigned short*)alloc((size_t)N_PAD * HID * 2);
    unsigned short* agg1_lo = (unsigned short*)alloc((size_t)N_PAD * HID * 2);
    // lifetime aliasing: x_hi/x_lo are dead after the feat GEMM; reuse the region
    unsigned short* agg2_hi = x_hi;
    unsigned short* agg2_lo = x_hi + (size_t)N_PAD * HID;
    float*          y       = (float*)x_lo;
    float* sums     = (float*)alloc(HID * 4);
    float* sumsq    = (float*)alloc(HID * 4);
    unsigned short* WTf_hi = (unsigned short*)alloc((size_t)HID * IN_CH * 2);
    unsigned short* WTf_lo = (unsigned short*)alloc((size_t)HID * IN_CH * 2);
    unsigned short* WT0_hi = (unsigned short*)alloc((size_t)HID * 3 * HID * 2);
    unsigned short* WT0_lo = (unsigned short*)alloc((size_t)HID * 3 * HID * 2);
    unsigned short* WT1_hi = (unsigned short*)alloc((size_t)HID * 3 * HID * 2);
    unsigned short* WT1_lo = (unsigned short*)alloc((size_t)HID * 3 * HID * 2);
    unsigned short* WTc_hi = (unsigned short*)alloc((size_t)128 * HID * 2);   // 40 rows padded to 128
    unsigned short* WTc_lo = (unsigned short*)alloc((size_t)128 * HID * 2);

    hipMemsetAsync(deg_row, 0, N * 4, stream);
    hipMemsetAsync(deg_col, 0, N * 4, stream);
    hipMemsetAsync(cursor, 0, N * 4, stream);
    hipMemsetAsync(WTc_hi, 0, (size_t)128 * HID * 2, stream);
    hipMemsetAsync(WTc_lo, 0, (size_t)128 * HID * 2, stream);

    // operand pre-splits (independent of CSR build)
    split_x_kernel<<<(N * IN_CH / 4 + 255) / 256, 256, 0, stream>>>(x, x_hi, x_lo, N * IN_CH / 4);
    dim3 tb(32, 8);
    transpose_split_kernel<<<dim3(HID / 32, IN_CH / 32), tb, 0, stream>>>(W_feat, WTf_hi, WTf_lo, IN_CH, HID);
    transpose_split_kernel<<<dim3(HID / 32, 3 * HID / 32), tb, 0, stream>>>(W0, WT0_hi, WT0_lo, 3 * HID, HID);
    transpose_split_kernel<<<dim3(HID / 32, 3 * HID / 32), tb, 0, stream>>>(W1, WT1_hi, WT1_lo, 3 * HID, HID);
    transpose_split_kernel<<<dim3((OUT_CH + 31) / 32, HID / 32), tb, 0, stream>>>(Wc, WTc_hi, WTc_lo, HID, OUT_CH);

    count_deg_kernel<<<(E + 255) / 256, 256, 0, stream>>>(row, col, deg_row, deg_col, E);
    dis_kernel<<<(N + 255) / 256, 256, 0, stream>>>(deg_row, dis, N);
    const int NB_SCAN = (N + 255) / 256;   // 196
    scan1_kernel<<<NB_SCAN, 256, 0, stream>>>(deg_col, bsums, N);
    scan2_kernel<<<1, 256, 0, stream>>>(bsums, NB_SCAN);
    scan3_kernel<<<NB_SCAN, 256, 0, stream>>>(deg_col, bsums, offsets, N);
    fill_csr_kernel<<<(E + 255) / 256, 256, 0, stream>>>(row, col, dis, offsets, cursor,
                                                         csr, E);

    const int NPAN = N_PAD / GBM;          // 392 row-panels
    // h = relu(x @ W_feat + b_feat) -> hi/lo pair
    mfma_gemm_kernel<1, 1, 2, 0><<<NPAN * 2, 256, 0, stream>>>(
        x_hi, x_lo, nullptr, nullptr, nullptr, nullptr, WTf_hi, WTf_lo, b_feat,
        nullptr, h_hi, h_lo, nullptr, nullptr, N, IN_CH, IN_CH, HID);

    const unsigned short* WThs[2] = {WT0_hi, WT1_hi};
    const unsigned short* WTls[2] = {WT0_lo, WT1_lo};
    const float* bs[2]    = {b0, b1};
    const float* gs[2]    = {g0, g1};
    const float* betas[2] = {beta0, beta1};
    int prop_grid = (N + 3) / 4;
    for (int layer = 0; layer < 2; ++layer) {
        prop_kernel<<<prop_grid, 256, 0, stream>>>(h_hi, offsets, csr, agg1_hi, agg1_lo, N);
        prop_kernel<<<prop_grid, 256, 0, stream>>>(agg1_hi, offsets, csr, agg2_hi, agg2_lo, N);
        hipMemsetAsync(sums, 0, HID * 4, stream);
        hipMemsetAsync(sumsq, 0, HID * 4, stream);
        mfma_gemm_kernel<0, 0, 2, 1><<<NPAN * 2, 256, 0, stream>>>(
            h_hi, h_lo, agg1_hi, agg1_lo, agg2_hi, agg2_lo, WThs[layer], WTls[layer], bs[layer],
            y, nullptr, nullptr, sums, sumsq, N, 3 * HID, HID, HID);
        bnrelu_kernel<<<(N * HID / 4 + 255) / 256, 256, 0, stream>>>(y, sums, sumsq, gs[layer],
                                                                     betas[layer], h_hi, h_lo, N);
    }

    mfma_gemm_kernel<0, 0, 1, 0><<<NPAN, 256, 0, stream>>>(
        h_hi, h_lo, nullptr, nullptr, nullptr, nullptr, WTc_hi, WTc_lo, bc,
        out, nullptr, nullptr, nullptr, nullptr, N, HID, HID, OUT_CH);
}

// Round 8
// 1068.393 us; speedup vs baseline: 1.5695x; 1.0426x over previous
//
#include <hip/hip_runtime.h>

#define N_NODES 50000
#define N_PAD   50176            // 392 * 128
#define N_EDGES 1600000
#define IN_CH   512
#define HID     256
#define OUT_C H_UNUSED 0
#undef N_PAD
#define N_PAD   50176
#define OUT_CH  40
#define BN_EPS  1e-5f

typedef _Float16 f16x8 __attribute__((ext_vector_type(8)));
typedef __attribute__((ext_vector_type(8))) unsigned short u16x8;
typedef __attribute__((ext_vector_type(4))) float f32x4;

__device__ __forceinline__ unsigned short f2h_us(float f) {
    _Float16 h = (_Float16)f;
    return __builtin_bit_cast(unsigned short, h);
}
__device__ __forceinline__ float h2f(unsigned short u) {
    return (float)__builtin_bit_cast(_Float16, u);
}
// split f into fp16 hi + fp16 lo (residual; exact subtraction in fp32)
__device__ __forceinline__ void f2h_split(float f, unsigned short& hi, unsigned short& lo) {
    _Float16 h = (_Float16)f;
    hi = __builtin_bit_cast(unsigned short, h);
    lo = f2h_us(f - (float)h);
}

// async global->LDS, 16B per lane; LDS dest is wave-uniform base + lane*16
__device__ __forceinline__ void gload_lds16(const void* gsrc, void* ldst) {
    __builtin_amdgcn_global_load_lds(
        (const __attribute__((address_space(1))) unsigned int*)gsrc,
        (__attribute__((address_space(3))) unsigned int*)ldst,
        16, 0, 0);
}

// ---------------- degree counting ----------------
__global__ void count_deg_kernel(const int* __restrict__ row, const int* __restrict__ col,
                                 int* __restrict__ deg_row, int* __restrict__ deg_col, int E) {
    int e = blockIdx.x * blockDim.x + threadIdx.x;
    if (e < E) {
        atomicAdd(&deg_row[row[e]], 1);
        atomicAdd(&deg_col[col[e]], 1);
    }
}

__global__ void dis_kernel(const int* __restrict__ deg_row, float* __restrict__ dis, int n) {
    int i = blockIdx.x * blockDim.x + threadIdx.x;
    if (i < n) {
        float d = (float)max(deg_row[i], 1);
        dis[i] = rsqrtf(d);
    }
}

// ---------------- 3-phase exclusive prefix sum ----------------
__global__ void scan1_kernel(const int* __restrict__ deg, int* __restrict__ bsums, int n) {
    __shared__ int sd[256];
    int t = threadIdx.x;
    int i = blockIdx.x * 256 + t;
    sd[t] = (i < n) ? deg[i] : 0;
    __syncthreads();
    for (int o = 128; o > 0; o >>= 1) {
        if (t < o) sd[t] += sd[t + o];
        __syncthreads();
    }
    if (t == 0) bsums[blockIdx.x] = sd[0];
}

__global__ void scan2_kernel(int* __restrict__ bsums, int nb) {   // 1 block, 256 threads
    __shared__ int sd[256];
    int t = threadIdx.x;
    int v = (t < nb) ? bsums[t] : 0;
    sd[t] = v;
    __syncthreads();
    for (int o = 1; o < 256; o <<= 1) {
        int u = (t >= o) ? sd[t - o] : 0;
        __syncthreads();
        sd[t] += u;
        __syncthreads();
    }
    if (t < nb) bsums[t] = sd[t] - v;   // exclusive
}

__global__ void scan3_kernel(const int* __restrict__ deg, const int* __restrict__ bsums,
                             int* __restrict__ offsets, int n) {
    __shared__ int sd[256];
    int t = threadIdx.x;
    int i = blockIdx.x * 256 + t;
    sd[t] = (i < n) ? deg[i] : 0;
    __syncthreads();
    for (int o = 1; o < 256; o <<= 1) {
        int u = (t >= o) ? sd[t - o] : 0;
        __syncthreads();
        sd[t] += u;
        __syncthreads();
    }
    if (i < n) offsets[i + 1] = bsums[blockIdx.x] + sd[t];
    if (i == 0) offsets[0] = 0;
}

// ---------------- CSR fill: single 8B record {src_row, norm_bits} per edge ----------------
__global__ void fill_csr_kernel(const int* __restrict__ row, const int* __restrict__ col,
                                const float* __restrict__ dis, const int* __restrict__ offsets,
                                int* __restrict__ cursor, int2* __restrict__ csr, int E) {
    int e = blockIdx.x * blockDim.x + threadIdx.x;
    if (e < E) {
        int r = row[e], c = col[e];
        int pos = atomicAdd(&cursor[c], 1);
        int idx = offsets[c] + pos;
        float nrm = dis[r] * dis[c];
        csr[idx] = make_int2(r, __float_as_int(nrm));
    }
}

// ---------------- x hi/lo split (fp16) ----------------
__global__ void split_x_kernel(const float* __restrict__ x, unsigned short* __restrict__ xhi,
                               unsigned short* __restrict__ xlo, int n4) {
    int i = blockIdx.x * blockDim.x + threadIdx.x;
    if (i < n4) {
        float4 v = ((const float4*)x)[i];
        float r[4] = {v.x, v.y, v.z, v.w};
        ushort4 hs, ls;
        unsigned short* hp = (unsigned short*)&hs;
        unsigned short* lp = (unsigned short*)&ls;
        #pragma unroll
        for (int j = 0; j < 4; ++j) f2h_split(r[j], hp[j], lp[j]);
        ((ushort4*)xhi)[i] = hs;
        ((ushort4*)xlo)[i] = ls;
    }
}

// ---------------- propagation (full-row fp16 gather, deep MLP) ----------------
__global__ void prop_kernel(const unsigned short* __restrict__ hsrc,
                            const int* __restrict__ offsets,
                            const int2* __restrict__ csr,
                            unsigned short* __restrict__ Ohi, unsigned short* __restrict__ Olo,
                            int n) {
    int node = blockIdx.x * 4 + (threadIdx.x >> 6);
    if (node >= n) return;
    int lane = threadIdx.x & 63;
    int half = lane >> 5;
    int cl   = lane & 31;           // 16B chunk id within the 512B row
    int beg = offsets[node], end = offsets[node + 1];
    float acc[8] = {0.f, 0.f, 0.f, 0.f, 0.f, 0.f, 0.f, 0.f};
    for (int i = beg; i < end; i += 8) {
        int ii[4] = {i + half, i + 2 + half, i + 4 + half, i + 6 + half};
        float w[4];
        int s[4];
        #pragma unroll
        for (int u = 0; u < 4; ++u) {
            int2 rec = csr[min(ii[u], end - 1)];
            w[u] = (ii[u] < end) ? __int_as_float(rec.y) : 0.f;
            s[u] = rec.x;
        }
        u16x8 v[4];
        #pragma unroll
        for (int u = 0; u < 4; ++u)
            v[u] = *(const u16x8*)(hsrc + (size_t)s[u] * HID + cl * 8);
        #pragma unroll
        for (int u = 0; u < 4; ++u)
            #pragma unroll
            for (int j = 0; j < 8; ++j)
                acc[j] += w[u] * h2f((unsigned short)v[u][j]);
    }
    #pragma unroll
    for (int j = 0; j < 8; ++j) acc[j] += __shfl_xor(acc[j], 32);
    u16x8 ov;
    if (half == 0) {
        #pragma unroll
        for (int j = 0; j < 8; ++j) ov[j] = f2h_us(acc[j]);
        *(u16x8*)(Ohi + (size_t)node * HID + cl * 8) = ov;
    } else {
        #pragma unroll
        for (int j = 0; j < 8; ++j) {
            unsigned short h, l;
            f2h_split(acc[j], h, l);
            ov[j] = l;
        }
        *(u16x8*)(Olo + (size_t)node * HID + cl * 8) = ov;
    }
}

// ---------------- tiled transpose -> single fp16 plane: src[R][C] -> dst[C][R] ----------------
__global__ void transpose_half_kernel(const float* __restrict__ src,
                                      unsigned short* __restrict__ dhi, int R, int C) {
    __shared__ float tile[32][33];
    int c0 = blockIdx.x * 32, r0 = blockIdx.y * 32;
    int tx = threadIdx.x, ty = threadIdx.y;   // block (32, 8)
    #pragma unroll
    for (int i = 0; i < 32; i += 8) {
        int r = r0 + ty + i, c = c0 + tx;
        tile[ty + i][tx] = (r < R && c < C) ? src[(size_t)r * C + c] : 0.f;
    }
    __syncthreads();
    #pragma unroll
    for (int i = 0; i < 32; i += 8) {
        int c = c0 + ty + i, r = r0 + tx;
        if (c < C && r < R) dhi[(size_t)c * R + r] = f2h_us(tile[tx][ty + i]);
    }
}

// ---------------- MFMA GEMM (fp16): A hi/lo x W hi -> 2 MFMAs per pair ----------------
#define GBM 128
#define GBN 128
#define GBK 32

// ACT: relu; OUTMODE: 0 = fp32 C, 1 = fp16 hi/lo pair; NC: column blocks; STATS: fused BN colstats
template<int ACT, int OUTMODE, int NC, int STATS>
__global__ __launch_bounds__(256)
void mfma_gemm_kernel(const unsigned short* __restrict__ A0h, const unsigned short* __restrict__ A0l,
                      const unsigned short* __restrict__ A1h, const unsigned short* __restrict__ A1l,
                      const unsigned short* __restrict__ A2h, const unsigned short* __restrict__ A2l,
                      const unsigned short* __restrict__ Wh,
                      const float* __restrict__ bvec,
                      float* __restrict__ C, unsigned short* __restrict__ Chi,
                      unsigned short* __restrict__ Clo,
                      float* __restrict__ bn_sums, float* __restrict__ bn_sumsq,
                      int M, int K, int seg, int Kout) {
    // [buf][kgroup(4)][row(128)][8 f16]; 8KB per plane per buf -> 48KB total
    __shared__ __attribute__((aligned(16))) unsigned short As_hi[2][4 * GBM * 8];
    __shared__ __attribute__((aligned(16))) unsigned short As_lo[2][4 * GBM * 8];
    __shared__ __attribute__((aligned(16))) unsigned short Bs_hi[2][4 * GBN * 8];

    int tid  = threadIdx.x;
    int lane = tid & 63;
    int w    = tid >> 6;                   // wave id == the kgroup this wave stages
    int wm   = w & 1, wn = w >> 1;         // 2x2 waves, 64x64 each
    int kg   = lane >> 4, lr = lane & 15;

    int bid = blockIdx.x, p, c;
    if (NC == 2) { p = ((bid >> 4) << 3) + (bid & 7); c = (bid >> 3) & 1; }
    else         { p = bid; c = 0; }
    int bm = p * GBM, bn = c * GBN;

    f32x4 acc[4][4];
    #pragma unroll
    for (int i = 0; i < 4; ++i)
        #pragma unroll
        for (int j = 0; j < 4; ++j)
            acc[i][j] = (f32x4){0.f, 0.f, 0.f, 0.f};

    auto STAGE = [&](int buf, int k0) {
        const unsigned short *Aph, *Apl; int kl0;
        if (k0 < seg)          { Aph = A0h; Apl = A0l; kl0 = k0; }
        else if (k0 < 2 * seg) { Aph = A1h; Apl = A1l; kl0 = k0 - seg; }
        else                   { Aph = A2h; Apl = A2l; kl0 = k0 - 2 * seg; }
        const unsigned short* a_h = Aph + (size_t)(bm + lane) * seg + kl0 + w * 8;
        const unsigned short* a_l = Apl + (size_t)(bm + lane) * seg + kl0 + w * 8;
        const unsigned short* b_h = Wh + (size_t)(bn + lane) * K + k0 + w * 8;
        size_t rA = (size_t)64 * seg, rB = (size_t)64 * K;
        gload_lds16(a_h,      &As_hi[buf][(w * 128) * 8]);
        gload_lds16(a_h + rA, &As_hi[buf][(w * 128 + 64) * 8]);
        gload_lds16(a_l,      &As_lo[buf][(w * 128) * 8]);
        gload_lds16(a_l + rA, &As_lo[buf][(w * 128 + 64) * 8]);
        gload_lds16(b_h,      &Bs_hi[buf][(w * 128) * 8]);
        gload_lds16(b_h + rB, &Bs_hi[buf][(w * 128 + 64) * 8]);
    };

    int nt = K / GBK;
    STAGE(0, 0);
    asm volatile("s_waitcnt vmcnt(0)" ::: "memory");
    __builtin_amdgcn_s_barrier();
    __builtin_amdgcn_sched_barrier(0);

    for (int t = 0; t < nt; ++t) {
        int cur = t & 1;
        if (t + 1 < nt) STAGE(cur ^ 1, (t + 1) * GBK);   // overlaps this step's compute

        int abase = (kg * GBM + wm * 64 + lr) * 8;
        int bbase = (kg * GBN + wn * 64 + lr) * 8;
        f16x8 ah[4], al[4], bh[4];
        #pragma unroll
        for (int mf = 0; mf < 4; ++mf) {
            ah[mf] = *(const f16x8*)&As_hi[cur][abase + mf * 16 * 8];
            al[mf] = *(const f16x8*)&As_lo[cur][abase + mf * 16 * 8];
        }
        #pragma unroll
        for (int nf = 0; nf < 4; ++nf)
            bh[nf] = *(const f16x8*)&Bs_hi[cur][bbase + nf * 16 * 8];
        #pragma unroll
        for (int mf = 0; mf < 4; ++mf)
            #pragma unroll
            for (int nf = 0; nf < 4; ++nf) {
                acc[mf][nf] = __builtin_amdgcn_mfma_f32_16x16x32_f16(ah[mf], bh[nf], acc[mf][nf], 0, 0, 0);
                acc[mf][nf] = __builtin_amdgcn_mfma_f32_16x16x32_f16(al[mf], bh[nf], acc[mf][nf], 0, 0, 0);
            }

        asm volatile("s_waitcnt vmcnt(0)" ::: "memory");  // next tile landed
        __builtin_amdgcn_s_barrier();                     // all reads of buf 'cur' done
        __builtin_amdgcn_sched_barrier(0);
    }

    // ---- epilogue: C/D layout col = lane&15, row = (lane>>4)*4 + reg ----
    #pragma unroll
    for (int nf = 0; nf < 4; ++nf) {
        int col = bn + wn * 64 + nf * 16 + lr;
        if (col >= Kout) continue;
        float bv = bvec[col];
        float s1 = 0.f, s2 = 0.f;
        #pragma unroll
        for (int mf = 0; mf < 4; ++mf) {
            #pragma unroll
            for (int i = 0; i < 4; ++i) {
                int rw = bm + wm * 64 + mf * 16 + kg * 4 + i;
                if (rw < M) {
                    float v = acc[mf][nf][i] + bv;
                    if (ACT == 1) v = fmaxf(v, 0.f);
                    if (STATS) { s1 += v; s2 += v * v; }
                    if (OUTMODE == 0) {
                        C[(size_t)rw * Kout + col] = v;
                    } else {
                        unsigned short hs, ls;
                        f2h_split(v, hs, ls);
                        Chi[(size_t)rw * Kout + col] = hs;
                        Clo[(size_t)rw * Kout + col] = ls;
                    }
                }
            }
        }
        if (STATS) {
            s1 += __shfl_xor(s1, 16); s1 += __shfl_xor(s1, 32);
            s2 += __shfl_xor(s2, 16); s2 += __shfl_xor(s2, 32);
            if (kg == 0) {
                atomicAdd(&bn_sums[col], s1);
                atomicAdd(&bn_sumsq[col], s2);
            }
        }
    }
}

__global__ void bnrelu_kernel(const float* __restrict__ y, const float* __restrict__ sums,
                              const float* __restrict__ sumsq, const float* __restrict__ g,
                              const float* __restrict__ beta,
                              unsigned short* __restrict__ Hhi, unsigned short* __restrict__ Hlo,
                              int M) {
    int idx = blockIdx.x * blockDim.x + threadIdx.x;   // group of 4 channels
    if (idx < M * HID / 4) {
        int col0 = (idx * 4) & (HID - 1);
        float4 v = ((const float4*)y)[idx];
        float invM = 1.0f / (float)M;
        float r[4] = {v.x, v.y, v.z, v.w};
        ushort4 hs, ls;
        unsigned short* hp = (unsigned short*)&hs;
        unsigned short* lp = (unsigned short*)&ls;
        #pragma unroll
        for (int j = 0; j < 4; ++j) {
            int col = col0 + j;
            float mean = sums[col] * invM;
            float var  = fmaxf(sumsq[col] * invM - mean * mean, 0.f);
            float o = (r[j] - mean) * rsqrtf(var + BN_EPS) * g[col] + beta[col];
            o = fmaxf(o, 0.f);
            f2h_split(o, hp[j], lp[j]);
        }
        ((ushort4*)Hhi)[idx] = hs;
        ((ushort4*)Hlo)[idx] = ls;
    }
}

extern "C" void kernel_launch(void* const* d_in, const int* in_sizes, int n_in,
                              void* d_out, int out_size, void* d_ws, size_t ws_size,
                              hipStream_t stream) {
    const float* x      = (const float*)d_in[0];
    const int*   ei     = (const int*)d_in[1];
    const float* W_feat = (const float*)d_in[2];
    const float* b_feat = (const float*)d_in[3];
    const float* W0     = (const float*)d_in[4];
    const float* b0     = (const float*)d_in[5];
    const float* g0     = (const float*)d_in[6];
    const float* beta0  = (const float*)d_in[7];
    const float* W1     = (const float*)d_in[8];
    const float* b1     = (const float*)d_in[9];
    const float* g1     = (const float*)d_in[10];
    const float* beta1  = (const float*)d_in[11];
    const float* Wc     = (const float*)d_in[12];
    const float* bc     = (const float*)d_in[13];
    float* out = (float*)d_out;

    const int N = N_NODES, E = N_EDGES;
    const int* row = ei;
    const int* col = ei + E;

    // workspace carve-up
    char* ws = (char*)d_ws;
    size_t off = 0;
    auto alloc = [&](size_t bytes) -> void* {
        void* p = ws + off;
        off = (off + bytes + 255) & ~(size_t)255;
        return p;
    };
    int*   deg_row  = (int*)  alloc(N * 4);
    int*   deg_col  = (int*)  alloc(N * 4);
    int*   cursor   = (int*)  alloc(N * 4);
    int*   offsets  = (int*)  alloc((N + 1) * 4);
    int*   bsums    = (int*)  alloc(256 * 4);
    float* dis      = (float*)alloc(N * 4);
    int2*  csr      = (int2*) alloc((size_t)E * 8);
    unsigned short* x_hi    = (unsigned short*)alloc((size_t)N_PAD * IN_CH * 2);
    unsigned short* x_lo    = (unsigned short*)alloc((size_t)N_PAD * IN_CH * 2);
    unsigned short* h_hi    = (unsigned short*)alloc((size_t)N_PAD * HID * 2);
    unsigned short* h_lo    = (unsigned short*)alloc((size_t)N_PAD * HID * 2);
    unsigned short* agg1_hi = (unsigned short*)alloc((size_t)N_PAD * HID * 2);
    unsigned short* agg1_lo = (unsigned short*)alloc((size_t)N_PAD * HID * 2);
    // lifetime aliasing: x_hi/x_lo are dead after the feat GEMM; reuse the region
    unsigned short* agg2_hi = x_hi;
    unsigned short* agg2_lo = x_hi + (size_t)N_PAD * HID;
    float*          y       = (float*)x_lo;
    float* sums     = (float*)alloc(HID * 4);
    float* sumsq    = (float*)alloc(HID * 4);
    unsigned short* WTf_hi = (unsigned short*)alloc((size_t)HID * IN_CH * 2);
    unsigned short* WT0_hi = (unsigned short*)alloc((size_t)HID * 3 * HID * 2);
    unsigned short* WT1_hi = (unsigned short*)alloc((size_t)HID * 3 * HID * 2);
    unsigned short* WTc_hi = (unsigned short*)alloc((size_t)128 * HID * 2);   // 40 rows padded to 128

    hipMemsetAsync(deg_row, 0, N * 4, stream);
    hipMemsetAsync(deg_col, 0, N * 4, stream);
    hipMemsetAsync(cursor, 0, N * 4, stream);
    hipMemsetAsync(WTc_hi, 0, (size_t)128 * HID * 2, stream);

    // operand pre-splits (independent of CSR build)
    split_x_kernel<<<(N * IN_CH / 4 + 255) / 256, 256, 0, stream>>>(x, x_hi, x_lo, N * IN_CH / 4);
    dim3 tb(32, 8);
    transpose_half_kernel<<<dim3(HID / 32, IN_CH / 32), tb, 0, stream>>>(W_feat, WTf_hi, IN_CH, HID);
    transpose_half_kernel<<<dim3(HID / 32, 3 * HID / 32), tb, 0, stream>>>(W0, WT0_hi, 3 * HID, HID);
    transpose_half_kernel<<<dim3(HID / 32, 3 * HID / 32), tb, 0, stream>>>(W1, WT1_hi, 3 * HID, HID);
    transpose_half_kernel<<<dim3((OUT_CH + 31) / 32, HID / 32), tb, 0, stream>>>(Wc, WTc_hi, HID, OUT_CH);

    count_deg_kernel<<<(E + 255) / 256, 256, 0, stream>>>(row, col, deg_row, deg_col, E);
    dis_kernel<<<(N + 255) / 256, 256, 0, stream>>>(deg_row, dis, N);
    const int NB_SCAN = (N + 255) / 256;   // 196
    scan1_kernel<<<NB_SCAN, 256, 0, stream>>>(deg_col, bsums, N);
    scan2_kernel<<<1, 256, 0, stream>>>(bsums, NB_SCAN);
    scan3_kernel<<<NB_SCAN, 256, 0, stream>>>(deg_col, bsums, offsets, N);
    fill_csr_kernel<<<(E + 255) / 256, 256, 0, stream>>>(row, col, dis, offsets, cursor,
                                                         csr, E);

    const int NPAN = N_PAD / GBM;          // 392 row-panels
    // h = relu(x @ W_feat + b_feat) -> fp16 hi/lo pair
    mfma_gemm_kernel<1, 1, 2, 0><<<NPAN * 2, 256, 0, stream>>>(
        x_hi, x_lo, nullptr, nullptr, nullptr, nullptr, WTf_hi, b_feat,
        nullptr, h_hi, h_lo, nullptr, nullptr, N, IN_CH, IN_CH, HID);

    const unsigned short* WThs[2] = {WT0_hi, WT1_hi};
    const float* bs[2]    = {b0, b1};
    const float* gs[2]    = {g0, g1};
    const float* betas[2] = {beta0, beta1};
    int prop_grid = (N + 3) / 4;
    for (int layer = 0; layer < 2; ++layer) {
        prop_kernel<<<prop_grid, 256, 0, stream>>>(h_hi, offsets, csr, agg1_hi, agg1_lo, N);
        prop_kernel<<<prop_grid, 256, 0, stream>>>(agg1_hi, offsets, csr, agg2_hi, agg2_lo, N);
        hipMemsetAsync(sums, 0, HID * 4, stream);
        hipMemsetAsync(sumsq, 0, HID * 4, stream);
        mfma_gemm_kernel<0, 0, 2, 1><<<NPAN * 2, 256, 0, stream>>>(
            h_hi, h_lo, agg1_hi, agg1_lo, agg2_hi, agg2_lo, WThs[layer], bs[layer],
            y, nullptr, nullptr, sums, sumsq, N, 3 * HID, HID, HID);
        bnrelu_kernel<<<(N * HID / 4 + 255) / 256, 256, 0, stream>>>(y, sums, sumsq, gs[layer],
                                                                     betas[layer], h_hi, h_lo, N);
    }

    mfma_gemm_kernel<0, 0, 1, 0><<<NPAN, 256, 0, stream>>>(
        h_hi, h_lo, nullptr, nullptr, nullptr, nullptr, WTc_hi, bc,
        out, nullptr, nullptr, nullptr, nullptr, N, HID, HID, OUT_CH);
}

// Round 9
// 1044.995 us; speedup vs baseline: 1.6047x; 1.0224x over previous
//
#include <hip/hip_runtime.h>

#define N_NODES 50000
#define N_PAD   50176            // 392 * 128 = 8 * 6272
#define N_EDGES 1600000
#define IN_CH   512
#define HID     256
#define OUT_CH  40
#define BN_EPS  1e-5f

#define HCHUNK  6272             // nodes per histogram chunk (8 chunks cover N_PAD)
#define NCHUNK  8
#define NSLICE  32               // edge slices; E/NSLICE = 50000 exactly

typedef _Float16 f16x8 __attribute__((ext_vector_type(8)));
typedef __attribute__((ext_vector_type(8))) unsigned short u16x8;
typedef __attribute__((ext_vector_type(4))) float f32x4;

__device__ __forceinline__ unsigned short f2h_us(float f) {
    _Float16 h = (_Float16)f;
    return __builtin_bit_cast(unsigned short, h);
}
__device__ __forceinline__ float h2f(unsigned short u) {
    return (float)__builtin_bit_cast(_Float16, u);
}
// split f into fp16 hi + fp16 lo (residual; exact subtraction in fp32)
__device__ __forceinline__ void f2h_split(float f, unsigned short& hi, unsigned short& lo) {
    _Float16 h = (_Float16)f;
    hi = __builtin_bit_cast(unsigned short, h);
    lo = f2h_us(f - (float)h);
}

// async global->LDS, 16B per lane; LDS dest is wave-uniform base + lane*16
__device__ __forceinline__ void gload_lds16(const void* gsrc, void* ldst) {
    __builtin_amdgcn_global_load_lds(
        (const __attribute__((address_space(1))) unsigned int*)gsrc,
        (__attribute__((address_space(3))) unsigned int*)ldst,
        16, 0, 0);
}

// ---------------- degree histograms via LDS privatization (no global atomics) ----------------
__global__ __launch_bounds__(256)
void hist_kernel(const int* __restrict__ row, const int* __restrict__ col,
                 int* __restrict__ part_row, int* __restrict__ part_col, int E) {
    __shared__ int hr[HCHUNK];
    __shared__ int hc[HCHUNK];
    int s = blockIdx.x;        // edge slice
    int c = blockIdx.y;        // node chunk
    int base = c * HCHUNK;
    int t = threadIdx.x;
    for (int i = t; i < HCHUNK; i += 256) { hr[i] = 0; hc[i] = 0; }
    __syncthreads();
    int e0 = s * (E / NSLICE), e1 = e0 + E / NSLICE;
    for (int e = e0 + t; e < e1; e += 256) {
        int r = row[e], cc = col[e];
        unsigned lr = (unsigned)(r - base);
        unsigned lc = (unsigned)(cc - base);
        if (lr < HCHUNK) atomicAdd(&hr[lr], 1);
        if (lc < HCHUNK) atomicAdd(&hc[lc], 1);
    }
    __syncthreads();
    int* pr = part_row + (size_t)s * N_PAD + base;
    int* pc = part_col + (size_t)s * N_PAD + base;
    for (int i = t; i < HCHUNK; i += 256) { pr[i] = hr[i]; pc[i] = hc[i]; }
}

__global__ void merge_deg_kernel(const int* __restrict__ part_row, const int* __restrict__ part_col,
                                 float* __restrict__ dis, int* __restrict__ deg_col, int n) {
    int i = blockIdx.x * blockDim.x + threadIdx.x;
    if (i < n) {
        int dr = 0, dc = 0;
        #pragma unroll
        for (int s = 0; s < NSLICE; ++s) {
            dr += part_row[(size_t)s * N_PAD + i];
            dc += part_col[(size_t)s * N_PAD + i];
        }
        dis[i] = rsqrtf((float)max(dr, 1));
        deg_col[i] = dc;
    }
}

// ---------------- 3-phase exclusive prefix sum ----------------
__global__ void scan1_kernel(const int* __restrict__ deg, int* __restrict__ bsums, int n) {
    __shared__ int sd[256];
    int t = threadIdx.x;
    int i = blockIdx.x * 256 + t;
    sd[t] = (i < n) ? deg[i] : 0;
    __syncthreads();
    for (int o = 128; o > 0; o >>= 1) {
        if (t < o) sd[t] += sd[t + o];
        __syncthreads();
    }
    if (t == 0) bsums[blockIdx.x] = sd[0];
}

__global__ void scan2_kernel(int* __restrict__ bsums, int nb) {   // 1 block, 256 threads
    __shared__ int sd[256];
    int t = threadIdx.x;
    int v = (t < nb) ? bsums[t] : 0;
    sd[t] = v;
    __syncthreads();
    for (int o = 1; o < 256; o <<= 1) {
        int u = (t >= o) ? sd[t - o] : 0;
        __syncthreads();
        sd[t] += u;
        __syncthreads();
    }
    if (t < nb) bsums[t] = sd[t] - v;   // exclusive
}

__global__ void scan3_kernel(const int* __restrict__ deg, const int* __restrict__ bsums,
                             int* __restrict__ offsets, int n) {
    __shared__ int sd[256];
    int t = threadIdx.x;
    int i = blockIdx.x * 256 + t;
    sd[t] = (i < n) ? deg[i] : 0;
    __syncthreads();
    for (int o = 1; o < 256; o <<= 1) {
        int u = (t >= o) ? sd[t - o] : 0;
        __syncthreads();
        sd[t] += u;
        __syncthreads();
    }
    if (i < n) offsets[i + 1] = bsums[blockIdx.x] + sd[t];
    if (i == 0) offsets[0] = 0;
}

// ---------------- CSR fill: single 8B record {src_row, norm_bits} per edge ----------------
__global__ void fill_csr_kernel(const int* __restrict__ row, const int* __restrict__ col,
                                const float* __restrict__ dis, const int* __restrict__ offsets,
                                int* __restrict__ cursor, int2* __restrict__ csr, int E) {
    int e = blockIdx.x * blockDim.x + threadIdx.x;
    if (e < E) {
        int r = row[e], c = col[e];
        int pos = atomicAdd(&cursor[c], 1);
        int idx = offsets[c] + pos;
        float nrm = dis[r] * dis[c];
        csr[idx] = make_int2(r, __float_as_int(nrm));
    }
}

// ---------------- x hi/lo split (fp16) ----------------
__global__ void split_x_kernel(const float* __restrict__ x, unsigned short* __restrict__ xhi,
                               unsigned short* __restrict__ xlo, int n4) {
    int i = blockIdx.x * blockDim.x + threadIdx.x;
    if (i < n4) {
        float4 v = ((const float4*)x)[i];
        float r[4] = {v.x, v.y, v.z, v.w};
        ushort4 hs, ls;
        unsigned short* hp = (unsigned short*)&hs;
        unsigned short* lp = (unsigned short*)&ls;
        #pragma unroll
        for (int j = 0; j < 4; ++j) f2h_split(r[j], hp[j], lp[j]);
        ((ushort4*)xhi)[i] = hs;
        ((ushort4*)xlo)[i] = ls;
    }
}

// ---------------- propagation (full-row fp16 gather, deep MLP) ----------------
__global__ void prop_kernel(const unsigned short* __restrict__ hsrc,
                            const int* __restrict__ offsets,
                            const int2* __restrict__ csr,
                            unsigned short* __restrict__ Ohi, unsigned short* __restrict__ Olo,
                            int n) {
    int node = blockIdx.x * 4 + (threadIdx.x >> 6);
    if (node >= n) return;
    int lane = threadIdx.x & 63;
    int half = lane >> 5;
    int cl   = lane & 31;           // 16B chunk id within the 512B row
    int beg = offsets[node], end = offsets[node + 1];
    float acc[8] = {0.f, 0.f, 0.f, 0.f, 0.f, 0.f, 0.f, 0.f};
    for (int i = beg; i < end; i += 8) {
        int ii[4] = {i + half, i + 2 + half, i + 4 + half, i + 6 + half};
        float w[4];
        int s[4];
        #pragma unroll
        for (int u = 0; u < 4; ++u) {
            int2 rec = csr[min(ii[u], end - 1)];
            w[u] = (ii[u] < end) ? __int_as_float(rec.y) : 0.f;
            s[u] = rec.x;
        }
        u16x8 v[4];
        #pragma unroll
        for (int u = 0; u < 4; ++u)
            v[u] = *(const u16x8*)(hsrc + (size_t)s[u] * HID + cl * 8);
        #pragma unroll
        for (int u = 0; u < 4; ++u)
            #pragma unroll
            for (int j = 0; j < 8; ++j)
                acc[j] += w[u] * h2f((unsigned short)v[u][j]);
    }
    #pragma unroll
    for (int j = 0; j < 8; ++j) acc[j] += __shfl_xor(acc[j], 32);
    u16x8 ov;
    if (half == 0) {
        #pragma unroll
        for (int j = 0; j < 8; ++j) ov[j] = f2h_us(acc[j]);
        *(u16x8*)(Ohi + (size_t)node * HID + cl * 8) = ov;
    } else {
        #pragma unroll
        for (int j = 0; j < 8; ++j) {
            unsigned short h, l;
            f2h_split(acc[j], h, l);
            ov[j] = l;
        }
        *(u16x8*)(Olo + (size_t)node * HID + cl * 8) = ov;
    }
}

// ---------------- tiled transpose -> single fp16 plane: src[R][C] -> dst[C][R] ----------------
__global__ void transpose_half_kernel(const float* __restrict__ src,
                                      unsigned short* __restrict__ dhi, int R, int C) {
    __shared__ float tile[32][33];
    int c0 = blockIdx.x * 32, r0 = blockIdx.y * 32;
    int tx = threadIdx.x, ty = threadIdx.y;   // block (32, 8)
    #pragma unroll
    for (int i = 0; i < 32; i += 8) {
        int r = r0 + ty + i, c = c0 + tx;
        tile[ty + i][tx] = (r < R && c < C) ? src[(size_t)r * C + c] : 0.f;
    }
    __syncthreads();
    #pragma unroll
    for (int i = 0; i < 32; i += 8) {
        int c = c0 + ty + i, r = r0 + tx;
        if (c < C && r < R) dhi[(size_t)c * R + r] = f2h_us(tile[tx][ty + i]);
    }
}

// ---------------- MFMA GEMM (fp16): A hi/lo x W hi -> 2 MFMAs per pair ----------------
#define GBM 128
#define GBN 128
#define GBK 32

// ACT: relu; OUTMODE: 0 = fp32 C, 1 = fp16 hi/lo pair; NC: column blocks; STATS: fused BN colstats
template<int ACT, int OUTMODE, int NC, int STATS>
__global__ __launch_bounds__(256)
void mfma_gemm_kernel(const unsigned short* __restrict__ A0h, const unsigned short* __restrict__ A0l,
                      const unsigned short* __restrict__ A1h, const unsigned short* __restrict__ A1l,
                      const unsigned short* __restrict__ A2h, const unsigned short* __restrict__ A2l,
                      const unsigned short* __restrict__ Wh,
                      const float* __restrict__ bvec,
                      float* __restrict__ C, unsigned short* __restrict__ Chi,
                      unsigned short* __restrict__ Clo,
                      float* __restrict__ bn_sums, float* __restrict__ bn_sumsq,
                      int M, int K, int seg, int Kout) {
    // [buf][kgroup(4)][row(128)][8 f16]; 8KB per plane per buf -> 48KB total
    __shared__ __attribute__((aligned(16))) unsigned short As_hi[2][4 * GBM * 8];
    __shared__ __attribute__((aligned(16))) unsigned short As_lo[2][4 * GBM * 8];
    __shared__ __attribute__((aligned(16))) unsigned short Bs_hi[2][4 * GBN * 8];

    int tid  = threadIdx.x;
    int lane = tid & 63;
    int w    = tid >> 6;                   // wave id == the kgroup this wave stages
    int wm   = w & 1, wn = w >> 1;         // 2x2 waves, 64x64 each
    int kg   = lane >> 4, lr = lane & 15;

    int bid = blockIdx.x, p, c;
    if (NC == 2) { p = ((bid >> 4) << 3) + (bid & 7); c = (bid >> 3) & 1; }
    else         { p = bid; c = 0; }
    int bm = p * GBM, bn = c * GBN;

    f32x4 acc[4][4];
    #pragma unroll
    for (int i = 0; i < 4; ++i)
        #pragma unroll
        for (int j = 0; j < 4; ++j)
            acc[i][j] = (f32x4){0.f, 0.f, 0.f, 0.f};

    auto STAGE = [&](int buf, int k0) {
        const unsigned short *Aph, *Apl; int kl0;
        if (k0 < seg)          { Aph = A0h; Apl = A0l; kl0 = k0; }
        else if (k0 < 2 * seg) { Aph = A1h; Apl = A1l; kl0 = k0 - seg; }
        else                   { Aph = A2h; Apl = A2l; kl0 = k0 - 2 * seg; }
        const unsigned short* a_h = Aph + (size_t)(bm + lane) * seg + kl0 + w * 8;
        const unsigned short* a_l = Apl + (size_t)(bm + lane) * seg + kl0 + w * 8;
        const unsigned short* b_h = Wh + (size_t)(bn + lane) * K + k0 + w * 8;
        size_t rA = (size_t)64 * seg, rB = (size_t)64 * K;
        gload_lds16(a_h,      &As_hi[buf][(w * 128) * 8]);
        gload_lds16(a_h + rA, &As_hi[buf][(w * 128 + 64) * 8]);
        gload_lds16(a_l,      &As_lo[buf][(w * 128) * 8]);
        gload_lds16(a_l + rA, &As_lo[buf][(w * 128 + 64) * 8]);
        gload_lds16(b_h,      &Bs_hi[buf][(w * 128) * 8]);
        gload_lds16(b_h + rB, &Bs_hi[buf][(w * 128 + 64) * 8]);
    };

    int nt = K / GBK;
    STAGE(0, 0);
    asm volatile("s_waitcnt vmcnt(0)" ::: "memory");
    __builtin_amdgcn_s_barrier();
    __builtin_amdgcn_sched_barrier(0);

    for (int t = 0; t < nt; ++t) {
        int cur = t & 1;
        if (t + 1 < nt) STAGE(cur ^ 1, (t + 1) * GBK);   // overlaps this step's compute

        int abase = (kg * GBM + wm * 64 + lr) * 8;
        int bbase = (kg * GBN + wn * 64 + lr) * 8;
        f16x8 ah[4], al[4], bh[4];
        #pragma unroll
        for (int mf = 0; mf < 4; ++mf) {
            ah[mf] = *(const f16x8*)&As_hi[cur][abase + mf * 16 * 8];
            al[mf] = *(const f16x8*)&As_lo[cur][abase + mf * 16 * 8];
        }
        #pragma unroll
        for (int nf = 0; nf < 4; ++nf)
            bh[nf] = *(const f16x8*)&Bs_hi[cur][bbase + nf * 16 * 8];
        #pragma unroll
        for (int mf = 0; mf < 4; ++mf)
            #pragma unroll
            for (int nf = 0; nf < 4; ++nf) {
                acc[mf][nf] = __builtin_amdgcn_mfma_f32_16x16x32_f16(ah[mf], bh[nf], acc[mf][nf], 0, 0, 0);
                acc[mf][nf] = __builtin_amdgcn_mfma_f32_16x16x32_f16(al[mf], bh[nf], acc[mf][nf], 0, 0, 0);
            }

        asm volatile("s_waitcnt vmcnt(0)" ::: "memory");  // next tile landed
        __builtin_amdgcn_s_barrier();                     // all reads of buf 'cur' done
        __builtin_amdgcn_sched_barrier(0);
    }

    // ---- epilogue: C/D layout col = lane&15, row = (lane>>4)*4 + reg ----
    #pragma unroll
    for (int nf = 0; nf < 4; ++nf) {
        int col = bn + wn * 64 + nf * 16 + lr;
        if (col >= Kout) continue;
        float bv = bvec[col];
        float s1 = 0.f, s2 = 0.f;
        #pragma unroll
        for (int mf = 0; mf < 4; ++mf) {
            #pragma unroll
            for (int i = 0; i < 4; ++i) {
                int rw = bm + wm * 64 + mf * 16 + kg * 4 + i;
                if (rw < M) {
                    float v = acc[mf][nf][i] + bv;
                    if (ACT == 1) v = fmaxf(v, 0.f);
                    if (STATS) { s1 += v; s2 += v * v; }
                    if (OUTMODE == 0) {
                        C[(size_t)rw * Kout + col] = v;
                    } else {
                        unsigned short hs, ls;
                        f2h_split(v, hs, ls);
                        Chi[(size_t)rw * Kout + col] = hs;
                        Clo[(size_t)rw * Kout + col] = ls;
                    }
                }
            }
        }
        if (STATS) {
            s1 += __shfl_xor(s1, 16); s1 += __shfl_xor(s1, 32);
            s2 += __shfl_xor(s2, 16); s2 += __shfl_xor(s2, 32);
            if (kg == 0) {
                atomicAdd(&bn_sums[col], s1);
                atomicAdd(&bn_sumsq[col], s2);
            }
        }
    }
}

__global__ void bnrelu_kernel(const float* __restrict__ y, const float* __restrict__ sums,
                              const float* __restrict__ sumsq, const float* __restrict__ g,
                              const float* __restrict__ beta,
                              unsigned short* __restrict__ Hhi, unsigned short* __restrict__ Hlo,
                              int M) {
    int idx = blockIdx.x * blockDim.x + threadIdx.x;   // group of 4 channels
    if (idx < M * HID / 4) {
        int col0 = (idx * 4) & (HID - 1);
        float4 v = ((const float4*)y)[idx];
        float invM = 1.0f / (float)M;
        float r[4] = {v.x, v.y, v.z, v.w};
        ushort4 hs, ls;
        unsigned short* hp = (unsigned short*)&hs;
        unsigned short* lp = (unsigned short*)&ls;
        #pragma unroll
        for (int j = 0; j < 4; ++j) {
            int col = col0 + j;
            float mean = sums[col] * invM;
            float var  = fmaxf(sumsq[col] * invM - mean * mean, 0.f);
            float o = (r[j] - mean) * rsqrtf(var + BN_EPS) * g[col] + beta[col];
            o = fmaxf(o, 0.f);
            f2h_split(o, hp[j], lp[j]);
        }
        ((ushort4*)Hhi)[idx] = hs;
        ((ushort4*)Hlo)[idx] = ls;
    }
}

extern "C" void kernel_launch(void* const* d_in, const int* in_sizes, int n_in,
                              void* d_out, int out_size, void* d_ws, size_t ws_size,
                              hipStream_t stream) {
    const float* x      = (const float*)d_in[0];
    const int*   ei     = (const int*)d_in[1];
    const float* W_feat = (const float*)d_in[2];
    const float* b_feat = (const float*)d_in[3];
    const float* W0     = (const float*)d_in[4];
    const float* b0     = (const float*)d_in[5];
    const float* g0     = (const float*)d_in[6];
    const float* beta0  = (const float*)d_in[7];
    const float* W1     = (const float*)d_in[8];
    const float* b1     = (const float*)d_in[9];
    const float* g1     = (const float*)d_in[10];
    const float* beta1  = (const float*)d_in[11];
    const float* Wc     = (const float*)d_in[12];
    const float* bc     = (const float*)d_in[13];
    float* out = (float*)d_out;

    const int N = N_NODES, E = N_EDGES;
    const int* row = ei;
    const int* col = ei + E;

    // workspace carve-up
    char* ws = (char*)d_ws;
    size_t off = 0;
    auto alloc = [&](size_t bytes) -> void* {
        void* p = ws + off;
        off = (off + bytes + 255) & ~(size_t)255;
        return p;
    };
    int*   deg_col  = (int*)  alloc(N * 4);
    int*   cursor   = (int*)  alloc(N * 4);
    int*   offsets  = (int*)  alloc((N + 1) * 4);
    int*   bsums    = (int*)  alloc(256 * 4);
    float* dis      = (float*)alloc(N * 4);
    int*   part_row = (int*)  alloc((size_t)NSLICE * N_PAD * 4);
    int*   part_col = (int*)  alloc((size_t)NSLICE * N_PAD * 4);
    int2*  csr      = (int2*) alloc((size_t)E * 8);
    unsigned short* x_hi    = (unsigned short*)alloc((size_t)N_PAD * IN_CH * 2);
    unsigned short* x_lo    = (unsigned short*)alloc((size_t)N_PAD * IN_CH * 2);
    unsigned short* h_hi    = (unsigned short*)alloc((size_t)N_PAD * HID * 2);
    unsigned short* h_lo    = (unsigned short*)alloc((size_t)N_PAD * HID * 2);
    unsigned short* agg1_hi = (unsigned short*)alloc((size_t)N_PAD * HID * 2);
    unsigned short* agg1_lo = (unsigned short*)alloc((size_t)N_PAD * HID * 2);
    // lifetime aliasing: x_hi/x_lo are dead after the feat GEMM; reuse the region
    unsigned short* agg2_hi = x_hi;
    unsigned short* agg2_lo = x_hi + (size_t)N_PAD * HID;
    float*          y       = (float*)x_lo;
    float* sums     = (float*)alloc(HID * 4);
    float* sumsq    = (float*)alloc(HID * 4);
    unsigned short* WTf_hi = (unsigned short*)alloc((size_t)HID * IN_CH * 2);
    unsigned short* WT0_hi = (unsigned short*)alloc((size_t)HID * 3 * HID * 2);
    unsigned short* WT1_hi = (unsigned short*)alloc((size_t)HID * 3 * HID * 2);
    unsigned short* WTc_hi = (unsigned short*)alloc((size_t)128 * HID * 2);   // 40 rows padded to 128

    hipMemsetAsync(cursor, 0, N * 4, stream);
    hipMemsetAsync(WTc_hi, 0, (size_t)128 * HID * 2, stream);

    // operand pre-splits (independent of CSR build)
    split_x_kernel<<<(N * IN_CH / 4 + 255) / 256, 256, 0, stream>>>(x, x_hi, x_lo, N * IN_CH / 4);
    dim3 tb(32, 8);
    transpose_half_kernel<<<dim3(HID / 32, IN_CH / 32), tb, 0, stream>>>(W_feat, WTf_hi, IN_CH, HID);
    transpose_half_kernel<<<dim3(HID / 32, 3 * HID / 32), tb, 0, stream>>>(W0, WT0_hi, 3 * HID, HID);
    transpose_half_kernel<<<dim3(HID / 32, 3 * HID / 32), tb, 0, stream>>>(W1, WT1_hi, 3 * HID, HID);
    transpose_half_kernel<<<dim3((OUT_CH + 31) / 32, HID / 32), tb, 0, stream>>>(Wc, WTc_hi, HID, OUT_CH);

    // degree histograms (LDS-privatized, atomic-free globally)
    hist_kernel<<<dim3(NSLICE, NCHUNK), 256, 0, stream>>>(row, col, part_row, part_col, E);
    merge_deg_kernel<<<(N + 255) / 256, 256, 0, stream>>>(part_row, part_col, dis, deg_col, N);

    const int NB_SCAN = (N + 255) / 256;   // 196
    scan1_kernel<<<NB_SCAN, 256, 0, stream>>>(deg_col, bsums, N);
    scan2_kernel<<<1, 256, 0, stream>>>(bsums, NB_SCAN);
    scan3_kernel<<<NB_SCAN, 256, 0, stream>>>(deg_col, bsums, offsets, N);
    fill_csr_kernel<<<(E + 255) / 256, 256, 0, stream>>>(row, col, dis, offsets, cursor,
                                                         csr, E);

    const int NPAN = N_PAD / GBM;          // 392 row-panels
    // h = relu(x @ W_feat + b_feat) -> fp16 hi/lo pair
    mfma_gemm_kernel<1, 1, 2, 0><<<NPAN * 2, 256, 0, stream>>>(
        x_hi, x_lo, nullptr, nullptr, nullptr, nullptr, WTf_hi, b_feat,
        nullptr, h_hi, h_lo, nullptr, nullptr, N, IN_CH, IN_CH, HID);

    const unsigned short* WThs[2] = {WT0_hi, WT1_hi};
    const float* bs[2]    = {b0, b1};
    const float* gs[2]    = {g0, g1};
    const float* betas[2] = {beta0, beta1};
    int prop_grid = (N + 3) / 4;
    for (int layer = 0; layer < 2; ++layer) {
        prop_kernel<<<prop_grid, 256, 0, stream>>>(h_hi, offsets, csr, agg1_hi, agg1_lo, N);
        prop_kernel<<<prop_grid, 256, 0, stream>>>(agg1_hi, offsets, csr, agg2_hi, agg2_lo, N);
        hipMemsetAsync(sums, 0, HID * 4, stream);
        hipMemsetAsync(sumsq, 0, HID * 4, stream);
        mfma_gemm_kernel<0, 0, 2, 1><<<NPAN * 2, 256, 0, stream>>>(
            h_hi, h_lo, agg1_hi, agg1_lo, agg2_hi, agg2_lo, WThs[layer], bs[layer],
            y, nullptr, nullptr, sums, sumsq, N, 3 * HID, HID, HID);
        bnrelu_kernel<<<(N * HID / 4 + 255) / 256, 256, 0, stream>>>(y, sums, sumsq, gs[layer],
                                                                     betas[layer], h_hi, h_lo, N);
    }

    mfma_gemm_kernel<0, 0, 1, 0><<<NPAN, 256, 0, stream>>>(
        h_hi, h_lo, nullptr, nullptr, nullptr, nullptr, WTc_hi, bc,
        out, nullptr, nullptr, nullptr, nullptr, N, HID, HID, OUT_CH);
}

// Round 10
// 1033.031 us; speedup vs baseline: 1.6233x; 1.0116x over previous
//
#include <hip/hip_runtime.h>

#define N_NODES 50000
#define N_PAD   50176            // 392 * 128 = 8 * 6272
#define N_EDGES 1600000
#define IN_CH   512
#define HID     256
#define OUT_CH  40
#define BN_EPS  1e-5f

#define HCHUNK  6272             // nodes per histogram chunk (8 chunks cover N_PAD)
#define NCHUNK  8
#define NSLICE  32               // edge slices; E/NSLICE = 50000 exactly

typedef _Float16 f16x8 __attribute__((ext_vector_type(8)));
typedef __attribute__((ext_vector_type(8))) unsigned short u16x8;
typedef __attribute__((ext_vector_type(4))) float f32x4;

__device__ __forceinline__ unsigned short f2h_us(float f) {
    _Float16 h = (_Float16)f;
    return __builtin_bit_cast(unsigned short, h);
}
__device__ __forceinline__ float h2f(unsigned short u) {
    return (float)__builtin_bit_cast(_Float16, u);
}
// split f into fp16 hi + fp16 lo (residual; exact subtraction in fp32)
__device__ __forceinline__ void f2h_split(float f, unsigned short& hi, unsigned short& lo) {
    _Float16 h = (_Float16)f;
    hi = __builtin_bit_cast(unsigned short, h);
    lo = f2h_us(f - (float)h);
}

// async global->LDS, 16B per lane; LDS dest is wave-uniform base + lane*16
__device__ __forceinline__ void gload_lds16(const void* gsrc, void* ldst) {
    __builtin_amdgcn_global_load_lds(
        (const __attribute__((address_space(1))) unsigned int*)gsrc,
        (__attribute__((address_space(3))) unsigned int*)ldst,
        16, 0, 0);
}

// ---------------- degree histograms via LDS privatization (no global atomics) ----------------
__global__ __launch_bounds__(256)
void hist_kernel(const int* __restrict__ row, const int* __restrict__ col,
                 int* __restrict__ part_row, int* __restrict__ part_col, int E) {
    __shared__ int hr[HCHUNK];
    __shared__ int hc[HCHUNK];
    int s = blockIdx.x;        // edge slice
    int c = blockIdx.y;        // node chunk
    int base = c * HCHUNK;
    int t = threadIdx.x;
    for (int i = t; i < HCHUNK; i += 256) { hr[i] = 0; hc[i] = 0; }
    __syncthreads();
    int e0 = s * (E / NSLICE), e1 = e0 + E / NSLICE;
    for (int e = e0 + t; e < e1; e += 256) {
        int r = row[e], cc = col[e];
        unsigned lr = (unsigned)(r - base);
        unsigned lc = (unsigned)(cc - base);
        if (lr < HCHUNK) atomicAdd(&hr[lr], 1);
        if (lc < HCHUNK) atomicAdd(&hc[lc], 1);
    }
    __syncthreads();
    int* pr = part_row + (size_t)s * N_PAD + base;
    int* pc = part_col + (size_t)s * N_PAD + base;
    for (int i = t; i < HCHUNK; i += 256) { pr[i] = hr[i]; pc[i] = hc[i]; }
}

__global__ void merge_deg_kernel(const int* __restrict__ part_row, const int* __restrict__ part_col,
                                 float* __restrict__ dis, int* __restrict__ deg_col, int n) {
    int i = blockIdx.x * blockDim.x + threadIdx.x;
    if (i < n) {
        int dr = 0, dc = 0;
        #pragma unroll
        for (int s = 0; s < NSLICE; ++s) {
            dr += part_row[(size_t)s * N_PAD + i];
            dc += part_col[(size_t)s * N_PAD + i];
        }
        dis[i] = rsqrtf((float)max(dr, 1));
        deg_col[i] = dc;
    }
}

// ---------------- 3-phase exclusive prefix sum ----------------
__global__ void scan1_kernel(const int* __restrict__ deg, int* __restrict__ bsums, int n) {
    __shared__ int sd[256];
    int t = threadIdx.x;
    int i = blockIdx.x * 256 + t;
    sd[t] = (i < n) ? deg[i] : 0;
    __syncthreads();
    for (int o = 128; o > 0; o >>= 1) {
        if (t < o) sd[t] += sd[t + o];
        __syncthreads();
    }
    if (t == 0) bsums[blockIdx.x] = sd[0];
}

__global__ void scan2_kernel(int* __restrict__ bsums, int nb) {   // 1 block, 256 threads
    __shared__ int sd[256];
    int t = threadIdx.x;
    int v = (t < nb) ? bsums[t] : 0;
    sd[t] = v;
    __syncthreads();
    for (int o = 1; o < 256; o <<= 1) {
        int u = (t >= o) ? sd[t - o] : 0;
        __syncthreads();
        sd[t] += u;
        __syncthreads();
    }
    if (t < nb) bsums[t] = sd[t] - v;   // exclusive
}

__global__ void scan3_kernel(const int* __restrict__ deg, const int* __restrict__ bsums,
                             int* __restrict__ offsets, int n) {
    __shared__ int sd[256];
    int t = threadIdx.x;
    int i = blockIdx.x * 256 + t;
    sd[t] = (i < n) ? deg[i] : 0;
    __syncthreads();
    for (int o = 1; o < 256; o <<= 1) {
        int u = (t >= o) ? sd[t - o] : 0;
        __syncthreads();
        sd[t] += u;
        __syncthreads();
    }
    if (i < n) offsets[i + 1] = bsums[blockIdx.x] + sd[t];
    if (i == 0) offsets[0] = 0;
}

// ---------------- CSR fill: single 8B record {src_row, norm_bits} per edge ----------------
__global__ void fill_csr_kernel(const int* __restrict__ row, const int* __restrict__ col,
                                const float* __restrict__ dis, const int* __restrict__ offsets,
                                int* __restrict__ cursor, int2* __restrict__ csr, int E) {
    int e = blockIdx.x * blockDim.x + threadIdx.x;
    if (e < E) {
        int r = row[e], c = col[e];
        int pos = atomicAdd(&cursor[c], 1);
        int idx = offsets[c] + pos;
        float nrm = dis[r] * dis[c];
        csr[idx] = make_int2(r, __float_as_int(nrm));
    }
}

// ---------------- x hi/lo split (fp16) ----------------
__global__ void split_x_kernel(const float* __restrict__ x, unsigned short* __restrict__ xhi,
                               unsigned short* __restrict__ xlo, int n4) {
    int i = blockIdx.x * blockDim.x + threadIdx.x;
    if (i < n4) {
        float4 v = ((const float4*)x)[i];
        float r[4] = {v.x, v.y, v.z, v.w};
        ushort4 hs, ls;
        unsigned short* hp = (unsigned short*)&hs;
        unsigned short* lp = (unsigned short*)&ls;
        #pragma unroll
        for (int j = 0; j < 4; ++j) f2h_split(r[j], hp[j], lp[j]);
        ((ushort4*)xhi)[i] = hs;
        ((ushort4*)xlo)[i] = ls;
    }
}

// ---------------- propagation (full-row fp16 gather, deep MLP) ----------------
__global__ void prop_kernel(const unsigned short* __restrict__ hsrc,
                            const int* __restrict__ offsets,
                            const int2* __restrict__ csr,
                            unsigned short* __restrict__ Ohi, unsigned short* __restrict__ Olo,
                            int n) {
    int node = blockIdx.x * 4 + (threadIdx.x >> 6);
    if (node >= n) return;
    int lane = threadIdx.x & 63;
    int half = lane >> 5;
    int cl   = lane & 31;           // 16B chunk id within the 512B row
    int beg = offsets[node], end = offsets[node + 1];
    float acc[8] = {0.f, 0.f, 0.f, 0.f, 0.f, 0.f, 0.f, 0.f};
    for (int i = beg; i < end; i += 8) {
        int ii[4] = {i + half, i + 2 + half, i + 4 + half, i + 6 + half};
        float w[4];
        int s[4];
        #pragma unroll
        for (int u = 0; u < 4; ++u) {
            int2 rec = csr[min(ii[u], end - 1)];
            w[u] = (ii[u] < end) ? __int_as_float(rec.y) : 0.f;
            s[u] = rec.x;
        }
        u16x8 v[4];
        #pragma unroll
        for (int u = 0; u < 4; ++u)
            v[u] = *(const u16x8*)(hsrc + (size_t)s[u] * HID + cl * 8);
        #pragma unroll
        for (int u = 0; u < 4; ++u)
            #pragma unroll
            for (int j = 0; j < 8; ++j)
                acc[j] += w[u] * h2f((unsigned short)v[u][j]);
    }
    #pragma unroll
    for (int j = 0; j < 8; ++j) acc[j] += __shfl_xor(acc[j], 32);
    u16x8 ov;
    if (half == 0) {
        #pragma unroll
        for (int j = 0; j < 8; ++j) ov[j] = f2h_us(acc[j]);
        *(u16x8*)(Ohi + (size_t)node * HID + cl * 8) = ov;
    } else {
        #pragma unroll
        for (int j = 0; j < 8; ++j) {
            unsigned short h, l;
            f2h_split(acc[j], h, l);
            ov[j] = l;
        }
        *(u16x8*)(Olo + (size_t)node * HID + cl * 8) = ov;
    }
}

// ---------------- tiled transpose -> single fp16 plane: src[R][C] -> dst[C][R] ----------------
__global__ void transpose_half_kernel(const float* __restrict__ src,
                                      unsigned short* __restrict__ dhi, int R, int C) {
    __shared__ float tile[32][33];
    int c0 = blockIdx.x * 32, r0 = blockIdx.y * 32;
    int tx = threadIdx.x, ty = threadIdx.y;   // block (32, 8)
    #pragma unroll
    for (int i = 0; i < 32; i += 8) {
        int r = r0 + ty + i, c = c0 + tx;
        tile[ty + i][tx] = (r < R && c < C) ? src[(size_t)r * C + c] : 0.f;
    }
    __syncthreads();
    #pragma unroll
    for (int i = 0; i < 32; i += 8) {
        int c = c0 + ty + i, r = r0 + tx;
        if (c < C && r < R) dhi[(size_t)c * R + r] = f2h_us(tile[tx][ty + i]);
    }
}

// ---------------- MFMA GEMM (fp16): triple-buffered LDS, depth-2 prefetch, counted vmcnt ----------------
#define GBM 128
#define GBN 128
#define GBK 32

// ACT: relu; OUTMODE: 0 = fp32 C, 1 = fp16 hi/lo pair; NC: column blocks; STATS: fused BN colstats
template<int ACT, int OUTMODE, int NC, int STATS>
__global__ __launch_bounds__(256)
void mfma_gemm_kernel(const unsigned short* __restrict__ A0h, const unsigned short* __restrict__ A0l,
                      const unsigned short* __restrict__ A1h, const unsigned short* __restrict__ A1l,
                      const unsigned short* __restrict__ A2h, const unsigned short* __restrict__ A2l,
                      const unsigned short* __restrict__ Wh,
                      const float* __restrict__ bvec,
                      float* __restrict__ C, unsigned short* __restrict__ Chi,
                      unsigned short* __restrict__ Clo,
                      float* __restrict__ bn_sums, float* __restrict__ bn_sumsq,
                      int M, int K, int seg, int Kout) {
    // [buf(3)][kgroup(4)][row(128)][8 f16]; 8KB per plane per buf -> 72KB total (2 blocks/CU)
    __shared__ __attribute__((aligned(16))) unsigned short As_hi[3][4 * GBM * 8];
    __shared__ __attribute__((aligned(16))) unsigned short As_lo[3][4 * GBM * 8];
    __shared__ __attribute__((aligned(16))) unsigned short Bs_hi[3][4 * GBN * 8];

    int tid  = threadIdx.x;
    int lane = tid & 63;
    int w    = tid >> 6;                   // wave id == the kgroup this wave stages
    int wm   = w & 1, wn = w >> 1;         // 2x2 waves, 64x64 each
    int kg   = lane >> 4, lr = lane & 15;

    int bid = blockIdx.x, p, c;
    if (NC == 2) { p = ((bid >> 4) << 3) + (bid & 7); c = (bid >> 3) & 1; }
    else         { p = bid; c = 0; }
    int bm = p * GBM, bn = c * GBN;

    f32x4 acc[4][4];
    #pragma unroll
    for (int i = 0; i < 4; ++i)
        #pragma unroll
        for (int j = 0; j < 4; ++j)
            acc[i][j] = (f32x4){0.f, 0.f, 0.f, 0.f};

    // each wave issues exactly 6 global_load_lds per STAGE
    auto STAGE = [&](int buf, int k0) {
        const unsigned short *Aph, *Apl; int kl0;
        if (k0 < seg)          { Aph = A0h; Apl = A0l; kl0 = k0; }
        else if (k0 < 2 * seg) { Aph = A1h; Apl = A1l; kl0 = k0 - seg; }
        else                   { Aph = A2h; Apl = A2l; kl0 = k0 - 2 * seg; }
        const unsigned short* a_h = Aph + (size_t)(bm + lane) * seg + kl0 + w * 8;
        const unsigned short* a_l = Apl + (size_t)(bm + lane) * seg + kl0 + w * 8;
        const unsigned short* b_h = Wh + (size_t)(bn + lane) * K + k0 + w * 8;
        size_t rA = (size_t)64 * seg, rB = (size_t)64 * K;
        gload_lds16(a_h,      &As_hi[buf][(w * 128) * 8]);
        gload_lds16(a_h + rA, &As_hi[buf][(w * 128 + 64) * 8]);
        gload_lds16(a_l,      &As_lo[buf][(w * 128) * 8]);
        gload_lds16(a_l + rA, &As_lo[buf][(w * 128 + 64) * 8]);
        gload_lds16(b_h,      &Bs_hi[buf][(w * 128) * 8]);
        gload_lds16(b_h + rB, &Bs_hi[buf][(w * 128 + 64) * 8]);
    };

    int nt = K / GBK;                      // >= 8 for all our shapes
    STAGE(0, 0);
    STAGE(1, GBK);

    for (int t = 0; t < nt; ++t) {
        int cur = t % 3;
        // depth-2 prefetch + counted wait: tile t's 6 loads are the oldest
        if (t + 2 < nt) {
            STAGE((t + 2) % 3, (t + 2) * GBK);   // overwrites buf(t-1): reads done at end of iter t-1
            asm volatile("s_waitcnt vmcnt(12)" ::: "memory");
        } else if (t + 1 < nt) {
            asm volatile("s_waitcnt vmcnt(6)" ::: "memory");
        } else {
            asm volatile("s_waitcnt vmcnt(0)" ::: "memory");
        }
        __builtin_amdgcn_s_barrier();          // buf cur fully written for all waves
        __builtin_amdgcn_sched_barrier(0);

        int abase = (kg * GBM + wm * 64 + lr) * 8;
        int bbase = (kg * GBN + wn * 64 + lr) * 8;
        f16x8 ah[4], al[4], bh[4];
        #pragma unroll
        for (int mf = 0; mf < 4; ++mf) {
            ah[mf] = *(const f16x8*)&As_hi[cur][abase + mf * 16 * 8];
            al[mf] = *(const f16x8*)&As_lo[cur][abase + mf * 16 * 8];
        }
        #pragma unroll
        for (int nf = 0; nf < 4; ++nf)
            bh[nf] = *(const f16x8*)&Bs_hi[cur][bbase + nf * 16 * 8];
        #pragma unroll
        for (int mf = 0; mf < 4; ++mf)
            #pragma unroll
            for (int nf = 0; nf < 4; ++nf) {
                acc[mf][nf] = __builtin_amdgcn_mfma_f32_16x16x32_f16(ah[mf], bh[nf], acc[mf][nf], 0, 0, 0);
                acc[mf][nf] = __builtin_amdgcn_mfma_f32_16x16x32_f16(al[mf], bh[nf], acc[mf][nf], 0, 0, 0);
            }

        __builtin_amdgcn_s_barrier();          // all waves done reading buf cur
        __builtin_amdgcn_sched_barrier(0);
    }

    // ---- epilogue: C/D layout col = lane&15, row = (lane>>4)*4 + reg ----
    #pragma unroll
    for (int nf = 0; nf < 4; ++nf) {
        int col = bn + wn * 64 + nf * 16 + lr;
        if (col >= Kout) continue;
        float bv = bvec[col];
        float s1 = 0.f, s2 = 0.f;
        #pragma unroll
        for (int mf = 0; mf < 4; ++mf) {
            #pragma unroll
            for (int i = 0; i < 4; ++i) {
                int rw = bm + wm * 64 + mf * 16 + kg * 4 + i;
                if (rw < M) {
                    float v = acc[mf][nf][i] + bv;
                    if (ACT == 1) v = fmaxf(v, 0.f);
                    if (STATS) { s1 += v; s2 += v * v; }
                    if (OUTMODE == 0) {
                        C[(size_t)rw * Kout + col] = v;
                    } else {
                        unsigned short hs, ls;
                        f2h_split(v, hs, ls);
                        Chi[(size_t)rw * Kout + col] = hs;
                        Clo[(size_t)rw * Kout + col] = ls;
                    }
                }
            }
        }
        if (STATS) {
            s1 += __shfl_xor(s1, 16); s1 += __shfl_xor(s1, 32);
            s2 += __shfl_xor(s2, 16); s2 += __shfl_xor(s2, 32);
            if (kg == 0) {
                atomicAdd(&bn_sums[col], s1);
                atomicAdd(&bn_sumsq[col], s2);
            }
        }
    }
}

__global__ void bnrelu_kernel(const float* __restrict__ y, const float* __restrict__ sums,
                              const float* __restrict__ sumsq, const float* __restrict__ g,
                              const float* __restrict__ beta,
                              unsigned short* __restrict__ Hhi, unsigned short* __restrict__ Hlo,
                              int M) {
    int idx = blockIdx.x * blockDim.x + threadIdx.x;   // group of 4 channels
    if (idx < M * HID / 4) {
        int col0 = (idx * 4) & (HID - 1);
        float4 v = ((const float4*)y)[idx];
        float invM = 1.0f / (float)M;
        float r[4] = {v.x, v.y, v.z, v.w};
        ushort4 hs, ls;
        unsigned short* hp = (unsigned short*)&hs;
        unsigned short* lp = (unsigned short*)&ls;
        #pragma unroll
        for (int j = 0; j < 4; ++j) {
            int col = col0 + j;
            float mean = sums[col] * invM;
            float var  = fmaxf(sumsq[col] * invM - mean * mean, 0.f);
            float o = (r[j] - mean) * rsqrtf(var + BN_EPS) * g[col] + beta[col];
            o = fmaxf(o, 0.f);
            f2h_split(o, hp[j], lp[j]);
        }
        ((ushort4*)Hhi)[idx] = hs;
        ((ushort4*)Hlo)[idx] = ls;
    }
}

extern "C" void kernel_launch(void* const* d_in, const int* in_sizes, int n_in,
                              void* d_out, int out_size, void* d_ws, size_t ws_size,
                              hipStream_t stream) {
    const float* x      = (const float*)d_in[0];
    const int*   ei     = (const int*)d_in[1];
    const float* W_feat = (const float*)d_in[2];
    const float* b_feat = (const float*)d_in[3];
    const float* W0     = (const float*)d_in[4];
    const float* b0     = (const float*)d_in[5];
    const float* g0     = (const float*)d_in[6];
    const float* beta0  = (const float*)d_in[7];
    const float* W1     = (const float*)d_in[8];
    const float* b1     = (const float*)d_in[9];
    const float* g1     = (const float*)d_in[10];
    const float* beta1  = (const float*)d_in[11];
    const float* Wc     = (const float*)d_in[12];
    const float* bc     = (const float*)d_in[13];
    float* out = (float*)d_out;

    const int N = N_NODES, E = N_EDGES;
    const int* row = ei;
    const int* col = ei + E;

    // workspace carve-up
    char* ws = (char*)d_ws;
    size_t off = 0;
    auto alloc = [&](size_t bytes) -> void* {
        void* p = ws + off;
        off = (off + bytes + 255) & ~(size_t)255;
        return p;
    };
    int*   deg_col  = (int*)  alloc(N * 4);
    int*   cursor   = (int*)  alloc(N * 4);
    int*   offsets  = (int*)  alloc((N + 1) * 4);
    int*   bsums    = (int*)  alloc(256 * 4);
    float* dis      = (float*)alloc(N * 4);
    int*   part_row = (int*)  alloc((size_t)NSLICE * N_PAD * 4);
    int*   part_col = (int*)  alloc((size_t)NSLICE * N_PAD * 4);
    int2*  csr      = (int2*) alloc((size_t)E * 8);
    unsigned short* x_hi    = (unsigned short*)alloc((size_t)N_PAD * IN_CH * 2);
    unsigned short* x_lo    = (unsigned short*)alloc((size_t)N_PAD * IN_CH * 2);
    unsigned short* h_hi    = (unsigned short*)alloc((size_t)N_PAD * HID * 2);
    unsigned short* h_lo    = (unsigned short*)alloc((size_t)N_PAD * HID * 2);
    unsigned short* agg1_hi = (unsigned short*)alloc((size_t)N_PAD * HID * 2);
    unsigned short* agg1_lo = (unsigned short*)alloc((size_t)N_PAD * HID * 2);
    // lifetime aliasing: x_hi/x_lo are dead after the feat GEMM; reuse the region
    unsigned short* agg2_hi = x_hi;
    unsigned short* agg2_lo = x_hi + (size_t)N_PAD * HID;
    float*          y       = (float*)x_lo;
    float* sums     = (float*)alloc(HID * 4);
    float* sumsq    = (float*)alloc(HID * 4);
    unsigned short* WTf_hi = (unsigned short*)alloc((size_t)HID * IN_CH * 2);
    unsigned short* WT0_hi = (unsigned short*)alloc((size_t)HID * 3 * HID * 2);
    unsigned short* WT1_hi = (unsigned short*)alloc((size_t)HID * 3 * HID * 2);
    unsigned short* WTc_hi = (unsigned short*)alloc((size_t)128 * HID * 2);   // 40 rows padded to 128

    hipMemsetAsync(cursor, 0, N * 4, stream);
    hipMemsetAsync(WTc_hi, 0, (size_t)128 * HID * 2, stream);

    // operand pre-splits (independent of CSR build)
    split_x_kernel<<<(N * IN_CH / 4 + 255) / 256, 256, 0, stream>>>(x, x_hi, x_lo, N * IN_CH / 4);
    dim3 tb(32, 8);
    transpose_half_kernel<<<dim3(HID / 32, IN_CH / 32), tb, 0, stream>>>(W_feat, WTf_hi, IN_CH, HID);
    transpose_half_kernel<<<dim3(HID / 32, 3 * HID / 32), tb, 0, stream>>>(W0, WT0_hi, 3 * HID, HID);
    transpose_half_kernel<<<dim3(HID / 32, 3 * HID / 32), tb, 0, stream>>>(W1, WT1_hi, 3 * HID, HID);
    transpose_half_kernel<<<dim3((OUT_CH + 31) / 32, HID / 32), tb, 0, stream>>>(Wc, WTc_hi, HID, OUT_CH);

    // degree histograms (LDS-privatized, atomic-free globally)
    hist_kernel<<<dim3(NSLICE, NCHUNK), 256, 0, stream>>>(row, col, part_row, part_col, E);
    merge_deg_kernel<<<(N + 255) / 256, 256, 0, stream>>>(part_row, part_col, dis, deg_col, N);

    const int NB_SCAN = (N + 255) / 256;   // 196
    scan1_kernel<<<NB_SCAN, 256, 0, stream>>>(deg_col, bsums, N);
    scan2_kernel<<<1, 256, 0, stream>>>(bsums, NB_SCAN);
    scan3_kernel<<<NB_SCAN, 256, 0, stream>>>(deg_col, bsums, offsets, N);
    fill_csr_kernel<<<(E + 255) / 256, 256, 0, stream>>>(row, col, dis, offsets, cursor,
                                                         csr, E);

    const int NPAN = N_PAD / GBM;          // 392 row-panels
    // h = relu(x @ W_feat + b_feat) -> fp16 hi/lo pair
    mfma_gemm_kernel<1, 1, 2, 0><<<NPAN * 2, 256, 0, stream>>>(
        x_hi, x_lo, nullptr, nullptr, nullptr, nullptr, WTf_hi, b_feat,
        nullptr, h_hi, h_lo, nullptr, nullptr, N, IN_CH, IN_CH, HID);

    const unsigned short* WThs[2] = {WT0_hi, WT1_hi};
    const float* bs[2]    = {b0, b1};
    const float* gs[2]    = {g0, g1};
    const float* betas[2] = {beta0, beta1};
    int prop_grid = (N + 3) / 4;
    for (int layer = 0; layer < 2; ++layer) {
        prop_kernel<<<prop_grid, 256, 0, stream>>>(h_hi, offsets, csr, agg1_hi, agg1_lo, N);
        prop_kernel<<<prop_grid, 256, 0, stream>>>(agg1_hi, offsets, csr, agg2_hi, agg2_lo, N);
        hipMemsetAsync(sums, 0, HID * 4, stream);
        hipMemsetAsync(sumsq, 0, HID * 4, stream);
        mfma_gemm_kernel<0, 0, 2, 1><<<NPAN * 2, 256, 0, stream>>>(
            h_hi, h_lo, agg1_hi, agg1_lo, agg2_hi, agg2_lo, WThs[layer], bs[layer],
            y, nullptr, nullptr, sums, sumsq, N, 3 * HID, HID, HID);
        bnrelu_kernel<<<(N * HID / 4 + 255) / 256, 256, 0, stream>>>(y, sums, sumsq, gs[layer],
                                                                     betas[layer], h_hi, h_lo, N);
    }

    mfma_gemm_kernel<0, 0, 1, 0><<<NPAN, 256, 0, stream>>>(
        h_hi, h_lo, nullptr, nullptr, nullptr, nullptr, WTc_hi, bc,
        out, nullptr, nullptr, nullptr, nullptr, N, HID, HID, OUT_CH);
}

// Round 11
// 987.961 us; speedup vs baseline: 1.6973x; 1.0456x over previous
//
#include <hip/hip_runtime.h>

#define N_NODES 50000
#define N_PAD   50176            // 196 * 256 = 8 * 6272
#define N_EDGES 1600000
#define IN_CH   512
#define HID     256
#define OUT_CH  40
#define BN_EPS  1e-5f

#define HCHUNK  6272             // nodes per histogram chunk (8 chunks cover N_PAD)
#define NCHUNK  8
#define NSLICE  32               // edge slices; E/NSLICE = 50000 exactly

typedef _Float16 f16x8 __attribute__((ext_vector_type(8)));
typedef __attribute__((ext_vector_type(8))) unsigned short u16x8;
typedef __attribute__((ext_vector_type(4))) float f32x4;

__device__ __forceinline__ unsigned short f2h_us(float f) {
    _Float16 h = (_Float16)f;
    return __builtin_bit_cast(unsigned short, h);
}
__device__ __forceinline__ float h2f(unsigned short u) {
    return (float)__builtin_bit_cast(_Float16, u);
}
// split f into fp16 hi + fp16 lo (residual; exact subtraction in fp32)
__device__ __forceinline__ void f2h_split(float f, unsigned short& hi, unsigned short& lo) {
    _Float16 h = (_Float16)f;
    hi = __builtin_bit_cast(unsigned short, h);
    lo = f2h_us(f - (float)h);
}

// async global->LDS, 16B per lane; LDS dest is wave-uniform base + lane*16
__device__ __forceinline__ void gload_lds16(const void* gsrc, void* ldst) {
    __builtin_amdgcn_global_load_lds(
        (const __attribute__((address_space(1))) unsigned int*)gsrc,
        (__attribute__((address_space(3))) unsigned int*)ldst,
        16, 0, 0);
}

// ---------------- degree histograms via LDS privatization (no global atomics) ----------------
__global__ __launch_bounds__(256)
void hist_kernel(const int* __restrict__ row, const int* __restrict__ col,
                 int* __restrict__ part_row, int* __restrict__ part_col, int E) {
    __shared__ int hr[HCHUNK];
    __shared__ int hc[HCHUNK];
    int s = blockIdx.x;        // edge slice
    int c = blockIdx.y;        // node chunk
    int base = c * HCHUNK;
    int t = threadIdx.x;
    for (int i = t; i < HCHUNK; i += 256) { hr[i] = 0; hc[i] = 0; }
    __syncthreads();
    int e0 = s * (E / NSLICE), e1 = e0 + E / NSLICE;
    for (int e = e0 + t; e < e1; e += 256) {
        int r = row[e], cc = col[e];
        unsigned lr = (unsigned)(r - base);
        unsigned lc = (unsigned)(cc - base);
        if (lr < HCHUNK) atomicAdd(&hr[lr], 1);
        if (lc < HCHUNK) atomicAdd(&hc[lc], 1);
    }
    __syncthreads();
    int* pr = part_row + (size_t)s * N_PAD + base;
    int* pc = part_col + (size_t)s * N_PAD + base;
    for (int i = t; i < HCHUNK; i += 256) { pr[i] = hr[i]; pc[i] = hc[i]; }
}

__global__ void merge_deg_kernel(const int* __restrict__ part_row, const int* __restrict__ part_col,
                                 float* __restrict__ dis, int* __restrict__ deg_col, int n) {
    int i = blockIdx.x * blockDim.x + threadIdx.x;
    if (i < n) {
        int dr = 0, dc = 0;
        #pragma unroll
        for (int s = 0; s < NSLICE; ++s) {
            dr += part_row[(size_t)s * N_PAD + i];
            dc += part_col[(size_t)s * N_PAD + i];
        }
        dis[i] = rsqrtf((float)max(dr, 1));
        deg_col[i] = dc;
    }
}

// ---------------- 3-phase exclusive prefix sum ----------------
__global__ void scan1_kernel(const int* __restrict__ deg, int* __restrict__ bsums, int n) {
    __shared__ int sd[256];
    int t = threadIdx.x;
    int i = blockIdx.x * 256 + t;
    sd[t] = (i < n) ? deg[i] : 0;
    __syncthreads();
    for (int o = 128; o > 0; o >>= 1) {
        if (t < o) sd[t] += sd[t + o];
        __syncthreads();
    }
    if (t == 0) bsums[blockIdx.x] = sd[0];
}

__global__ void scan2_kernel(int* __restrict__ bsums, int nb) {   // 1 block, 256 threads
    __shared__ int sd[256];
    int t = threadIdx.x;
    int v = (t < nb) ? bsums[t] : 0;
    sd[t] = v;
    __syncthreads();
    for (int o = 1; o < 256; o <<= 1) {
        int u = (t >= o) ? sd[t - o] : 0;
        __syncthreads();
        sd[t] += u;
        __syncthreads();
    }
    if (t < nb) bsums[t] = sd[t] - v;   // exclusive
}

__global__ void scan3_kernel(const int* __restrict__ deg, const int* __restrict__ bsums,
                             int* __restrict__ offsets, int n) {
    __shared__ int sd[256];
    int t = threadIdx.x;
    int i = blockIdx.x * 256 + t;
    sd[t] = (i < n) ? deg[i] : 0;
    __syncthreads();
    for (int o = 1; o < 256; o <<= 1) {
        int u = (t >= o) ? sd[t - o] : 0;
        __syncthreads();
        sd[t] += u;
        __syncthreads();
    }
    if (i < n) offsets[i + 1] = bsums[blockIdx.x] + sd[t];
    if (i == 0) offsets[0] = 0;
}

// ---------------- CSR fill: single 8B record {src_row, norm_bits} per edge ----------------
__global__ void fill_csr_kernel(const int* __restrict__ row, const int* __restrict__ col,
                                const float* __restrict__ dis, const int* __restrict__ offsets,
                                int* __restrict__ cursor, int2* __restrict__ csr, int E) {
    int e = blockIdx.x * blockDim.x + threadIdx.x;
    if (e < E) {
        int r = row[e], c = col[e];
        int pos = atomicAdd(&cursor[c], 1);
        int idx = offsets[c] + pos;
        float nrm = dis[r] * dis[c];
        csr[idx] = make_int2(r, __float_as_int(nrm));
    }
}

// ---------------- x hi/lo split (fp16) ----------------
__global__ void split_x_kernel(const float* __restrict__ x, unsigned short* __restrict__ xhi,
                               unsigned short* __restrict__ xlo, int n4) {
    int i = blockIdx.x * blockDim.x + threadIdx.x;
    if (i < n4) {
        float4 v = ((const float4*)x)[i];
        float r[4] = {v.x, v.y, v.z, v.w};
        ushort4 hs, ls;
        unsigned short* hp = (unsigned short*)&hs;
        unsigned short* lp = (unsigned short*)&ls;
        #pragma unroll
        for (int j = 0; j < 4; ++j) f2h_split(r[j], hp[j], lp[j]);
        ((ushort4*)xhi)[i] = hs;
        ((ushort4*)xlo)[i] = ls;
    }
}

// ---------------- propagation (full-row fp16 gather, deep MLP) ----------------
__global__ void prop_kernel(const unsigned short* __restrict__ hsrc,
                            const int* __restrict__ offsets,
                            const int2* __restrict__ csr,
                            unsigned short* __restrict__ Ohi, unsigned short* __restrict__ Olo,
                            int n) {
    int node = blockIdx.x * 4 + (threadIdx.x >> 6);
    if (node >= n) return;
    int lane = threadIdx.x & 63;
    int half = lane >> 5;
    int cl   = lane & 31;           // 16B chunk id within the 512B row
    int beg = offsets[node], end = offsets[node + 1];
    float acc[8] = {0.f, 0.f, 0.f, 0.f, 0.f, 0.f, 0.f, 0.f};
    for (int i = beg; i < end; i += 8) {
        int ii[4] = {i + half, i + 2 + half, i + 4 + half, i + 6 + half};
        float w[4];
        int s[4];
        #pragma unroll
        for (int u = 0; u < 4; ++u) {
            int2 rec = csr[min(ii[u], end - 1)];
            w[u] = (ii[u] < end) ? __int_as_float(rec.y) : 0.f;
            s[u] = rec.x;
        }
        u16x8 v[4];
        #pragma unroll
        for (int u = 0; u < 4; ++u)
            v[u] = *(const u16x8*)(hsrc + (size_t)s[u] * HID + cl * 8);
        #pragma unroll
        for (int u = 0; u < 4; ++u)
            #pragma unroll
            for (int j = 0; j < 8; ++j)
                acc[j] += w[u] * h2f((unsigned short)v[u][j]);
    }
    #pragma unroll
    for (int j = 0; j < 8; ++j) acc[j] += __shfl_xor(acc[j], 32);
    u16x8 ov;
    if (half == 0) {
        #pragma unroll
        for (int j = 0; j < 8; ++j) ov[j] = f2h_us(acc[j]);
        *(u16x8*)(Ohi + (size_t)node * HID + cl * 8) = ov;
    } else {
        #pragma unroll
        for (int j = 0; j < 8; ++j) {
            unsigned short h, l;
            f2h_split(acc[j], h, l);
            ov[j] = l;
        }
        *(u16x8*)(Olo + (size_t)node * HID + cl * 8) = ov;
    }
}

// ---------------- tiled transpose -> single fp16 plane: src[R][C] -> dst[C][R] ----------------
__global__ void transpose_half_kernel(const float* __restrict__ src,
                                      unsigned short* __restrict__ dhi, int R, int C) {
    __shared__ float tile[32][33];
    int c0 = blockIdx.x * 32, r0 = blockIdx.y * 32;
    int tx = threadIdx.x, ty = threadIdx.y;   // block (32, 8)
    #pragma unroll
    for (int i = 0; i < 32; i += 8) {
        int r = r0 + ty + i, c = c0 + tx;
        tile[ty + i][tx] = (r < R && c < C) ? src[(size_t)r * C + c] : 0.f;
    }
    __syncthreads();
    #pragma unroll
    for (int i = 0; i < 32; i += 8) {
        int c = c0 + ty + i, r = r0 + tx;
        if (c < C && r < R) dhi[(size_t)c * R + r] = f2h_us(tile[tx][ty + i]);
    }
}

// ---------------- MFMA GEMM (fp16): 256x128 tile, 8 waves, double-buffered 2-phase ----------------
#define GBM 256
#define GBN 128
#define GBK 32

// ACT: relu; OUTMODE: 0 = fp32 C, 1 = fp16 hi/lo pair; NC: column blocks; STATS: fused BN colstats
template<int ACT, int OUTMODE, int NC, int STATS>
__global__ __launch_bounds__(512)
void mfma_gemm_kernel(const unsigned short* __restrict__ A0h, const unsigned short* __restrict__ A0l,
                      const unsigned short* __restrict__ A1h, const unsigned short* __restrict__ A1l,
                      const unsigned short* __restrict__ A2h, const unsigned short* __restrict__ A2l,
                      const unsigned short* __restrict__ Wh,
                      const float* __restrict__ bvec,
                      float* __restrict__ C, unsigned short* __restrict__ Chi,
                      unsigned short* __restrict__ Clo,
                      float* __restrict__ bn_sums, float* __restrict__ bn_sumsq,
                      int M, int K, int seg, int Kout) {
    // [buf][kgroup(4)][row][8 f16]: A planes 16KB/buf, B plane 8KB/buf -> 80KB total (2 blocks/CU)
    __shared__ __attribute__((aligned(16))) unsigned short As_hi[2][4 * GBM * 8];
    __shared__ __attribute__((aligned(16))) unsigned short As_lo[2][4 * GBM * 8];
    __shared__ __attribute__((aligned(16))) unsigned short Bs_hi[2][4 * GBN * 8];

    int tid  = threadIdx.x;
    int lane = tid & 63;
    int w    = tid >> 6;                   // wave id 0..7
    int wm   = w & 3, wn = w >> 2;         // 4x2 waves, 64x64 output each
    int kg   = lane >> 4, lr = lane & 15;  // fragment lane decomposition
    int kgq  = w & 3, hf = w >> 2;         // staging role: kgroup + half

    int bid = blockIdx.x, p, c;
    if (NC == 2) {
        p = ((bid >> 4) << 3) + (bid & 7);
        c = (bid >> 3) & 1;
        if (p >= N_PAD / GBM) return;      // grid padded to multiple of 16
    } else { p = bid; c = 0; }
    int bm = p * GBM, bn = c * GBN;

    f32x4 acc[4][4];
    #pragma unroll
    for (int i = 0; i < 4; ++i)
        #pragma unroll
        for (int j = 0; j < 4; ++j)
            acc[i][j] = (f32x4){0.f, 0.f, 0.f, 0.f};

    // each wave issues exactly 5 global_load_lds per STAGE (4 A + 1 B)
    auto STAGE = [&](int buf, int k0) {
        const unsigned short *Aph, *Apl; int kl0;
        if (k0 < seg)          { Aph = A0h; Apl = A0l; kl0 = k0; }
        else if (k0 < 2 * seg) { Aph = A1h; Apl = A1l; kl0 = k0 - seg; }
        else                   { Aph = A2h; Apl = A2l; kl0 = k0 - 2 * seg; }
        const unsigned short* a_h = Aph + (size_t)(bm + hf * 128 + lane) * seg + kl0 + kgq * 8;
        const unsigned short* a_l = Apl + (size_t)(bm + hf * 128 + lane) * seg + kl0 + kgq * 8;
        const unsigned short* b_h = Wh + (size_t)(bn + hf * 64 + lane) * K + k0 + kgq * 8;
        size_t rA = (size_t)64 * seg;
        gload_lds16(a_h,      &As_hi[buf][(kgq * GBM + hf * 128)      * 8]);
        gload_lds16(a_h + rA, &As_hi[buf][(kgq * GBM + hf * 128 + 64) * 8]);
        gload_lds16(a_l,      &As_lo[buf][(kgq * GBM + hf * 128)      * 8]);
        gload_lds16(a_l + rA, &As_lo[buf][(kgq * GBM + hf * 128 + 64) * 8]);
        gload_lds16(b_h,      &Bs_hi[buf][(kgq * GBN + hf * 64)       * 8]);
    };

    int nt = K / GBK;
    STAGE(0, 0);
    asm volatile("s_waitcnt vmcnt(0)" ::: "memory");
    __builtin_amdgcn_s_barrier();
    __builtin_amdgcn_sched_barrier(0);

    for (int t = 0; t < nt; ++t) {
        int cur = t & 1;
        if (t + 1 < nt) STAGE(cur ^ 1, (t + 1) * GBK);   // overlaps this step's compute

        int abase = (kg * GBM + wm * 64 + lr) * 8;
        int bbase = (kg * GBN + wn * 64 + lr) * 8;
        f16x8 ah[4], al[4], bh[4];
        #pragma unroll
        for (int mf = 0; mf < 4; ++mf) {
            ah[mf] = *(const f16x8*)&As_hi[cur][abase + mf * 16 * 8];
            al[mf] = *(const f16x8*)&As_lo[cur][abase + mf * 16 * 8];
        }
        #pragma unroll
        for (int nf = 0; nf < 4; ++nf)
            bh[nf] = *(const f16x8*)&Bs_hi[cur][bbase + nf * 16 * 8];
        #pragma unroll
        for (int mf = 0; mf < 4; ++mf)
            #pragma unroll
            for (int nf = 0; nf < 4; ++nf) {
                acc[mf][nf] = __builtin_amdgcn_mfma_f32_16x16x32_f16(ah[mf], bh[nf], acc[mf][nf], 0, 0, 0);
                acc[mf][nf] = __builtin_amdgcn_mfma_f32_16x16x32_f16(al[mf], bh[nf], acc[mf][nf], 0, 0, 0);
            }

        asm volatile("s_waitcnt vmcnt(0)" ::: "memory");  // next tile landed
        __builtin_amdgcn_s_barrier();                     // all waves done reading buf cur
        __builtin_amdgcn_sched_barrier(0);
    }

    // ---- epilogue: C/D layout col = lane&15, row = (lane>>4)*4 + reg ----
    #pragma unroll
    for (int nf = 0; nf < 4; ++nf) {
        int col = bn + wn * 64 + nf * 16 + lr;
        if (col >= Kout) continue;
        float bv = bvec[col];
        float s1 = 0.f, s2 = 0.f;
        #pragma unroll
        for (int mf = 0; mf < 4; ++mf) {
            #pragma unroll
            for (int i = 0; i < 4; ++i) {
                int rw = bm + wm * 64 + mf * 16 + kg * 4 + i;
                if (rw < M) {
                    float v = acc[mf][nf][i] + bv;
                    if (ACT == 1) v = fmaxf(v, 0.f);
                    if (STATS) { s1 += v; s2 += v * v; }
                    if (OUTMODE == 0) {
                        C[(size_t)rw * Kout + col] = v;
                    } else {
                        unsigned short hs, ls;
                        f2h_split(v, hs, ls);
                        Chi[(size_t)rw * Kout + col] = hs;
                        Clo[(size_t)rw * Kout + col] = ls;
                    }
                }
            }
        }
        if (STATS) {
            s1 += __shfl_xor(s1, 16); s1 += __shfl_xor(s1, 32);
            s2 += __shfl_xor(s2, 16); s2 += __shfl_xor(s2, 32);
            if (kg == 0) {
                atomicAdd(&bn_sums[col], s1);
                atomicAdd(&bn_sumsq[col], s2);
            }
        }
    }
}

__global__ void bnrelu_kernel(const float* __restrict__ y, const float* __restrict__ sums,
                              const float* __restrict__ sumsq, const float* __restrict__ g,
                              const float* __restrict__ beta,
                              unsigned short* __restrict__ Hhi, unsigned short* __restrict__ Hlo,
                              int M) {
    int idx = blockIdx.x * blockDim.x + threadIdx.x;   // group of 4 channels
    if (idx < M * HID / 4) {
        int col0 = (idx * 4) & (HID - 1);
        float4 v = ((const float4*)y)[idx];
        float invM = 1.0f / (float)M;
        float r[4] = {v.x, v.y, v.z, v.w};
        ushort4 hs, ls;
        unsigned short* hp = (unsigned short*)&hs;
        unsigned short* lp = (unsigned short*)&ls;
        #pragma unroll
        for (int j = 0; j < 4; ++j) {
            int col = col0 + j;
            float mean = sums[col] * invM;
            float var  = fmaxf(sumsq[col] * invM - mean * mean, 0.f);
            float o = (r[j] - mean) * rsqrtf(var + BN_EPS) * g[col] + beta[col];
            o = fmaxf(o, 0.f);
            f2h_split(o, hp[j], lp[j]);
        }
        ((ushort4*)Hhi)[idx] = hs;
        ((ushort4*)Hlo)[idx] = ls;
    }
}

extern "C" void kernel_launch(void* const* d_in, const int* in_sizes, int n_in,
                              void* d_out, int out_size, void* d_ws, size_t ws_size,
                              hipStream_t stream) {
    const float* x      = (const float*)d_in[0];
    const int*   ei     = (const int*)d_in[1];
    const float* W_feat = (const float*)d_in[2];
    const float* b_feat = (const float*)d_in[3];
    const float* W0     = (const float*)d_in[4];
    const float* b0     = (const float*)d_in[5];
    const float* g0     = (const float*)d_in[6];
    const float* beta0  = (const float*)d_in[7];
    const float* W1     = (const float*)d_in[8];
    const float* b1     = (const float*)d_in[9];
    const float* g1     = (const float*)d_in[10];
    const float* beta1  = (const float*)d_in[11];
    const float* Wc     = (const float*)d_in[12];
    const float* bc     = (const float*)d_in[13];
    float* out = (float*)d_out;

    const int N = N_NODES, E = N_EDGES;
    const int* row = ei;
    const int* col = ei + E;

    // workspace carve-up
    char* ws = (char*)d_ws;
    size_t off = 0;
    auto alloc = [&](size_t bytes) -> void* {
        void* p = ws + off;
        off = (off + bytes + 255) & ~(size_t)255;
        return p;
    };
    int*   deg_col  = (int*)  alloc(N * 4);
    int*   cursor   = (int*)  alloc(N * 4);
    int*   offsets  = (int*)  alloc((N + 1) * 4);
    int*   bsums    = (int*)  alloc(256 * 4);
    float* dis      = (float*)alloc(N * 4);
    int*   part_row = (int*)  alloc((size_t)NSLICE * N_PAD * 4);
    int*   part_col = (int*)  alloc((size_t)NSLICE * N_PAD * 4);
    int2*  csr      = (int2*) alloc((size_t)E * 8);
    unsigned short* x_hi    = (unsigned short*)alloc((size_t)N_PAD * IN_CH * 2);
    unsigned short* x_lo    = (unsigned short*)alloc((size_t)N_PAD * IN_CH * 2);
    unsigned short* h_hi    = (unsigned short*)alloc((size_t)N_PAD * HID * 2);
    unsigned short* h_lo    = (unsigned short*)alloc((size_t)N_PAD * HID * 2);
    unsigned short* agg1_hi = (unsigned short*)alloc((size_t)N_PAD * HID * 2);
    unsigned short* agg1_lo = (unsigned short*)alloc((size_t)N_PAD * HID * 2);
    // lifetime aliasing: x_hi/x_lo are dead after the feat GEMM; reuse the region
    unsigned short* agg2_hi = x_hi;
    unsigned short* agg2_lo = x_hi + (size_t)N_PAD * HID;
    float*          y       = (float*)x_lo;
    float* sums     = (float*)alloc(HID * 4);
    float* sumsq    = (float*)alloc(HID * 4);
    unsigned short* WTf_hi = (unsigned short*)alloc((size_t)HID * IN_CH * 2);
    unsigned short* WT0_hi = (unsigned short*)alloc((size_t)HID * 3 * HID * 2);
    unsigned short* WT1_hi = (unsigned short*)alloc((size_t)HID * 3 * HID * 2);
    unsigned short* WTc_hi = (unsigned short*)alloc((size_t)128 * HID * 2);   // 40 rows padded to 128

    hipMemsetAsync(cursor, 0, N * 4, stream);
    hipMemsetAsync(WTc_hi, 0, (size_t)128 * HID * 2, stream);

    // operand pre-splits (independent of CSR build)
    split_x_kernel<<<(N * IN_CH / 4 + 255) / 256, 256, 0, stream>>>(x, x_hi, x_lo, N * IN_CH / 4);
    dim3 tb(32, 8);
    transpose_half_kernel<<<dim3(HID / 32, IN_CH / 32), tb, 0, stream>>>(W_feat, WTf_hi, IN_CH, HID);
    transpose_half_kernel<<<dim3(HID / 32, 3 * HID / 32), tb, 0, stream>>>(W0, WT0_hi, 3 * HID, HID);
    transpose_half_kernel<<<dim3(HID / 32, 3 * HID / 32), tb, 0, stream>>>(W1, WT1_hi, 3 * HID, HID);
    transpose_half_kernel<<<dim3((OUT_CH + 31) / 32, HID / 32), tb, 0, stream>>>(Wc, WTc_hi, HID, OUT_CH);

    // degree histograms (LDS-privatized, atomic-free globally)
    hist_kernel<<<dim3(NSLICE, NCHUNK), 256, 0, stream>>>(row, col, part_row, part_col, E);
    merge_deg_kernel<<<(N + 255) / 256, 256, 0, stream>>>(part_row, part_col, dis, deg_col, N);

    const int NB_SCAN = (N + 255) / 256;   // 196
    scan1_kernel<<<NB_SCAN, 256, 0, stream>>>(deg_col, bsums, N);
    scan2_kernel<<<1, 256, 0, stream>>>(bsums, NB_SCAN);
    scan3_kernel<<<NB_SCAN, 256, 0, stream>>>(deg_col, bsums, offsets, N);
    fill_csr_kernel<<<(E + 255) / 256, 256, 0, stream>>>(row, col, dis, offsets, cursor,
                                                         csr, E);

    // NC=2 grids: 196 panels x 2 col-blocks, swizzle needs grid multiple of 16 -> 400 (guarded)
    const int G2 = 400;
    // h = relu(x @ W_feat + b_feat) -> fp16 hi/lo pair
    mfma_gemm_kernel<1, 1, 2, 0><<<G2, 512, 0, stream>>>(
        x_hi, x_lo, nullptr, nullptr, nullptr, nullptr, WTf_hi, b_feat,
        nullptr, h_hi, h_lo, nullptr, nullptr, N, IN_CH, IN_CH, HID);

    const unsigned short* WThs[2] = {WT0_hi, WT1_hi};
    const float* bs[2]    = {b0, b1};
    const float* gs[2]    = {g0, g1};
    const float* betas[2] = {beta0, beta1};
    int prop_grid = (N + 3) / 4;
    for (int layer = 0; layer < 2; ++layer) {
        prop_kernel<<<prop_grid, 256, 0, stream>>>(h_hi, offsets, csr, agg1_hi, agg1_lo, N);
        prop_kernel<<<prop_grid, 256, 0, stream>>>(agg1_hi, offsets, csr, agg2_hi, agg2_lo, N);
        hipMemsetAsync(sums, 0, HID * 4, stream);
        hipMemsetAsync(sumsq, 0, HID * 4, stream);
        mfma_gemm_kernel<0, 0, 2, 1><<<G2, 512, 0, stream>>>(
            h_hi, h_lo, agg1_hi, agg1_lo, agg2_hi, agg2_lo, WThs[layer], bs[layer],
            y, nullptr, nullptr, sums, sumsq, N, 3 * HID, HID, HID);
        bnrelu_kernel<<<(N * HID / 4 + 255) / 256, 256, 0, stream>>>(y, sums, sumsq, gs[layer],
                                                                     betas[layer], h_hi, h_lo, N);
    }

    mfma_gemm_kernel<0, 0, 1, 0><<<N_PAD / GBM, 512, 0, stream>>>(
        h_hi, h_lo, nullptr, nullptr, nullptr, nullptr, WTc_hi, bc,
        out, nullptr, nullptr, nullptr, nullptr, N, HID, HID, OUT_CH);
}

// Round 12
// 984.477 us; speedup vs baseline: 1.7033x; 1.0035x over previous
//
#include <hip/hip_runtime.h>

#define N_NODES 50000
#define N_PAD   50176            // 196 * 256 = 8 * 6272
#define N_EDGES 1600000
#define IN_CH   512
#define HID     256
#define OUT_CH  40
#define BN_EPS  1e-5f

#define HCHUNK  6272             // nodes per histogram chunk (8 chunks cover N_PAD)
#define NCHUNK  8
#define NSLICE  32               // edge slices; E/NSLICE = 50000 exactly

typedef _Float16 f16x8 __attribute__((ext_vector_type(8)));
typedef __attribute__((ext_vector_type(8))) unsigned short u16x8;
typedef __attribute__((ext_vector_type(4))) float f32x4;

__device__ __forceinline__ unsigned short f2h_us(float f) {
    _Float16 h = (_Float16)f;
    return __builtin_bit_cast(unsigned short, h);
}
__device__ __forceinline__ float h2f(unsigned short u) {
    return (float)__builtin_bit_cast(_Float16, u);
}
// split f into fp16 hi + fp16 lo (residual; exact subtraction in fp32)
__device__ __forceinline__ void f2h_split(float f, unsigned short& hi, unsigned short& lo) {
    _Float16 h = (_Float16)f;
    hi = __builtin_bit_cast(unsigned short, h);
    lo = f2h_us(f - (float)h);
}

// async global->LDS, 16B per lane; LDS dest is wave-uniform base + lane*16
__device__ __forceinline__ void gload_lds16(const void* gsrc, void* ldst) {
    __builtin_amdgcn_global_load_lds(
        (const __attribute__((address_space(1))) unsigned int*)gsrc,
        (__attribute__((address_space(3))) unsigned int*)ldst,
        16, 0, 0);
}

// ---------------- degree histograms via LDS privatization (no global atomics) ----------------
__global__ __launch_bounds__(256)
void hist_kernel(const int* __restrict__ row, const int* __restrict__ col,
                 int* __restrict__ part_row, int* __restrict__ part_col, int E) {
    __shared__ int hr[HCHUNK];
    __shared__ int hc[HCHUNK];
    int s = blockIdx.x;        // edge slice
    int c = blockIdx.y;        // node chunk
    int base = c * HCHUNK;
    int t = threadIdx.x;
    for (int i = t; i < HCHUNK; i += 256) { hr[i] = 0; hc[i] = 0; }
    __syncthreads();
    int e0 = s * (E / NSLICE), e1 = e0 + E / NSLICE;
    for (int e = e0 + t; e < e1; e += 256) {
        int r = row[e], cc = col[e];
        unsigned lr = (unsigned)(r - base);
        unsigned lc = (unsigned)(cc - base);
        if (lr < HCHUNK) atomicAdd(&hr[lr], 1);
        if (lc < HCHUNK) atomicAdd(&hc[lc], 1);
    }
    __syncthreads();
    int* pr = part_row + (size_t)s * N_PAD + base;
    int* pc = part_col + (size_t)s * N_PAD + base;
    for (int i = t; i < HCHUNK; i += 256) { pr[i] = hr[i]; pc[i] = hc[i]; }
}

__global__ void merge_deg_kernel(const int* __restrict__ part_row, const int* __restrict__ part_col,
                                 float* __restrict__ dis, int* __restrict__ deg_col, int n) {
    int i = blockIdx.x * blockDim.x + threadIdx.x;
    if (i < n) {
        int dr = 0, dc = 0;
        #pragma unroll
        for (int s = 0; s < NSLICE; ++s) {
            dr += part_row[(size_t)s * N_PAD + i];
            dc += part_col[(size_t)s * N_PAD + i];
        }
        dis[i] = rsqrtf((float)max(dr, 1));
        deg_col[i] = dc;
    }
}

// ---------------- 3-phase exclusive prefix sum ----------------
__global__ void scan1_kernel(const int* __restrict__ deg, int* __restrict__ bsums, int n) {
    __shared__ int sd[256];
    int t = threadIdx.x;
    int i = blockIdx.x * 256 + t;
    sd[t] = (i < n) ? deg[i] : 0;
    __syncthreads();
    for (int o = 128; o > 0; o >>= 1) {
        if (t < o) sd[t] += sd[t + o];
        __syncthreads();
    }
    if (t == 0) bsums[blockIdx.x] = sd[0];
}

__global__ void scan2_kernel(int* __restrict__ bsums, int nb) {   // 1 block, 256 threads
    __shared__ int sd[256];
    int t = threadIdx.x;
    int v = (t < nb) ? bsums[t] : 0;
    sd[t] = v;
    __syncthreads();
    for (int o = 1; o < 256; o <<= 1) {
        int u = (t >= o) ? sd[t - o] : 0;
        __syncthreads();
        sd[t] += u;
        __syncthreads();
    }
    if (t < nb) bsums[t] = sd[t] - v;   // exclusive
}

__global__ void scan3_kernel(const int* __restrict__ deg, const int* __restrict__ bsums,
                             int* __restrict__ offsets, int n) {
    __shared__ int sd[256];
    int t = threadIdx.x;
    int i = blockIdx.x * 256 + t;
    sd[t] = (i < n) ? deg[i] : 0;
    __syncthreads();
    for (int o = 1; o < 256; o <<= 1) {
        int u = (t >= o) ? sd[t - o] : 0;
        __syncthreads();
        sd[t] += u;
        __syncthreads();
    }
    if (i < n) offsets[i + 1] = bsums[blockIdx.x] + sd[t];
    if (i == 0) offsets[0] = 0;
}

// ---------------- CSR fill: single 8B record {src_row, norm_bits} per edge ----------------
__global__ void fill_csr_kernel(const int* __restrict__ row, const int* __restrict__ col,
                                const float* __restrict__ dis, const int* __restrict__ offsets,
                                int* __restrict__ cursor, int2* __restrict__ csr, int E) {
    int e = blockIdx.x * blockDim.x + threadIdx.x;
    if (e < E) {
        int r = row[e], c = col[e];
        int pos = atomicAdd(&cursor[c], 1);
        int idx = offsets[c] + pos;
        float nrm = dis[r] * dis[c];
        csr[idx] = make_int2(r, __float_as_int(nrm));
    }
}

// ---------------- x hi/lo split (fp16) ----------------
__global__ void split_x_kernel(const float* __restrict__ x, unsigned short* __restrict__ xhi,
                               unsigned short* __restrict__ xlo, int n4) {
    int i = blockIdx.x * blockDim.x + threadIdx.x;
    if (i < n4) {
        float4 v = ((const float4*)x)[i];
        float r[4] = {v.x, v.y, v.z, v.w};
        ushort4 hs, ls;
        unsigned short* hp = (unsigned short*)&hs;
        unsigned short* lp = (unsigned short*)&ls;
        #pragma unroll
        for (int j = 0; j < 4; ++j) f2h_split(r[j], hp[j], lp[j]);
        ((ushort4*)xhi)[i] = hs;
        ((ushort4*)xlo)[i] = ls;
    }
}

// ---------------- propagation (full-row fp16 gather, 8-deep MLP per half-wave) ----------------
__global__ void prop_kernel(const unsigned short* __restrict__ hsrc,
                            const int* __restrict__ offsets,
                            const int2* __restrict__ csr,
                            unsigned short* __restrict__ Ohi, unsigned short* __restrict__ Olo,
                            int n) {
    int node = blockIdx.x * 4 + (threadIdx.x >> 6);
    if (node >= n) return;
    int lane = threadIdx.x & 63;
    int half = lane >> 5;
    int cl   = lane & 31;           // 16B chunk id within the 512B row
    int beg = offsets[node], end = offsets[node + 1];
    float acc[8] = {0.f, 0.f, 0.f, 0.f, 0.f, 0.f, 0.f, 0.f};
    for (int i = beg; i < end; i += 16) {
        float w[8];
        int s[8];
        #pragma unroll
        for (int u = 0; u < 8; ++u) {
            int iu = i + 2 * u + half;
            int2 rec = csr[min(iu, end - 1)];
            w[u] = (iu < end) ? __int_as_float(rec.y) : 0.f;
            s[u] = rec.x;
        }
        u16x8 v[8];
        #pragma unroll
        for (int u = 0; u < 8; ++u)
            v[u] = *(const u16x8*)(hsrc + (size_t)s[u] * HID + cl * 8);
        #pragma unroll
        for (int u = 0; u < 8; ++u)
            #pragma unroll
            for (int j = 0; j < 8; ++j)
                acc[j] += w[u] * h2f((unsigned short)v[u][j]);
    }
    #pragma unroll
    for (int j = 0; j < 8; ++j) acc[j] += __shfl_xor(acc[j], 32);
    u16x8 ov;
    if (half == 0) {
        #pragma unroll
        for (int j = 0; j < 8; ++j) ov[j] = f2h_us(acc[j]);
        *(u16x8*)(Ohi + (size_t)node * HID + cl * 8) = ov;
    } else {
        #pragma unroll
        for (int j = 0; j < 8; ++j) {
            unsigned short h, l;
            f2h_split(acc[j], h, l);
            ov[j] = l;
        }
        *(u16x8*)(Olo + (size_t)node * HID + cl * 8) = ov;
    }
}

// ---------------- tiled transpose -> single fp16 plane: src[R][C] -> dst[C][R] ----------------
__global__ void transpose_half_kernel(const float* __restrict__ src,
                                      unsigned short* __restrict__ dhi, int R, int C) {
    __shared__ float tile[32][33];
    int c0 = blockIdx.x * 32, r0 = blockIdx.y * 32;
    int tx = threadIdx.x, ty = threadIdx.y;   // block (32, 8)
    #pragma unroll
    for (int i = 0; i < 32; i += 8) {
        int r = r0 + ty + i, c = c0 + tx;
        tile[ty + i][tx] = (r < R && c < C) ? src[(size_t)r * C + c] : 0.f;
    }
    __syncthreads();
    #pragma unroll
    for (int i = 0; i < 32; i += 8) {
        int c = c0 + ty + i, r = r0 + tx;
        if (c < C && r < R) dhi[(size_t)c * R + r] = f2h_us(tile[tx][ty + i]);
    }
}

// ---------------- MFMA GEMM (fp16): 256x128 tile, 8 waves, double-buffered 2-phase ----------------
#define GBM 256
#define GBN 128
#define GBK 32

// ACT: relu; OUTMODE: 0 = fp32 C, 1 = fp16 hi/lo pair; NC: column blocks; STATS: fused BN colstats
template<int ACT, int OUTMODE, int NC, int STATS>
__global__ __launch_bounds__(512)
void mfma_gemm_kernel(const unsigned short* __restrict__ A0h, const unsigned short* __restrict__ A0l,
                      const unsigned short* __restrict__ A1h, const unsigned short* __restrict__ A1l,
                      const unsigned short* __restrict__ A2h, const unsigned short* __restrict__ A2l,
                      const unsigned short* __restrict__ Wh,
                      const float* __restrict__ bvec,
                      float* __restrict__ C, unsigned short* __restrict__ Chi,
                      unsigned short* __restrict__ Clo,
                      float* __restrict__ bn_sums, float* __restrict__ bn_sumsq,
                      int M, int K, int seg, int Kout) {
    // [buf][kgroup(4)][row][8 f16]: A planes 16KB/buf, B plane 8KB/buf -> 80KB total (2 blocks/CU)
    __shared__ __attribute__((aligned(16))) unsigned short As_hi[2][4 * GBM * 8];
    __shared__ __attribute__((aligned(16))) unsigned short As_lo[2][4 * GBM * 8];
    __shared__ __attribute__((aligned(16))) unsigned short Bs_hi[2][4 * GBN * 8];

    int tid  = threadIdx.x;
    int lane = tid & 63;
    int w    = tid >> 6;                   // wave id 0..7
    int wm   = w & 3, wn = w >> 2;         // 4x2 waves, 64x64 output each
    int kg   = lane >> 4, lr = lane & 15;  // fragment lane decomposition
    int kgq  = w & 3, hf = w >> 2;         // staging role: kgroup + half

    int bid = blockIdx.x, p, c;
    if (NC == 2) {
        p = ((bid >> 4) << 3) + (bid & 7);
        c = (bid >> 3) & 1;
        if (p >= N_PAD / GBM) return;      // grid padded to multiple of 16
    } else { p = bid; c = 0; }
    int bm = p * GBM, bn = c * GBN;

    f32x4 acc[4][4];
    #pragma unroll
    for (int i = 0; i < 4; ++i)
        #pragma unroll
        for (int j = 0; j < 4; ++j)
            acc[i][j] = (f32x4){0.f, 0.f, 0.f, 0.f};

    // each wave issues exactly 5 global_load_lds per STAGE (4 A + 1 B)
    auto STAGE = [&](int buf, int k0) {
        const unsigned short *Aph, *Apl; int kl0;
        if (k0 < seg)          { Aph = A0h; Apl = A0l; kl0 = k0; }
        else if (k0 < 2 * seg) { Aph = A1h; Apl = A1l; kl0 = k0 - seg; }
        else                   { Aph = A2h; Apl = A2l; kl0 = k0 - 2 * seg; }
        const unsigned short* a_h = Aph + (size_t)(bm + hf * 128 + lane) * seg + kl0 + kgq * 8;
        const unsigned short* a_l = Apl + (size_t)(bm + hf * 128 + lane) * seg + kl0 + kgq * 8;
        const unsigned short* b_h = Wh + (size_t)(bn + hf * 64 + lane) * K + k0 + kgq * 8;
        size_t rA = (size_t)64 * seg;
        gload_lds16(a_h,      &As_hi[buf][(kgq * GBM + hf * 128)      * 8]);
        gload_lds16(a_h + rA, &As_hi[buf][(kgq * GBM + hf * 128 + 64) * 8]);
        gload_lds16(a_l,      &As_lo[buf][(kgq * GBM + hf * 128)      * 8]);
        gload_lds16(a_l + rA, &As_lo[buf][(kgq * GBM + hf * 128 + 64) * 8]);
        gload_lds16(b_h,      &Bs_hi[buf][(kgq * GBN + hf * 64)       * 8]);
    };

    int nt = K / GBK;
    STAGE(0, 0);
    asm volatile("s_waitcnt vmcnt(0)" ::: "memory");
    __builtin_amdgcn_s_barrier();
    __builtin_amdgcn_sched_barrier(0);

    for (int t = 0; t < nt; ++t) {
        int cur = t & 1;
        if (t + 1 < nt) STAGE(cur ^ 1, (t + 1) * GBK);   // overlaps this step's compute

        int abase = (kg * GBM + wm * 64 + lr) * 8;
        int bbase = (kg * GBN + wn * 64 + lr) * 8;
        f16x8 ah[4], al[4], bh[4];
        #pragma unroll
        for (int mf = 0; mf < 4; ++mf) {
            ah[mf] = *(const f16x8*)&As_hi[cur][abase + mf * 16 * 8];
            al[mf] = *(const f16x8*)&As_lo[cur][abase + mf * 16 * 8];
        }
        #pragma unroll
        for (int nf = 0; nf < 4; ++nf)
            bh[nf] = *(const f16x8*)&Bs_hi[cur][bbase + nf * 16 * 8];
        #pragma unroll
        for (int mf = 0; mf < 4; ++mf)
            #pragma unroll
            for (int nf = 0; nf < 4; ++nf) {
                acc[mf][nf] = __builtin_amdgcn_mfma_f32_16x16x32_f16(ah[mf], bh[nf], acc[mf][nf], 0, 0, 0);
                acc[mf][nf] = __builtin_amdgcn_mfma_f32_16x16x32_f16(al[mf], bh[nf], acc[mf][nf], 0, 0, 0);
            }

        asm volatile("s_waitcnt vmcnt(0)" ::: "memory");  // next tile landed
        __builtin_amdgcn_s_barrier();                     // all waves done reading buf cur
        __builtin_amdgcn_sched_barrier(0);
    }

    // ---- epilogue: C/D layout col = lane&15, row = (lane>>4)*4 + reg ----
    #pragma unroll
    for (int nf = 0; nf < 4; ++nf) {
        int col = bn + wn * 64 + nf * 16 + lr;
        if (col >= Kout) continue;
        float bv = bvec[col];
        float s1 = 0.f, s2 = 0.f;
        #pragma unroll
        for (int mf = 0; mf < 4; ++mf) {
            #pragma unroll
            for (int i = 0; i < 4; ++i) {
                int rw = bm + wm * 64 + mf * 16 + kg * 4 + i;
                if (rw < M) {
                    float v = acc[mf][nf][i] + bv;
                    if (ACT == 1) v = fmaxf(v, 0.f);
                    if (STATS) { s1 += v; s2 += v * v; }
                    if (OUTMODE == 0) {
                        C[(size_t)rw * Kout + col] = v;
                    } else {
                        unsigned short hs, ls;
                        f2h_split(v, hs, ls);
                        Chi[(size_t)rw * Kout + col] = hs;
                        Clo[(size_t)rw * Kout + col] = ls;
                    }
                }
            }
        }
        if (STATS) {
            s1 += __shfl_xor(s1, 16); s1 += __shfl_xor(s1, 32);
            s2 += __shfl_xor(s2, 16); s2 += __shfl_xor(s2, 32);
            if (kg == 0) {
                atomicAdd(&bn_sums[col], s1);
                atomicAdd(&bn_sumsq[col], s2);
            }
        }
    }
}

__global__ void bnrelu_kernel(const float* __restrict__ y, const float* __restrict__ sums,
                              const float* __restrict__ sumsq, const float* __restrict__ g,
                              const float* __restrict__ beta,
                              unsigned short* __restrict__ Hhi, unsigned short* __restrict__ Hlo,
                              int M) {
    int idx = blockIdx.x * blockDim.x + threadIdx.x;   // group of 4 channels
    if (idx < M * HID / 4) {
        int col0 = (idx * 4) & (HID - 1);
        float4 v = ((const float4*)y)[idx];
        float invM = 1.0f / (float)M;
        float r[4] = {v.x, v.y, v.z, v.w};
        ushort4 hs, ls;
        unsigned short* hp = (unsigned short*)&hs;
        unsigned short* lp = (unsigned short*)&ls;
        #pragma unroll
        for (int j = 0; j < 4; ++j) {
            int col = col0 + j;
            float mean = sums[col] * invM;
            float var  = fmaxf(sumsq[col] * invM - mean * mean, 0.f);
            float o = (r[j] - mean) * rsqrtf(var + BN_EPS) * g[col] + beta[col];
            o = fmaxf(o, 0.f);
            f2h_split(o, hp[j], lp[j]);
        }
        ((ushort4*)Hhi)[idx] = hs;
        ((ushort4*)Hlo)[idx] = ls;
    }
}

extern "C" void kernel_launch(void* const* d_in, const int* in_sizes, int n_in,
                              void* d_out, int out_size, void* d_ws, size_t ws_size,
                              hipStream_t stream) {
    const float* x      = (const float*)d_in[0];
    const int*   ei     = (const int*)d_in[1];
    const float* W_feat = (const float*)d_in[2];
    const float* b_feat = (const float*)d_in[3];
    const float* W0     = (const float*)d_in[4];
    const float* b0     = (const float*)d_in[5];
    const float* g0     = (const float*)d_in[6];
    const float* beta0  = (const float*)d_in[7];
    const float* W1     = (const float*)d_in[8];
    const float* b1     = (const float*)d_in[9];
    const float* g1     = (const float*)d_in[10];
    const float* beta1  = (const float*)d_in[11];
    const float* Wc     = (const float*)d_in[12];
    const float* bc     = (const float*)d_in[13];
    float* out = (float*)d_out;

    const int N = N_NODES, E = N_EDGES;
    const int* row = ei;
    const int* col = ei + E;

    // workspace carve-up
    char* ws = (char*)d_ws;
    size_t off = 0;
    auto alloc = [&](size_t bytes) -> void* {
        void* p = ws + off;
        off = (off + bytes + 255) & ~(size_t)255;
        return p;
    };
    int*   deg_col  = (int*)  alloc(N * 4);
    int*   cursor   = (int*)  alloc(N * 4);
    int*   offsets  = (int*)  alloc((N + 1) * 4);
    int*   bsums    = (int*)  alloc(256 * 4);
    float* dis      = (float*)alloc(N * 4);
    int*   part_row = (int*)  alloc((size_t)NSLICE * N_PAD * 4);
    int*   part_col = (int*)  alloc((size_t)NSLICE * N_PAD * 4);
    int2*  csr      = (int2*) alloc((size_t)E * 8);
    unsigned short* x_hi    = (unsigned short*)alloc((size_t)N_PAD * IN_CH * 2);
    unsigned short* x_lo    = (unsigned short*)alloc((size_t)N_PAD * IN_CH * 2);
    unsigned short* h_hi    = (unsigned short*)alloc((size_t)N_PAD * HID * 2);
    unsigned short* h_lo    = (unsigned short*)alloc((size_t)N_PAD * HID * 2);
    unsigned short* agg1_hi = (unsigned short*)alloc((size_t)N_PAD * HID * 2);
    unsigned short* agg1_lo = (unsigned short*)alloc((size_t)N_PAD * HID * 2);
    // lifetime aliasing: x_hi/x_lo are dead after the feat GEMM; reuse the region
    unsigned short* agg2_hi = x_hi;
    unsigned short* agg2_lo = x_hi + (size_t)N_PAD * HID;
    float*          y       = (float*)x_lo;
    float* sums     = (float*)alloc(HID * 4);
    float* sumsq    = (float*)alloc(HID * 4);
    unsigned short* WTf_hi = (unsigned short*)alloc((size_t)HID * IN_CH * 2);
    unsigned short* WT0_hi = (unsigned short*)alloc((size_t)HID * 3 * HID * 2);
    unsigned short* WT1_hi = (unsigned short*)alloc((size_t)HID * 3 * HID * 2);
    unsigned short* WTc_hi = (unsigned short*)alloc((size_t)128 * HID * 2);   // 40 rows padded to 128

    hipMemsetAsync(cursor, 0, N * 4, stream);
    hipMemsetAsync(WTc_hi, 0, (size_t)128 * HID * 2, stream);

    // operand pre-splits (independent of CSR build)
    split_x_kernel<<<(N * IN_CH / 4 + 255) / 256, 256, 0, stream>>>(x, x_hi, x_lo, N * IN_CH / 4);
    dim3 tb(32, 8);
    transpose_half_kernel<<<dim3(HID / 32, IN_CH / 32), tb, 0, stream>>>(W_feat, WTf_hi, IN_CH, HID);
    transpose_half_kernel<<<dim3(HID / 32, 3 * HID / 32), tb, 0, stream>>>(W0, WT0_hi, 3 * HID, HID);
    transpose_half_kernel<<<dim3(HID / 32, 3 * HID / 32), tb, 0, stream>>>(W1, WT1_hi, 3 * HID, HID);
    transpose_half_kernel<<<dim3((OUT_CH + 31) / 32, HID / 32), tb, 0, stream>>>(Wc, WTc_hi, HID, OUT_CH);

    // degree histograms (LDS-privatized, atomic-free globally)
    hist_kernel<<<dim3(NSLICE, NCHUNK), 256, 0, stream>>>(row, col, part_row, part_col, E);
    merge_deg_kernel<<<(N + 255) / 256, 256, 0, stream>>>(part_row, part_col, dis, deg_col, N);

    const int NB_SCAN = (N + 255) / 256;   // 196
    scan1_kernel<<<NB_SCAN, 256, 0, stream>>>(deg_col, bsums, N);
    scan2_kernel<<<1, 256, 0, stream>>>(bsums, NB_SCAN);
    scan3_kernel<<<NB_SCAN, 256, 0, stream>>>(deg_col, bsums, offsets, N);
    fill_csr_kernel<<<(E + 255) / 256, 256, 0, stream>>>(row, col, dis, offsets, cursor,
                                                         csr, E);

    // NC=2 grids: 196 panels x 2 col-blocks, swizzle needs grid multiple of 16 -> 400 (guarded)
    const int G2 = 400;
    // h = relu(x @ W_feat + b_feat) -> fp16 hi/lo pair
    mfma_gemm_kernel<1, 1, 2, 0><<<G2, 512, 0, stream>>>(
        x_hi, x_lo, nullptr, nullptr, nullptr, nullptr, WTf_hi, b_feat,
        nullptr, h_hi, h_lo, nullptr, nullptr, N, IN_CH, IN_CH, HID);

    const unsigned short* WThs[2] = {WT0_hi, WT1_hi};
    const float* bs[2]    = {b0, b1};
    const float* gs[2]    = {g0, g1};
    const float* betas[2] = {beta0, beta1};
    int prop_grid = (N + 3) / 4;
    for (int layer = 0; layer < 2; ++layer) {
        prop_kernel<<<prop_grid, 256, 0, stream>>>(h_hi, offsets, csr, agg1_hi, agg1_lo, N);
        prop_kernel<<<prop_grid, 256, 0, stream>>>(agg1_hi, offsets, csr, agg2_hi, agg2_lo, N);
        hipMemsetAsync(sums, 0, HID * 4, stream);
        hipMemsetAsync(sumsq, 0, HID * 4, stream);
        mfma_gemm_kernel<0, 0, 2, 1><<<G2, 512, 0, stream>>>(
            h_hi, h_lo, agg1_hi, agg1_lo, agg2_hi, agg2_lo, WThs[layer], bs[layer],
            y, nullptr, nullptr, sums, sumsq, N, 3 * HID, HID, HID);
        bnrelu_kernel<<<(N * HID / 4 + 255) / 256, 256, 0, stream>>>(y, sums, sumsq, gs[layer],
                                                                     betas[layer], h_hi, h_lo, N);
    }

    mfma_gemm_kernel<0, 0, 1, 0><<<N_PAD / GBM, 512, 0, stream>>>(
        h_hi, h_lo, nullptr, nullptr, nullptr, nullptr, WTc_hi, bc,
        out, nullptr, nullptr, nullptr, nullptr, N, HID, HID, OUT_CH);
}